// Round 9
// baseline (486.221 us; speedup 1.0000x reference)
//
#include <hip/hip_runtime.h>
#include <hip/hip_bf16.h>

// Problem constants
#define NB   4
#define NT   4096
#define BT   16384   // NB*NT
#define NDIM 1024
#define NH   16
#define NDH  64
#define CC   64              // chunk size (time steps)
#define NCH  (NT / CC)       // 64 chunks per pair
#define NPAIR 64             // B*H
#define NU   (NPAIR * NCH)   // 4096 units
#define DBS  24              // Db row stride (u16 elems), padded for banks

using u16 = unsigned short;
typedef __bf16 bf16x8 __attribute__((ext_vector_type(8)));
typedef float f32x4 __attribute__((ext_vector_type(4)));
typedef unsigned short u16x8 __attribute__((ext_vector_type(8)));
typedef unsigned short u16x4 __attribute__((ext_vector_type(4)));

__device__ __forceinline__ float bf2f(u16 b) { return __uint_as_float(((unsigned)b) << 16); }
__device__ __forceinline__ u16 f2bf(float f) {
  return __builtin_bit_cast(u16, __float2bfloat16(f));
}
// LDS row swizzle (u16-element index, 8-elem granular): breaks stride-128B bank conflicts
__device__ __forceinline__ int swz(int row, int e) { return e ^ ((row & 7) << 3); }
__device__ __forceinline__ bf16x8 zfrag() {
  u16x8 z = {0, 0, 0, 0, 0, 0, 0, 0};
  return __builtin_bit_cast(bf16x8, z);
}
// head-major qkv layout: [slot(3)][head(16)][bt(BT)][d(64)] — per-(h,chunk) tile contiguous
__device__ __forceinline__ long qkvT_idx(int s, int h, long bt, int d) {
  return ((long)(s * 16 + h) * BT + bt) * 64 + d;
}

// ---------------- convert fp32 -> bf16 (vectorized) ----------------
__global__ __launch_bounds__(256) void k_f32_to_bf16(const float* __restrict__ in,
                                                     u16* __restrict__ out, long n4) {
  long i = (long)blockIdx.x * blockDim.x + threadIdx.x;
  if (i >= n4) return;
  float4 f = reinterpret_cast<const float4*>(in)[i];
  u16x4 o;
  o.x = f2bf(f.x); o.y = f2bf(f.y); o.z = f2bf(f.z); o.w = f2bf(f.w);
  reinterpret_cast<u16x4*>(out)[i] = o;
}

// ---------------- build padded gate weight matrix (128 x 1024 bf16) ----------------
__global__ __launch_bounds__(256) void k_build_wgb(const float* __restrict__ Wg,
                                                   const float* __restrict__ Wb,
                                                   u16* __restrict__ out) {
  int i = blockIdx.x * 256 + threadIdx.x;
  int row = i >> 10, col = i & 1023;
  float f = 0.f;
  if (row < 16)       f = Wg[row * 1024 + col];
  else if (row < 32)  f = Wb[(row - 16) * 1024 + col];
  out[i] = f2bf(f);
}

// ---------------- global_load_lds helper ----------------
typedef unsigned int u32_as1 __attribute__((address_space(1)));
typedef unsigned int u32_as3 __attribute__((address_space(3)));
__device__ __forceinline__ void gload_lds16(const void* g, void* l) {
  __builtin_amdgcn_global_load_lds((const u32_as1*)g, (u32_as3*)l, 16, 0, 0);
}

// ---------------- bf16 GEMM (small-N path): C(MxN) = A(MxK) @ B(NxK)^T -------
template <typename OutT>
__global__ __launch_bounds__(256) void k_gemm_bt(const u16* __restrict__ A,
                                                 const u16* __restrict__ B,
                                                 OutT* __restrict__ C,
                                                 int M, int N, int K) {
  constexpr int BM = 128, BN = 128, BK = 32;
  __shared__ __align__(16) u16 As[BM * BK];
  __shared__ __align__(16) u16 Bs[BN * BK];
  const int tid = threadIdx.x;
  const int l = tid & 63, w = tid >> 6;
  const int tn = blockIdx.x, tm = blockIdx.y;
  const long a0 = (long)tm * BM * K;
  const long b0 = (long)tn * BN * K;
  const int srow = tid >> 2;
  const int scol = (tid & 3) << 3;
  const int wrow = (w >> 1) << 6;
  const int wcol = (w & 1) << 6;
  const int fr = l & 15, fq = l >> 4;

  f32x4 acc[4][4];
#pragma unroll
  for (int m = 0; m < 4; ++m)
#pragma unroll
    for (int n = 0; n < 4; ++n) acc[m][n] = f32x4{0.f, 0.f, 0.f, 0.f};

  for (int kk = 0; kk < K; kk += BK) {
    __syncthreads();
    const u16* gA = A + a0 + (long)srow * K + kk + scol;
    const u16* gB = B + b0 + (long)srow * K + kk + scol;
    gload_lds16(gA,                &As[(w * 16) * BK]);
    gload_lds16(gA + 64 * (long)K, &As[(64 + w * 16) * BK]);
    gload_lds16(gB,                &Bs[(w * 16) * BK]);
    gload_lds16(gB + 64 * (long)K, &Bs[(64 + w * 16) * BK]);
    __syncthreads();

    bf16x8 af[4], bfv[4];
#pragma unroll
    for (int m = 0; m < 4; ++m)
      af[m] = *(const bf16x8*)&As[(wrow + m * 16 + fr) * BK + (fq << 3)];
#pragma unroll
    for (int n = 0; n < 4; ++n)
      bfv[n] = *(const bf16x8*)&Bs[(wcol + n * 16 + fr) * BK + (fq << 3)];
#pragma unroll
    for (int m = 0; m < 4; ++m)
#pragma unroll
      for (int n = 0; n < 4; ++n)
        acc[m][n] = __builtin_amdgcn_mfma_f32_16x16x32_bf16(af[m], bfv[n], acc[m][n], 0, 0, 0);
  }

#pragma unroll
  for (int m = 0; m < 4; ++m) {
#pragma unroll
    for (int n = 0; n < 4; ++n) {
      const int r0 = tm * BM + wrow + m * 16 + fq * 4;
      const int c  = tn * BN + wcol + n * 16 + fr;
#pragma unroll
      for (int r = 0; r < 4; ++r) {
        float v = acc[m][n][r];
        long idx = (long)(r0 + r) * N + c;
        if constexpr (sizeof(OutT) == 2) C[idx] = f2bf(v);
        else                             C[idx] = v;
      }
    }
  }
}

// ============ 256x256-tile 8-phase bf16 GEMM: C = A(MxK) @ B(NxK)^T ==========
// QKVT=true: write head-major qkv layout [48][BT][64] instead of [BT][3072].
template <typename OutT, bool QKVT>
__global__ __launch_bounds__(512, 2) void k_gemm256(const u16* __restrict__ A,
                                                    const u16* __restrict__ B,
                                                    OutT* __restrict__ C,
                                                    int M, int N, int K) {
  __shared__ __align__(16) u16 As[2][2][256 * 32];
  __shared__ __align__(16) u16 Bs[2][2][256 * 32];
  const int tid = threadIdx.x;
  const int l = tid & 63, w = tid >> 6;
  const int wm = w >> 2, wn = w & 3;          // 2 x 4 wave grid
  const int fr = l & 15, fq = l >> 4;
  const int nwg = gridDim.x;
  const int cpx = nwg >> 3;
  const int bid = blockIdx.x;
  const int sbid = (bid & 7) * cpx + (bid >> 3);
  const int ntn = N >> 8;
  const int tm = sbid / ntn, tn = sbid - tm * ntn;
  const long a0 = (long)tm * 256 * K;
  const long b0 = (long)tn * 256 * K;
  const int srow0 = tid >> 2;
  const int scol8 = (((tid & 3) ^ ((tid >> 4) & 3)) << 3);
  const int cswz = ((fq ^ ((fr >> 2) & 3)) << 3);
  const int NKT = K >> 6;

  auto stage_half = [&](int kt, int buf, int hf) {
    const int ks = hf >> 1;
    const u16* Gp = (hf & 1) ? B : A;
    const long g0 = ((hf & 1) ? b0 : a0) + (long)kt * 64 + ks * 32 + scol8;
    u16* lb = (hf & 1) ? &Bs[buf][ks][w * 512] : &As[buf][ks][w * 512];
#pragma unroll
    for (int r = 0; r < 2; ++r)
      gload_lds16(Gp + g0 + (long)(r * 128 + srow0) * K, lb + r * 4096);
  };

  f32x4 acc[8][4];
#pragma unroll
  for (int m = 0; m < 8; ++m)
#pragma unroll
    for (int n = 0; n < 4; ++n) acc[m][n] = f32x4{0.f, 0.f, 0.f, 0.f};

  stage_half(0, 0, 0); stage_half(0, 0, 1); stage_half(0, 0, 2); stage_half(0, 0, 3);

  for (int kt = 0; kt < NKT; ++kt) {
    const int bi = kt & 1;
    const bool pf = (kt + 1 < NKT);
    asm volatile("s_waitcnt vmcnt(4)" ::: "memory");
    __builtin_amdgcn_sched_barrier(0);
    __builtin_amdgcn_s_barrier();
    __builtin_amdgcn_sched_barrier(0);
    {
      const u16* ap = &As[bi][0][(wm * 128 + fr) * 32 + cswz];
      const u16* bp = &Bs[bi][0][(wn * 64 + fr) * 32 + cswz];
      bf16x8 bfr[4], afr[4];
#pragma unroll
      for (int n = 0; n < 4; ++n) bfr[n] = *(const bf16x8*)(bp + n * 512);
#pragma unroll
      for (int m = 0; m < 4; ++m) afr[m] = *(const bf16x8*)(ap + m * 512);
      if (pf) stage_half(kt + 1, bi ^ 1, 0);
      __builtin_amdgcn_s_setprio(1);
#pragma unroll
      for (int m = 0; m < 4; ++m)
#pragma unroll
        for (int n = 0; n < 4; ++n)
          acc[m][n] = __builtin_amdgcn_mfma_f32_16x16x32_bf16(afr[m], bfr[n], acc[m][n], 0, 0, 0);
      __builtin_amdgcn_s_setprio(0);
#pragma unroll
      for (int m = 0; m < 4; ++m) afr[m] = *(const bf16x8*)(ap + (4 + m) * 512);
      if (pf) stage_half(kt + 1, bi ^ 1, 1);
      __builtin_amdgcn_s_setprio(1);
#pragma unroll
      for (int m = 0; m < 4; ++m)
#pragma unroll
        for (int n = 0; n < 4; ++n)
          acc[4 + m][n] = __builtin_amdgcn_mfma_f32_16x16x32_bf16(afr[m], bfr[n], acc[4 + m][n], 0, 0, 0);
      __builtin_amdgcn_s_setprio(0);
    }
    if (pf) { asm volatile("s_waitcnt vmcnt(4)" ::: "memory"); }
    else    { asm volatile("s_waitcnt vmcnt(0)" ::: "memory"); }
    __builtin_amdgcn_sched_barrier(0);
    __builtin_amdgcn_s_barrier();
    __builtin_amdgcn_sched_barrier(0);
    {
      const u16* ap = &As[bi][1][(wm * 128 + fr) * 32 + cswz];
      const u16* bp = &Bs[bi][1][(wn * 64 + fr) * 32 + cswz];
      bf16x8 bfr[4], afr[4];
#pragma unroll
      for (int n = 0; n < 4; ++n) bfr[n] = *(const bf16x8*)(bp + n * 512);
#pragma unroll
      for (int m = 0; m < 4; ++m) afr[m] = *(const bf16x8*)(ap + m * 512);
      if (pf) stage_half(kt + 1, bi ^ 1, 2);
      __builtin_amdgcn_s_setprio(1);
#pragma unroll
      for (int m = 0; m < 4; ++m)
#pragma unroll
        for (int n = 0; n < 4; ++n)
          acc[m][n] = __builtin_amdgcn_mfma_f32_16x16x32_bf16(afr[m], bfr[n], acc[m][n], 0, 0, 0);
      __builtin_amdgcn_s_setprio(0);
#pragma unroll
      for (int m = 0; m < 4; ++m) afr[m] = *(const bf16x8*)(ap + (4 + m) * 512);
      if (pf) stage_half(kt + 1, bi ^ 1, 3);
      __builtin_amdgcn_s_setprio(1);
#pragma unroll
      for (int m = 0; m < 4; ++m)
#pragma unroll
        for (int n = 0; n < 4; ++n)
          acc[4 + m][n] = __builtin_amdgcn_mfma_f32_16x16x32_bf16(afr[m], bfr[n], acc[4 + m][n], 0, 0, 0);
      __builtin_amdgcn_s_setprio(0);
    }
  }

#pragma unroll
  for (int m = 0; m < 8; ++m)
#pragma unroll
    for (int n = 0; n < 4; ++n) {
      const int row0 = tm * 256 + wm * 128 + m * 16 + fq * 4;
      const int col  = tn * 256 + wn * 64 + n * 16 + fr;
#pragma unroll
      for (int r = 0; r < 4; ++r) {
        if constexpr (QKVT) {
          const int hb = (tn * 256 + wn * 64) >> 6;
          long idx = ((long)hb * BT + (row0 + r)) * 64 + (n * 16 + fr);
          C[idx] = (OutT)f2bf(acc[m][n][r]);
        } else {
          long idx = (long)(row0 + r) * N + col;
          if constexpr (sizeof(OutT) == 2) C[idx] = f2bf(acc[m][n][r]);
          else                             C[idx] = acc[m][n][r];
        }
      }
    }
}

// ---------------- gate finalize: sigmoid(raw + bias) ----------------
__global__ __launch_bounds__(256) void k_gates_fin(const float* __restrict__ raw,
                                                   const float* __restrict__ bg,
                                                   const float* __restrict__ bb,
                                                   float* __restrict__ alpha,
                                                   float* __restrict__ beta) {
  int i = blockIdx.x * 256 + threadIdx.x;
  if (i >= BT * NH) return;
  int bt = i >> 4, h = i & 15;
  float ga = raw[(long)bt * 128 + h] + bg[h];
  float gb = raw[(long)bt * 128 + 16 + h] + bb[h];
  alpha[i] = 1.f / (1.f + __expf(-ga));
  beta[i]  = 1.f / (1.f + __expf(-gb));
}

// ================= chunked WY scan (MFMA block-solve, fused l2norm) =======
// qkv head-major: per-(h,chunk) q/k/v tiles contiguous 8KB.
// Epilogue: Qeff/G/U/Oi staged in dead LDS, then u16x8 full-line stores to
// 4 contiguous 8KB destinations (fix for partial-line write amplification).
__global__ __launch_bounds__(256, 3) void k_prep(u16* __restrict__ qkv,
                                                 const float* __restrict__ alpha,
                                                 const float* __restrict__ beta,
                                                 float* __restrict__ A63G,
                                                 u16* __restrict__ oi) {
  __shared__ __align__(16) u16 Ks[64 * 64];
  __shared__ __align__(16) u16 WTs[128 * 64];   // rows 0-63: VbT->WvT; 64-127: KbT->TwT
  __shared__ __align__(16) u16 Lb[64 * 64];     // L (b-scaled), later -L~ in 6 sub-blocks
  __shared__ __align__(16) u16 MqS[64 * 64];
  __shared__ __align__(16) u16 KdT[64 * 64];
  __shared__ __align__(16) u16 Db[4 * 16 * DBS];
  __shared__ float cvec[64], Avec[64], bvec[64], nkinv[64], nqinv[64];

  const int unit = blockIdx.x;
  const int pair = unit >> 6, ch = unit & 63;
  const int b = pair >> 4, h = pair & 15;
  const int tid = threadIdx.x, l = tid & 63, w = tid >> 6;
  const int fr = l & 15, fq = l >> 4;
  const long t0 = (long)b * NT + (long)ch * CC;

  // ---- P0: issue global loads into regs (incl. qpre, L2-hot); wave0 cumsum ----
  u16x8 kreg[2], vreg[2], qreg[2];
  int srow_[2], sseg_[2];
#pragma unroll
  for (int p = 0; p < 2; ++p) {
    int idx = p * 256 + tid;
    srow_[p] = idx >> 3; sseg_[p] = (idx & 7) * 8;
    qreg[p] = *(const u16x8*)&qkv[qkvT_idx(0, h, t0 + srow_[p], sseg_[p])];
    kreg[p] = *(const u16x8*)&qkv[qkvT_idx(1, h, t0 + srow_[p], sseg_[p])];
    vreg[p] = *(const u16x8*)&qkv[qkvT_idx(2, h, t0 + srow_[p], sseg_[p])];
  }
  const int ar = w * 16 + fr;
  u16x8 qa[2];
#pragma unroll
  for (int kk = 0; kk < 2; ++kk)
    qa[kk] = *(const u16x8*)&qkv[qkvT_idx(0, h, t0 + ar, kk * 32 + fq * 8)];
  u16 qpre[4][4];
#pragma unroll
  for (int n = 0; n < 4; ++n)
#pragma unroll
    for (int r = 0; r < 4; ++r)
      qpre[n][r] = qkv[qkvT_idx(0, h, t0 + w * 16 + fq * 4 + r, n * 16 + fr)];

  if (w == 0) {
    float av = alpha[(t0 + l) * 16 + h];
    float bv = beta[(t0 + l) * 16 + h];
    float cl = __log2f(av);
#pragma unroll
    for (int d = 1; d < 64; d <<= 1) {
      float up = __shfl_up(cl, d);
      if (l >= d) cl += up;
    }
    float A = exp2f(cl);
    cvec[l] = cl; Avec[l] = A; bvec[l] = bv;
    if (l == 63) A63G[unit] = A;
  }
  __syncthreads();

  // ---- P1: stage Ks rows + VbT (b-scaled, transposed); norms via shuffle ----
#pragma unroll
  for (int p = 0; p < 2; ++p) {
    int row = srow_[p], seg = sseg_[p];
    *(u16x8*)&Ks[row * 64 + swz(row, seg)] = kreg[p];
    float kss = 0.f, qss = 0.f;
    const float bs = bvec[row];
#pragma unroll
    for (int e = 0; e < 8; ++e) {
      float kf = bf2f(kreg[p][e]), qf = bf2f(qreg[p][e]);
      kss += kf * kf; qss += qf * qf;
      int c = seg + e;
      WTs[c * 64 + swz(c, row)] = f2bf(bs * bf2f(vreg[p][e]));
    }
    kss += __shfl_xor(kss, 1); kss += __shfl_xor(kss, 2); kss += __shfl_xor(kss, 4);
    qss += __shfl_xor(qss, 1); qss += __shfl_xor(qss, 2); qss += __shfl_xor(qss, 4);
    if ((tid & 7) == 0) { nkinv[row] = kss; nqinv[row] = qss; }
  }
  __syncthreads();

  // ---- P2: inverse norms ----
  if (tid < 64)       nkinv[tid] = rsqrtf(fmaxf(nkinv[tid], 1e-24f));
  else if (tid < 128) nqinv[tid - 64] = rsqrtf(fmaxf(nqinv[tid - 64], 1e-24f));
  __syncthreads();

  // ---- P3: KK^T + QK^T MFMA; build KbT & KdT; L/Mq epilogue ----
  f32x4 akk[4], aqk[4];
#pragma unroll
  for (int n = 0; n < 4; ++n) { akk[n] = f32x4{0, 0, 0, 0}; aqk[n] = f32x4{0, 0, 0, 0}; }
  {
    bf16x8 afK[2], afQ[2];
#pragma unroll
    for (int kk = 0; kk < 2; ++kk) {
      afK[kk] = __builtin_bit_cast(bf16x8, *(const u16x8*)&Ks[ar * 64 + swz(ar, kk * 32 + fq * 8)]);
      afQ[kk] = __builtin_bit_cast(bf16x8, qa[kk]);
    }
#pragma unroll
    for (int n = 0; n < 4; ++n) {
      const int br = n * 16 + fr;
#pragma unroll
      for (int kk = 0; kk < 2; ++kk) {
        bf16x8 bk = __builtin_bit_cast(bf16x8, *(const u16x8*)&Ks[br * 64 + swz(br, kk * 32 + fq * 8)]);
        akk[n] = __builtin_amdgcn_mfma_f32_16x16x32_bf16(afK[kk], bk, akk[n], 0, 0, 0);
        aqk[n] = __builtin_amdgcn_mfma_f32_16x16x32_bf16(afQ[kk], bk, aqk[n], 0, 0, 0);
      }
    }
  }
  {
    const int j = tid & 63, tg4 = tid >> 6;
    const float c63 = cvec[63];
    u16 kb[16], kd[16];
#pragma unroll
    for (int tt = 0; tt < 16; ++tt) {
      int t = tg4 * 16 + tt;
      float kv = bf2f(Ks[t * 64 + swz(t, j)]) * nkinv[t];
      kb[tt] = f2bf(bvec[t] * Avec[t] * kv);
      kd[tt] = f2bf(exp2f(c63 - cvec[t]) * kv);
    }
#pragma unroll
    for (int g8 = 0; g8 < 2; ++g8) {
      u16x8 o1, o2;
#pragma unroll
      for (int e = 0; e < 8; ++e) { o1[e] = kb[g8 * 8 + e]; o2[e] = kd[g8 * 8 + e]; }
      int colg = tg4 * 16 + g8 * 8;
      *(u16x8*)&WTs[(64 + j) * 64 + swz(64 + j, colg)] = o1;
      *(u16x8*)&KdT[j * 64 + swz(j, colg)] = o2;
    }
  }
#pragma unroll
  for (int n = 0; n < 4; ++n)
#pragma unroll
    for (int r = 0; r < 4; ++r) {
      const int t = w * 16 + fq * 4 + r;
      const int s = n * 16 + fr;
      const float e = exp2f(cvec[t] - cvec[s]);
      Lb[t * 64 + swz(t, s)] = (s < t) ? f2bf(bvec[t] * e * nkinv[t] * nkinv[s] * akk[n][r]) : (u16)0;
      MqS[t * 64 + swz(t, s)] = (s <= t) ? f2bf(e * nqinv[t] * nkinv[s] * aqk[n][r]) : (u16)0;
    }
  __syncthreads();

  // ---- P4: Dinv of the 4 diagonal 16x16 blocks (wave w owns block w) ----
  if (l < 16) {
    const int c = l;
    const int rb = w * 16;
    float x[16];
#pragma unroll
    for (int u = 0; u < 16; ++u) {
      float a2 = (u == c) ? 1.f : 0.f;
#pragma unroll
      for (int s = 0; s < u; ++s)
        a2 -= bf2f(Lb[(rb + u) * 64 + swz(rb + u, rb + s)]) * x[s];
      x[u] = a2;
    }
#pragma unroll
    for (int u = 0; u < 16; ++u)
      Db[w * 16 * DBS + u * DBS + c] = f2bf(x[u]);
  }
  __syncthreads();

  // ---- P5: L~ = Dinv.L (scalar, store NEGATED); R~T = RT.DinvT (MFMA) ----
  float ltil[6];
  {
    const int pbi[6] = {1, 2, 2, 3, 3, 3}, pbj[6] = {0, 0, 1, 0, 1, 2};
    const int tt = tid >> 4, s = tid & 15;
#pragma unroll
    for (int e = 0; e < 6; ++e) {
      int bi = pbi[e], bj = pbj[e];
      float a2 = 0.f;
#pragma unroll
      for (int u = 0; u < 16; ++u)
        a2 += bf2f(Db[bi * 16 * DBS + tt * DBS + u]) *
              bf2f(Lb[(bi * 16 + u) * 64 + swz(bi * 16 + u, bj * 16 + s)]);
      ltil[e] = a2;
    }
  }
  f32x4 rtacc[2][4];
#pragma unroll
  for (int rt2 = 0; rt2 < 2; ++rt2) {
    const int rrow = (w * 2 + rt2) * 16 + fr;
#pragma unroll
    for (int bi = 0; bi < 4; ++bi) {
      bf16x8 a2 = (fq < 2)
        ? __builtin_bit_cast(bf16x8, *(const u16x8*)&WTs[rrow * 64 + swz(rrow, bi * 16 + fq * 8)])
        : zfrag();
      bf16x8 b2 = (fq < 2)
        ? __builtin_bit_cast(bf16x8, *(const u16x8*)&Db[bi * 16 * DBS + fr * DBS + fq * 8])
        : zfrag();
      rtacc[rt2][bi] = __builtin_amdgcn_mfma_f32_16x16x32_bf16(a2, b2, f32x4{0, 0, 0, 0}, 0, 0, 0);
    }
  }
  __syncthreads();   // all L~/R~ reads done before overwrites
  {
    const int pbi[6] = {1, 2, 2, 3, 3, 3}, pbj[6] = {0, 0, 1, 0, 1, 2};
    const int tt = tid >> 4, s = tid & 15;
#pragma unroll
    for (int e = 0; e < 6; ++e)
      Lb[(pbi[e] * 16 + tt) * 64 + swz(pbi[e] * 16 + tt, pbj[e] * 16 + s)] = f2bf(-ltil[e]);
  }
#pragma unroll
  for (int rt2 = 0; rt2 < 2; ++rt2)
#pragma unroll
    for (int bi = 0; bi < 4; ++bi)
#pragma unroll
      for (int r = 0; r < 4; ++r) {
        int rr = (w * 2 + rt2) * 16 + fq * 4 + r;
        WTs[rr * 64 + swz(rr, bi * 16 + fr)] = f2bf(rtacc[rt2][bi][r]);
      }
  __syncthreads();

  // ---- P6: 3-step MFMA substitution (row-tiles wave-exclusive, no barriers) ----
#pragma unroll
  for (int rt2 = 0; rt2 < 2; ++rt2) {
    const int rrow = (w * 2 + rt2) * 16 + fr;
    const int wr0 = (w * 2 + rt2) * 16 + fq * 4;
#pragma unroll
    for (int i = 1; i < 4; ++i) {
      f32x4 a2;
#pragma unroll
      for (int r = 0; r < 4; ++r)
        a2[r] = bf2f(WTs[(wr0 + r) * 64 + swz(wr0 + r, i * 16 + fr)]);
      {
        bf16x8 af = __builtin_bit_cast(bf16x8, *(const u16x8*)&WTs[rrow * 64 + swz(rrow, fq * 8)]);
        bf16x8 bf_;
        if (i == 1) bf_ = (fq < 2)
          ? __builtin_bit_cast(bf16x8, *(const u16x8*)&Lb[(16 + fr) * 64 + swz(16 + fr, fq * 8)])
          : zfrag();
        else bf_ = __builtin_bit_cast(bf16x8, *(const u16x8*)&Lb[(i * 16 + fr) * 64 + swz(i * 16 + fr, fq * 8)]);
        a2 = __builtin_amdgcn_mfma_f32_16x16x32_bf16(af, bf_, a2, 0, 0, 0);
      }
      if (i == 3) {
        bf16x8 af = __builtin_bit_cast(bf16x8, *(const u16x8*)&WTs[rrow * 64 + swz(rrow, 32 + fq * 8)]);
        bf16x8 bf_ = (fq < 2)
          ? __builtin_bit_cast(bf16x8, *(const u16x8*)&Lb[(48 + fr) * 64 + swz(48 + fr, 32 + fq * 8)])
          : zfrag();
        a2 = __builtin_amdgcn_mfma_f32_16x16x32_bf16(af, bf_, a2, 0, 0, 0);
      }
#pragma unroll
      for (int r = 0; r < 4; ++r)
        WTs[(wr0 + r) * 64 + swz(wr0 + r, i * 16 + fr)] = f2bf(a2[r]);
    }
  }
  __syncthreads();

  // ---- P7: final 4 GEMMs ----
  f32x4 aG[4], aU[4], aQe[4], aOi[4];
#pragma unroll
  for (int n = 0; n < 4; ++n) {
    aG[n] = f32x4{0, 0, 0, 0}; aU[n] = f32x4{0, 0, 0, 0};
    aQe[n] = f32x4{0, 0, 0, 0}; aOi[n] = f32x4{0, 0, 0, 0};
  }
  {
    bf16x8 aKd[2], aWv[2], aMq[2];
#pragma unroll
    for (int kk = 0; kk < 2; ++kk) {
      aKd[kk] = __builtin_bit_cast(bf16x8, *(const u16x8*)&KdT[ar * 64 + swz(ar, kk * 32 + fq * 8)]);
      aWv[kk] = __builtin_bit_cast(bf16x8, *(const u16x8*)&WTs[ar * 64 + swz(ar, kk * 32 + fq * 8)]);
      aMq[kk] = __builtin_bit_cast(bf16x8, *(const u16x8*)&MqS[ar * 64 + swz(ar, kk * 32 + fq * 8)]);
    }
#pragma unroll
    for (int n = 0; n < 4; ++n) {
      const int br = n * 16 + fr;
#pragma unroll
      for (int kk = 0; kk < 2; ++kk) {
        bf16x8 bTw = __builtin_bit_cast(bf16x8, *(const u16x8*)&WTs[(64 + br) * 64 + swz(64 + br, kk * 32 + fq * 8)]);
        bf16x8 bKd = __builtin_bit_cast(bf16x8, *(const u16x8*)&KdT[br * 64 + swz(br, kk * 32 + fq * 8)]);
        bf16x8 bWv = __builtin_bit_cast(bf16x8, *(const u16x8*)&WTs[br * 64 + swz(br, kk * 32 + fq * 8)]);
        aG[n]  = __builtin_amdgcn_mfma_f32_16x16x32_bf16(aKd[kk], bTw, aG[n], 0, 0, 0);
        aU[n]  = __builtin_amdgcn_mfma_f32_16x16x32_bf16(aWv[kk], bKd, aU[n], 0, 0, 0);
        aQe[n] = __builtin_amdgcn_mfma_f32_16x16x32_bf16(aMq[kk], bTw, aQe[n], 0, 0, 0);
        aOi[n] = __builtin_amdgcn_mfma_f32_16x16x32_bf16(aMq[kk], bWv, aOi[n], 0, 0, 0);
      }
    }
  }
  // ---- P8: stage into dead LDS (pre-swz values, linear pos), full-line store ----
  __syncthreads();   // all P7 LDS reads done before overwrite
#pragma unroll
  for (int n = 0; n < 4; ++n)
#pragma unroll
    for (int r = 0; r < 4; ++r) {
      const int i = w * 16 + fq * 4 + r;
      const int cn = n * 16 + fr;
      const int sw = i * 64 + swz(i, cn);
      Ks[sw]  = f2bf(Avec[i] * nqinv[i] * bf2f(qpre[n][r]) - aQe[n][r]);  // Qeff
      Lb[sw]  = f2bf(-aG[n][r]);                                          // G
      MqS[sw] = f2bf(aU[n][r]);                                           // U
      KdT[i * 64 + cn] = f2bf(aOi[n][r]);                                 // O_intra (linear)
    }
  __syncthreads();
#pragma unroll
  for (int p = 0; p < 2; ++p) {
    const int idx = p * 256 + tid;
    const int row = idx >> 3, seg = (idx & 7) * 8;
    *(u16x8*)&qkv[qkvT_idx(0, h, t0 + row, seg)] = *(const u16x8*)&Ks[row * 64 + seg];
    *(u16x8*)&qkv[qkvT_idx(1, h, t0 + row, seg)] = *(const u16x8*)&Lb[row * 64 + seg];
    *(u16x8*)&qkv[qkvT_idx(2, h, t0 + row, seg)] = *(const u16x8*)&MqS[row * 64 + seg];
    *(u16x8*)&oi[(long)unit * 4096 + row * 64 + seg] = *(const u16x8*)&KdT[row * 64 + seg];
  }
}

// ---------------- sequential chunk recurrence (double-buffered async staging) --
__global__ __launch_bounds__(256) void k_seq(const u16* __restrict__ qkv,
                                             const u16* __restrict__ oi,
                                             const float* __restrict__ A63G,
                                             u16* __restrict__ ob) {
  __shared__ __align__(16) u16 Sb[64 * 64];
  __shared__ __align__(16) u16 Obs[64 * 64];         // O writeout staging
  __shared__ __align__(16) u16 stg[2][4][64 * 64];   // [buf][Qe,G,U,Oi][..]
  __shared__ float a63s[64];
  const int pair = blockIdx.x;
  const int b = pair >> 4, h = pair & 15;
  const int tid = threadIdx.x, l = tid & 63, w = tid >> 6;
  const int fr = l & 15, fq = l >> 4;
  const int ar = w * 16 + fr;

  auto stage = [&](int c, int bi) {
    const long tg = (long)b * NT + (long)c * CC;
#pragma unroll
    for (int m = 0; m < 4; ++m)
#pragma unroll
      for (int p = 0; p < 2; ++p) {
        int idx = p * 256 + tid;
        int row = idx >> 3, seg = (idx & 7) * 8;
        const u16* src = (m < 3)
          ? &qkv[qkvT_idx(m, h, tg + row, seg)]
          : &oi[(long)(pair * 64 + c) * 4096 + row * 64 + seg];
        gload_lds16(src, &stg[bi][m][p * 2048 + w * 512]);
      }
  };

  if (tid < 64) a63s[tid] = A63G[pair * 64 + tid];
  for (int i = tid; i < 4096; i += 256) Sb[i] = 0;
  stage(0, 0);
  f32x4 sacc[4];
#pragma unroll
  for (int n = 0; n < 4; ++n) sacc[n] = f32x4{0, 0, 0, 0};
  asm volatile("s_waitcnt lgkmcnt(0)" ::: "memory");
  __builtin_amdgcn_sched_barrier(0);

  for (int c = 0; c < NCH; ++c) {
    const int bi = c & 1;
    const long tg = (long)b * NT + (long)c * CC;
    if (c + 1 < NCH) {
      stage(c + 1, bi ^ 1);
      asm volatile("s_waitcnt vmcnt(8)" ::: "memory");
    } else {
      asm volatile("s_waitcnt vmcnt(0)" ::: "memory");
    }
    __builtin_amdgcn_sched_barrier(0);
    __builtin_amdgcn_s_barrier();
    __builtin_amdgcn_sched_barrier(0);

    const u16* Qe = stg[bi][0];
    const u16* Gm = stg[bi][1];
    const u16* Um = stg[bi][2];
    const u16* Obl = stg[bi][3];

    // O_cross[t][d] = sum_j Qeff[t][j] S[d][j]
    bf16x8 aq[2];
#pragma unroll
    for (int kk = 0; kk < 2; ++kk)
      aq[kk] = __builtin_bit_cast(bf16x8, *(const u16x8*)&Qe[ar * 64 + swz(ar, kk * 32 + fq * 8)]);
    f32x4 ao[4];
#pragma unroll
    for (int n = 0; n < 4; ++n) ao[n] = f32x4{0, 0, 0, 0};
#pragma unroll
    for (int n = 0; n < 4; ++n) {
      const int br = n * 16 + fr;
#pragma unroll
      for (int kk = 0; kk < 2; ++kk) {
        bf16x8 sb = __builtin_bit_cast(bf16x8, *(const u16x8*)&Sb[br * 64 + swz(br, kk * 32 + fq * 8)]);
        ao[n] = __builtin_amdgcn_mfma_f32_16x16x32_bf16(aq[kk], sb, ao[n], 0, 0, 0);
      }
    }
    // S update: sacc = A63*sacc + S.G (+U below)
    bf16x8 as_[2];
#pragma unroll
    for (int kk = 0; kk < 2; ++kk)
      as_[kk] = __builtin_bit_cast(bf16x8, *(const u16x8*)&Sb[ar * 64 + swz(ar, kk * 32 + fq * 8)]);
    const float A63 = a63s[c];
#pragma unroll
    for (int n = 0; n < 4; ++n) {
#pragma unroll
      for (int r = 0; r < 4; ++r) sacc[n][r] *= A63;
      const int br = n * 16 + fr;
#pragma unroll
      for (int kk = 0; kk < 2; ++kk) {
        bf16x8 g = __builtin_bit_cast(bf16x8, *(const u16x8*)&Gm[br * 64 + swz(br, kk * 32 + fq * 8)]);
        sacc[n] = __builtin_amdgcn_mfma_f32_16x16x32_bf16(as_[kk], g, sacc[n], 0, 0, 0);
      }
    }
    // +U, O -> Obs staging
#pragma unroll
    for (int n = 0; n < 4; ++n)
#pragma unroll
      for (int r = 0; r < 4; ++r) {
        const int i = w * 16 + fq * 4 + r;
        const int cn = n * 16 + fr;
        sacc[n][r] += bf2f(Um[i * 64 + swz(i, cn)]);
        Obs[i * 64 + cn] = f2bf(bf2f(Obl[i * 64 + cn]) + ao[n][r]);
      }
    asm volatile("s_waitcnt lgkmcnt(0)" ::: "memory");
    __builtin_amdgcn_s_barrier();   // all waves done reading Sb; Obs visible
#pragma unroll
    for (int n = 0; n < 4; ++n)
#pragma unroll
      for (int r = 0; r < 4; ++r) {
        const int d = w * 16 + fq * 4 + r, j = n * 16 + fr;
        Sb[d * 64 + swz(d, j)] = f2bf(sacc[n][r]);
      }
    // vectorized O writeout (full 128B rows)
#pragma unroll
    for (int p = 0; p < 2; ++p) {
      const int idx = p * 256 + tid;
      const int row = idx >> 3, seg = (idx & 7) * 8;
      *(u16x8*)&ob[(tg + row) * 1024 + h * 64 + seg] = *(const u16x8*)&Obs[row * 64 + seg];
    }
    asm volatile("s_waitcnt lgkmcnt(0)" ::: "memory");
    __builtin_amdgcn_sched_barrier(0);
  }
}

extern "C" void kernel_launch(void* const* d_in, const int* in_sizes, int n_in,
                              void* d_out, int out_size, void* d_ws, size_t ws_size,
                              hipStream_t stream) {
  const float* x    = (const float*)d_in[0];
  const float* Wqkv = (const float*)d_in[1];
  const float* Wg   = (const float*)d_in[2];
  const float* bg   = (const float*)d_in[3];
  const float* Wb   = (const float*)d_in[4];
  const float* bb   = (const float*)d_in[5];
  const float* Wout = (const float*)d_in[6];
  float* out = (float*)d_out;

  char* ws = (char*)d_ws;
  u16* xb    = (u16*)ws;                               // 16384*1024   (32MB)
  u16* wqkvb = xb    + (long)BT * NDIM;                // 3072*1024    (6MB)
  u16* woutb = wqkvb + (long)3072 * 1024;              // 1024*1024    (2MB)
  u16* wgbb  = woutb + (long)1024 * 1024;              // 128*1024
  u16* qkvb  = wgbb  + (long)128 * 1024;               // [48][BT][64] (96MB)
  u16* ob    = qkvb  + (long)BT * 3072;                // 16384*1024   (32MB)
  float* graw  = (float*)(ob + (long)BT * NDIM);       // 16384*128    (8MB)
  float* alpha = graw + (long)BT * 128;                // 16384*16     (1MB)
  float* beta  = alpha + (long)BT * NH;                // 16384*16     (1MB)
  float* A63G  = graw;   // reuse: graw dead after k_gates_fin (needs 16KB)
  u16*   oi    = xb;     // reuse: xb dead after gates GEMM; NU*4096 u16 = 32MB exact

  // 1. converts
  k_f32_to_bf16<<<(BT * (long)NDIM / 4 + 255) / 256, 256, 0, stream>>>(x, xb, BT * (long)NDIM / 4);
  k_f32_to_bf16<<<(3072L * 1024 / 4 + 255) / 256, 256, 0, stream>>>(Wqkv, wqkvb, 3072L * 1024 / 4);
  k_f32_to_bf16<<<(1024L * 1024 / 4 + 255) / 256, 256, 0, stream>>>(Wout, woutb, 1024L * 1024 / 4);
  k_build_wgb<<<(128 * 1024) / 256, 256, 0, stream>>>(Wg, Wb, wgbb);

  // 2. qkv GEMM (256^2 8-phase, head-major output)
  k_gemm256<u16, true><<<64 * 12, 512, 0, stream>>>(xb, wqkvb, qkvb, BT, 3072, NDIM);

  // 3. gates GEMM (N=128, old path) + finalize
  k_gemm_bt<float><<<dim3(1, BT / 128), 256, 0, stream>>>(xb, wgbb, graw, BT, 128, NDIM);
  k_gates_fin<<<(BT * NH + 255) / 256, 256, 0, stream>>>(graw, bg, bb, alpha, beta);

  // 4. chunked WY: parallel precompute + sequential chunk GEMMs
  k_prep<<<NU, 256, 0, stream>>>(qkvb, alpha, beta, A63G, oi);
  k_seq<<<NPAIR, 256, 0, stream>>>(qkvb, oi, A63G, ob);

  // 5. out GEMM (256^2 8-phase): 16384x1024 = ob @ woutb^T (fp32 out)
  k_gemm256<float, false><<<64 * 4, 512, 0, stream>>>(ob, woutb, out, BT, NDIM, NDIM);
}

// Round 10
// 421.169 us; speedup vs baseline: 1.1545x; 1.1545x over previous
//
#include <hip/hip_runtime.h>
#include <hip/hip_bf16.h>

// Problem constants
#define NB   4
#define NT   4096
#define BT   16384   // NB*NT
#define NDIM 1024
#define NH   16
#define NDH  64
#define CC   64              // chunk size (time steps)
#define NCH  (NT / CC)       // 64 chunks per pair
#define NPAIR 64             // B*H
#define NU   (NPAIR * NCH)   // 4096 units
#define DBS  24              // Db row stride (u16 elems), padded for banks

using u16 = unsigned short;
typedef __bf16 bf16x8 __attribute__((ext_vector_type(8)));
typedef float f32x4 __attribute__((ext_vector_type(4)));
typedef unsigned short u16x8 __attribute__((ext_vector_type(8)));
typedef unsigned short u16x4 __attribute__((ext_vector_type(4)));

__device__ __forceinline__ float bf2f(u16 b) { return __uint_as_float(((unsigned)b) << 16); }
__device__ __forceinline__ u16 f2bf(float f) {
  return __builtin_bit_cast(u16, __float2bfloat16(f));
}
// LDS row swizzle (u16-element index, 8-elem granular): breaks stride-128B bank conflicts
__device__ __forceinline__ int swz(int row, int e) { return e ^ ((row & 7) << 3); }
__device__ __forceinline__ bf16x8 zfrag() {
  u16x8 z = {0, 0, 0, 0, 0, 0, 0, 0};
  return __builtin_bit_cast(bf16x8, z);
}
// head-major qkv layout: [slot(3)][head(16)][bt(BT)][d(64)] — per-(h,chunk) tile contiguous
__device__ __forceinline__ long qkvT_idx(int s, int h, long bt, int d) {
  return ((long)(s * 16 + h) * BT + bt) * 64 + d;
}

// ---------------- convert fp32 -> bf16 (vectorized) ----------------
__global__ __launch_bounds__(256) void k_f32_to_bf16(const float* __restrict__ in,
                                                     u16* __restrict__ out, long n4) {
  long i = (long)blockIdx.x * blockDim.x + threadIdx.x;
  if (i >= n4) return;
  float4 f = reinterpret_cast<const float4*>(in)[i];
  u16x4 o;
  o.x = f2bf(f.x); o.y = f2bf(f.y); o.z = f2bf(f.z); o.w = f2bf(f.w);
  reinterpret_cast<u16x4*>(out)[i] = o;
}

// ---------------- build padded gate weight matrix (128 x 1024 bf16) ----------------
__global__ __launch_bounds__(256) void k_build_wgb(const float* __restrict__ Wg,
                                                   const float* __restrict__ Wb,
                                                   u16* __restrict__ out) {
  int i = blockIdx.x * 256 + threadIdx.x;
  int row = i >> 10, col = i & 1023;
  float f = 0.f;
  if (row < 16)       f = Wg[row * 1024 + col];
  else if (row < 32)  f = Wb[(row - 16) * 1024 + col];
  out[i] = f2bf(f);
}

// ---------------- global_load_lds helper ----------------
typedef unsigned int u32_as1 __attribute__((address_space(1)));
typedef unsigned int u32_as3 __attribute__((address_space(3)));
__device__ __forceinline__ void gload_lds16(const void* g, void* l) {
  __builtin_amdgcn_global_load_lds((const u32_as1*)g, (u32_as3*)l, 16, 0, 0);
}

// ---------------- bf16 GEMM (small-N path): C(MxN) = A(MxK) @ B(NxK)^T -------
template <typename OutT>
__global__ __launch_bounds__(256) void k_gemm_bt(const u16* __restrict__ A,
                                                 const u16* __restrict__ B,
                                                 OutT* __restrict__ C,
                                                 int M, int N, int K) {
  constexpr int BM = 128, BN = 128, BK = 32;
  __shared__ __align__(16) u16 As[BM * BK];
  __shared__ __align__(16) u16 Bs[BN * BK];
  const int tid = threadIdx.x;
  const int l = tid & 63, w = tid >> 6;
  const int tn = blockIdx.x, tm = blockIdx.y;
  const long a0 = (long)tm * BM * K;
  const long b0 = (long)tn * BN * K;
  const int srow = tid >> 2;
  const int scol = (tid & 3) << 3;
  const int wrow = (w >> 1) << 6;
  const int wcol = (w & 1) << 6;
  const int fr = l & 15, fq = l >> 4;

  f32x4 acc[4][4];
#pragma unroll
  for (int m = 0; m < 4; ++m)
#pragma unroll
    for (int n = 0; n < 4; ++n) acc[m][n] = f32x4{0.f, 0.f, 0.f, 0.f};

  for (int kk = 0; kk < K; kk += BK) {
    __syncthreads();
    const u16* gA = A + a0 + (long)srow * K + kk + scol;
    const u16* gB = B + b0 + (long)srow * K + kk + scol;
    gload_lds16(gA,                &As[(w * 16) * BK]);
    gload_lds16(gA + 64 * (long)K, &As[(64 + w * 16) * BK]);
    gload_lds16(gB,                &Bs[(w * 16) * BK]);
    gload_lds16(gB + 64 * (long)K, &Bs[(64 + w * 16) * BK]);
    __syncthreads();

    bf16x8 af[4], bfv[4];
#pragma unroll
    for (int m = 0; m < 4; ++m)
      af[m] = *(const bf16x8*)&As[(wrow + m * 16 + fr) * BK + (fq << 3)];
#pragma unroll
    for (int n = 0; n < 4; ++n)
      bfv[n] = *(const bf16x8*)&Bs[(wcol + n * 16 + fr) * BK + (fq << 3)];
#pragma unroll
    for (int m = 0; m < 4; ++m)
#pragma unroll
      for (int n = 0; n < 4; ++n)
        acc[m][n] = __builtin_amdgcn_mfma_f32_16x16x32_bf16(af[m], bfv[n], acc[m][n], 0, 0, 0);
  }

#pragma unroll
  for (int m = 0; m < 4; ++m) {
#pragma unroll
    for (int n = 0; n < 4; ++n) {
      const int r0 = tm * BM + wrow + m * 16 + fq * 4;
      const int c  = tn * BN + wcol + n * 16 + fr;
#pragma unroll
      for (int r = 0; r < 4; ++r) {
        float v = acc[m][n][r];
        long idx = (long)(r0 + r) * N + c;
        if constexpr (sizeof(OutT) == 2) C[idx] = f2bf(v);
        else                             C[idx] = v;
      }
    }
  }
}

// ============ 256x256-tile 8-phase bf16 GEMM: C = A(MxK) @ B(NxK)^T ==========
// QKVT=true: write head-major qkv layout [48][BT][64] instead of [BT][3072].
template <typename OutT, bool QKVT>
__global__ __launch_bounds__(512, 2) void k_gemm256(const u16* __restrict__ A,
                                                    const u16* __restrict__ B,
                                                    OutT* __restrict__ C,
                                                    int M, int N, int K) {
  __shared__ __align__(16) u16 As[2][2][256 * 32];
  __shared__ __align__(16) u16 Bs[2][2][256 * 32];
  const int tid = threadIdx.x;
  const int l = tid & 63, w = tid >> 6;
  const int wm = w >> 2, wn = w & 3;          // 2 x 4 wave grid
  const int fr = l & 15, fq = l >> 4;
  const int nwg = gridDim.x;
  const int cpx = nwg >> 3;
  const int bid = blockIdx.x;
  const int sbid = (bid & 7) * cpx + (bid >> 3);
  const int ntn = N >> 8;
  const int tm = sbid / ntn, tn = sbid - tm * ntn;
  const long a0 = (long)tm * 256 * K;
  const long b0 = (long)tn * 256 * K;
  const int srow0 = tid >> 2;
  const int scol8 = (((tid & 3) ^ ((tid >> 4) & 3)) << 3);
  const int cswz = ((fq ^ ((fr >> 2) & 3)) << 3);
  const int NKT = K >> 6;

  auto stage_half = [&](int kt, int buf, int hf) {
    const int ks = hf >> 1;
    const u16* Gp = (hf & 1) ? B : A;
    const long g0 = ((hf & 1) ? b0 : a0) + (long)kt * 64 + ks * 32 + scol8;
    u16* lb = (hf & 1) ? &Bs[buf][ks][w * 512] : &As[buf][ks][w * 512];
#pragma unroll
    for (int r = 0; r < 2; ++r)
      gload_lds16(Gp + g0 + (long)(r * 128 + srow0) * K, lb + r * 4096);
  };

  f32x4 acc[8][4];
#pragma unroll
  for (int m = 0; m < 8; ++m)
#pragma unroll
    for (int n = 0; n < 4; ++n) acc[m][n] = f32x4{0.f, 0.f, 0.f, 0.f};

  stage_half(0, 0, 0); stage_half(0, 0, 1); stage_half(0, 0, 2); stage_half(0, 0, 3);

  for (int kt = 0; kt < NKT; ++kt) {
    const int bi = kt & 1;
    const bool pf = (kt + 1 < NKT);
    asm volatile("s_waitcnt vmcnt(4)" ::: "memory");
    __builtin_amdgcn_sched_barrier(0);
    __builtin_amdgcn_s_barrier();
    __builtin_amdgcn_sched_barrier(0);
    {
      const u16* ap = &As[bi][0][(wm * 128 + fr) * 32 + cswz];
      const u16* bp = &Bs[bi][0][(wn * 64 + fr) * 32 + cswz];
      bf16x8 bfr[4], afr[4];
#pragma unroll
      for (int n = 0; n < 4; ++n) bfr[n] = *(const bf16x8*)(bp + n * 512);
#pragma unroll
      for (int m = 0; m < 4; ++m) afr[m] = *(const bf16x8*)(ap + m * 512);
      if (pf) stage_half(kt + 1, bi ^ 1, 0);
      __builtin_amdgcn_s_setprio(1);
#pragma unroll
      for (int m = 0; m < 4; ++m)
#pragma unroll
        for (int n = 0; n < 4; ++n)
          acc[m][n] = __builtin_amdgcn_mfma_f32_16x16x32_bf16(afr[m], bfr[n], acc[m][n], 0, 0, 0);
      __builtin_amdgcn_s_setprio(0);
#pragma unroll
      for (int m = 0; m < 4; ++m) afr[m] = *(const bf16x8*)(ap + (4 + m) * 512);
      if (pf) stage_half(kt + 1, bi ^ 1, 1);
      __builtin_amdgcn_s_setprio(1);
#pragma unroll
      for (int m = 0; m < 4; ++m)
#pragma unroll
        for (int n = 0; n < 4; ++n)
          acc[4 + m][n] = __builtin_amdgcn_mfma_f32_16x16x32_bf16(afr[m], bfr[n], acc[4 + m][n], 0, 0, 0);
      __builtin_amdgcn_s_setprio(0);
    }
    if (pf) { asm volatile("s_waitcnt vmcnt(4)" ::: "memory"); }
    else    { asm volatile("s_waitcnt vmcnt(0)" ::: "memory"); }
    __builtin_amdgcn_sched_barrier(0);
    __builtin_amdgcn_s_barrier();
    __builtin_amdgcn_sched_barrier(0);
    {
      const u16* ap = &As[bi][1][(wm * 128 + fr) * 32 + cswz];
      const u16* bp = &Bs[bi][1][(wn * 64 + fr) * 32 + cswz];
      bf16x8 bfr[4], afr[4];
#pragma unroll
      for (int n = 0; n < 4; ++n) bfr[n] = *(const bf16x8*)(bp + n * 512);
#pragma unroll
      for (int m = 0; m < 4; ++m) afr[m] = *(const bf16x8*)(ap + m * 512);
      if (pf) stage_half(kt + 1, bi ^ 1, 2);
      __builtin_amdgcn_s_setprio(1);
#pragma unroll
      for (int m = 0; m < 4; ++m)
#pragma unroll
        for (int n = 0; n < 4; ++n)
          acc[m][n] = __builtin_amdgcn_mfma_f32_16x16x32_bf16(afr[m], bfr[n], acc[m][n], 0, 0, 0);
      __builtin_amdgcn_s_setprio(0);
#pragma unroll
      for (int m = 0; m < 4; ++m) afr[m] = *(const bf16x8*)(ap + (4 + m) * 512);
      if (pf) stage_half(kt + 1, bi ^ 1, 3);
      __builtin_amdgcn_s_setprio(1);
#pragma unroll
      for (int m = 0; m < 4; ++m)
#pragma unroll
        for (int n = 0; n < 4; ++n)
          acc[4 + m][n] = __builtin_amdgcn_mfma_f32_16x16x32_bf16(afr[m], bfr[n], acc[4 + m][n], 0, 0, 0);
      __builtin_amdgcn_s_setprio(0);
    }
  }

#pragma unroll
  for (int m = 0; m < 8; ++m)
#pragma unroll
    for (int n = 0; n < 4; ++n) {
      const int row0 = tm * 256 + wm * 128 + m * 16 + fq * 4;
      const int col  = tn * 256 + wn * 64 + n * 16 + fr;
#pragma unroll
      for (int r = 0; r < 4; ++r) {
        if constexpr (QKVT) {
          const int hb = (tn * 256 + wn * 64) >> 6;
          long idx = ((long)hb * BT + (row0 + r)) * 64 + (n * 16 + fr);
          C[idx] = (OutT)f2bf(acc[m][n][r]);
        } else {
          long idx = (long)(row0 + r) * N + col;
          if constexpr (sizeof(OutT) == 2) C[idx] = f2bf(acc[m][n][r]);
          else                             C[idx] = acc[m][n][r];
        }
      }
    }
}

// ---------------- gate finalize: sigmoid(raw + bias) ----------------
__global__ __launch_bounds__(256) void k_gates_fin(const float* __restrict__ raw,
                                                   const float* __restrict__ bg,
                                                   const float* __restrict__ bb,
                                                   float* __restrict__ alpha,
                                                   float* __restrict__ beta) {
  int i = blockIdx.x * 256 + threadIdx.x;
  if (i >= BT * NH) return;
  int bt = i >> 4, h = i & 15;
  float ga = raw[(long)bt * 128 + h] + bg[h];
  float gb = raw[(long)bt * 128 + 16 + h] + bb[h];
  alpha[i] = 1.f / (1.f + __expf(-ga));
  beta[i]  = 1.f / (1.f + __expf(-gb));
}

// ================= chunked WY scan (MFMA block-solve, fused l2norm) =======
// REVERTED to the R8 (123us) version: scattered qkv-slot stores inline in the
// epilogue, qpre loaded in P7, O_intra via dead-Ks staging to contiguous oi.
__global__ __launch_bounds__(256, 3) void k_prep(u16* __restrict__ qkv,
                                                 const float* __restrict__ alpha,
                                                 const float* __restrict__ beta,
                                                 float* __restrict__ A63G,
                                                 u16* __restrict__ oi) {
  __shared__ __align__(16) u16 Ks[64 * 64];
  __shared__ __align__(16) u16 WTs[128 * 64];   // rows 0-63: VbT->WvT; 64-127: KbT->TwT
  __shared__ __align__(16) u16 Lb[64 * 64];     // L (b-scaled), later -L~ in 6 sub-blocks
  __shared__ __align__(16) u16 MqS[64 * 64];
  __shared__ __align__(16) u16 KdT[64 * 64];
  __shared__ __align__(16) u16 Db[4 * 16 * DBS];
  __shared__ float cvec[64], Avec[64], bvec[64], nkinv[64], nqinv[64];

  const int unit = blockIdx.x;
  const int pair = unit >> 6, ch = unit & 63;
  const int b = pair >> 4, h = pair & 15;
  const int tid = threadIdx.x, l = tid & 63, w = tid >> 6;
  const int fr = l & 15, fq = l >> 4;
  const long t0 = (long)b * NT + (long)ch * CC;

  // ---- P0: issue global loads into regs; wave0 cumsum ----
  u16x8 kreg[2], vreg[2], qreg[2];
  int srow_[2], sseg_[2];
#pragma unroll
  for (int p = 0; p < 2; ++p) {
    int idx = p * 256 + tid;
    srow_[p] = idx >> 3; sseg_[p] = (idx & 7) * 8;
    qreg[p] = *(const u16x8*)&qkv[qkvT_idx(0, h, t0 + srow_[p], sseg_[p])];
    kreg[p] = *(const u16x8*)&qkv[qkvT_idx(1, h, t0 + srow_[p], sseg_[p])];
    vreg[p] = *(const u16x8*)&qkv[qkvT_idx(2, h, t0 + srow_[p], sseg_[p])];
  }
  const int ar = w * 16 + fr;
  u16x8 qa[2];
#pragma unroll
  for (int kk = 0; kk < 2; ++kk)
    qa[kk] = *(const u16x8*)&qkv[qkvT_idx(0, h, t0 + ar, kk * 32 + fq * 8)];

  if (w == 0) {
    float av = alpha[(t0 + l) * 16 + h];
    float bv = beta[(t0 + l) * 16 + h];
    float cl = __log2f(av);
#pragma unroll
    for (int d = 1; d < 64; d <<= 1) {
      float up = __shfl_up(cl, d);
      if (l >= d) cl += up;
    }
    float A = exp2f(cl);
    cvec[l] = cl; Avec[l] = A; bvec[l] = bv;
    if (l == 63) A63G[unit] = A;
  }
  __syncthreads();

  // ---- P1: stage Ks rows + VbT (b-scaled, transposed); norms via shuffle ----
#pragma unroll
  for (int p = 0; p < 2; ++p) {
    int row = srow_[p], seg = sseg_[p];
    *(u16x8*)&Ks[row * 64 + swz(row, seg)] = kreg[p];
    float kss = 0.f, qss = 0.f;
    const float bs = bvec[row];
#pragma unroll
    for (int e = 0; e < 8; ++e) {
      float kf = bf2f(kreg[p][e]), qf = bf2f(qreg[p][e]);
      kss += kf * kf; qss += qf * qf;
      int c = seg + e;
      WTs[c * 64 + swz(c, row)] = f2bf(bs * bf2f(vreg[p][e]));
    }
    kss += __shfl_xor(kss, 1); kss += __shfl_xor(kss, 2); kss += __shfl_xor(kss, 4);
    qss += __shfl_xor(qss, 1); qss += __shfl_xor(qss, 2); qss += __shfl_xor(qss, 4);
    if ((tid & 7) == 0) { nkinv[row] = kss; nqinv[row] = qss; }
  }
  __syncthreads();

  // ---- P2: inverse norms ----
  if (tid < 64)       nkinv[tid] = rsqrtf(fmaxf(nkinv[tid], 1e-24f));
  else if (tid < 128) nqinv[tid - 64] = rsqrtf(fmaxf(nqinv[tid - 64], 1e-24f));
  __syncthreads();

  // ---- P3: KK^T + QK^T MFMA; build KbT & KdT; L/Mq epilogue ----
  f32x4 akk[4], aqk[4];
#pragma unroll
  for (int n = 0; n < 4; ++n) { akk[n] = f32x4{0, 0, 0, 0}; aqk[n] = f32x4{0, 0, 0, 0}; }
  {
    bf16x8 afK[2], afQ[2];
#pragma unroll
    for (int kk = 0; kk < 2; ++kk) {
      afK[kk] = __builtin_bit_cast(bf16x8, *(const u16x8*)&Ks[ar * 64 + swz(ar, kk * 32 + fq * 8)]);
      afQ[kk] = __builtin_bit_cast(bf16x8, qa[kk]);
    }
#pragma unroll
    for (int n = 0; n < 4; ++n) {
      const int br = n * 16 + fr;
#pragma unroll
      for (int kk = 0; kk < 2; ++kk) {
        bf16x8 bk = __builtin_bit_cast(bf16x8, *(const u16x8*)&Ks[br * 64 + swz(br, kk * 32 + fq * 8)]);
        akk[n] = __builtin_amdgcn_mfma_f32_16x16x32_bf16(afK[kk], bk, akk[n], 0, 0, 0);
        aqk[n] = __builtin_amdgcn_mfma_f32_16x16x32_bf16(afQ[kk], bk, aqk[n], 0, 0, 0);
      }
    }
  }
  {
    const int j = tid & 63, tg4 = tid >> 6;
    const float c63 = cvec[63];
    u16 kb[16], kd[16];
#pragma unroll
    for (int tt = 0; tt < 16; ++tt) {
      int t = tg4 * 16 + tt;
      float kv = bf2f(Ks[t * 64 + swz(t, j)]) * nkinv[t];
      kb[tt] = f2bf(bvec[t] * Avec[t] * kv);
      kd[tt] = f2bf(exp2f(c63 - cvec[t]) * kv);
    }
#pragma unroll
    for (int g8 = 0; g8 < 2; ++g8) {
      u16x8 o1, o2;
#pragma unroll
      for (int e = 0; e < 8; ++e) { o1[e] = kb[g8 * 8 + e]; o2[e] = kd[g8 * 8 + e]; }
      int colg = tg4 * 16 + g8 * 8;
      *(u16x8*)&WTs[(64 + j) * 64 + swz(64 + j, colg)] = o1;
      *(u16x8*)&KdT[j * 64 + swz(j, colg)] = o2;
    }
  }
#pragma unroll
  for (int n = 0; n < 4; ++n)
#pragma unroll
    for (int r = 0; r < 4; ++r) {
      const int t = w * 16 + fq * 4 + r;
      const int s = n * 16 + fr;
      const float e = exp2f(cvec[t] - cvec[s]);
      Lb[t * 64 + swz(t, s)] = (s < t) ? f2bf(bvec[t] * e * nkinv[t] * nkinv[s] * akk[n][r]) : (u16)0;
      MqS[t * 64 + swz(t, s)] = (s <= t) ? f2bf(e * nqinv[t] * nkinv[s] * aqk[n][r]) : (u16)0;
    }
  __syncthreads();

  // ---- P4: Dinv of the 4 diagonal 16x16 blocks (wave w owns block w) ----
  if (l < 16) {
    const int c = l;
    const int rb = w * 16;
    float x[16];
#pragma unroll
    for (int u = 0; u < 16; ++u) {
      float a2 = (u == c) ? 1.f : 0.f;
#pragma unroll
      for (int s = 0; s < u; ++s)
        a2 -= bf2f(Lb[(rb + u) * 64 + swz(rb + u, rb + s)]) * x[s];
      x[u] = a2;
    }
#pragma unroll
    for (int u = 0; u < 16; ++u)
      Db[w * 16 * DBS + u * DBS + c] = f2bf(x[u]);
  }
  __syncthreads();

  // ---- P5: L~ = Dinv.L (scalar, store NEGATED); R~T = RT.DinvT (MFMA) ----
  float ltil[6];
  {
    const int pbi[6] = {1, 2, 2, 3, 3, 3}, pbj[6] = {0, 0, 1, 0, 1, 2};
    const int tt = tid >> 4, s = tid & 15;
#pragma unroll
    for (int e = 0; e < 6; ++e) {
      int bi = pbi[e], bj = pbj[e];
      float a2 = 0.f;
#pragma unroll
      for (int u = 0; u < 16; ++u)
        a2 += bf2f(Db[bi * 16 * DBS + tt * DBS + u]) *
              bf2f(Lb[(bi * 16 + u) * 64 + swz(bi * 16 + u, bj * 16 + s)]);
      ltil[e] = a2;
    }
  }
  f32x4 rtacc[2][4];
#pragma unroll
  for (int rt2 = 0; rt2 < 2; ++rt2) {
    const int rrow = (w * 2 + rt2) * 16 + fr;
#pragma unroll
    for (int bi = 0; bi < 4; ++bi) {
      bf16x8 a2 = (fq < 2)
        ? __builtin_bit_cast(bf16x8, *(const u16x8*)&WTs[rrow * 64 + swz(rrow, bi * 16 + fq * 8)])
        : zfrag();
      bf16x8 b2 = (fq < 2)
        ? __builtin_bit_cast(bf16x8, *(const u16x8*)&Db[bi * 16 * DBS + fr * DBS + fq * 8])
        : zfrag();
      rtacc[rt2][bi] = __builtin_amdgcn_mfma_f32_16x16x32_bf16(a2, b2, f32x4{0, 0, 0, 0}, 0, 0, 0);
    }
  }
  __syncthreads();   // all L~/R~ reads done before overwrites
  {
    const int pbi[6] = {1, 2, 2, 3, 3, 3}, pbj[6] = {0, 0, 1, 0, 1, 2};
    const int tt = tid >> 4, s = tid & 15;
#pragma unroll
    for (int e = 0; e < 6; ++e)
      Lb[(pbi[e] * 16 + tt) * 64 + swz(pbi[e] * 16 + tt, pbj[e] * 16 + s)] = f2bf(-ltil[e]);
  }
#pragma unroll
  for (int rt2 = 0; rt2 < 2; ++rt2)
#pragma unroll
    for (int bi = 0; bi < 4; ++bi)
#pragma unroll
      for (int r = 0; r < 4; ++r) {
        int rr = (w * 2 + rt2) * 16 + fq * 4 + r;
        WTs[rr * 64 + swz(rr, bi * 16 + fr)] = f2bf(rtacc[rt2][bi][r]);
      }
  __syncthreads();

  // ---- P6: 3-step MFMA substitution (row-tiles wave-exclusive, no barriers) ----
#pragma unroll
  for (int rt2 = 0; rt2 < 2; ++rt2) {
    const int rrow = (w * 2 + rt2) * 16 + fr;
    const int wr0 = (w * 2 + rt2) * 16 + fq * 4;
#pragma unroll
    for (int i = 1; i < 4; ++i) {
      f32x4 a2;
#pragma unroll
      for (int r = 0; r < 4; ++r)
        a2[r] = bf2f(WTs[(wr0 + r) * 64 + swz(wr0 + r, i * 16 + fr)]);
      {
        bf16x8 af = __builtin_bit_cast(bf16x8, *(const u16x8*)&WTs[rrow * 64 + swz(rrow, fq * 8)]);
        bf16x8 bf_;
        if (i == 1) bf_ = (fq < 2)
          ? __builtin_bit_cast(bf16x8, *(const u16x8*)&Lb[(16 + fr) * 64 + swz(16 + fr, fq * 8)])
          : zfrag();
        else bf_ = __builtin_bit_cast(bf16x8, *(const u16x8*)&Lb[(i * 16 + fr) * 64 + swz(i * 16 + fr, fq * 8)]);
        a2 = __builtin_amdgcn_mfma_f32_16x16x32_bf16(af, bf_, a2, 0, 0, 0);
      }
      if (i == 3) {
        bf16x8 af = __builtin_bit_cast(bf16x8, *(const u16x8*)&WTs[rrow * 64 + swz(rrow, 32 + fq * 8)]);
        bf16x8 bf_ = (fq < 2)
          ? __builtin_bit_cast(bf16x8, *(const u16x8*)&Lb[(48 + fr) * 64 + swz(48 + fr, 32 + fq * 8)])
          : zfrag();
        a2 = __builtin_amdgcn_mfma_f32_16x16x32_bf16(af, bf_, a2, 0, 0, 0);
      }
#pragma unroll
      for (int r = 0; r < 4; ++r)
        WTs[(wr0 + r) * 64 + swz(wr0 + r, i * 16 + fr)] = f2bf(a2[r]);
    }
  }
  __syncthreads();

  // ---- P7: final 4 GEMMs ----
  u16 qpre[4][4];
#pragma unroll
  for (int n = 0; n < 4; ++n)
#pragma unroll
    for (int r = 0; r < 4; ++r)
      qpre[n][r] = qkv[qkvT_idx(0, h, t0 + w * 16 + fq * 4 + r, n * 16 + fr)];

  f32x4 aG[4], aU[4], aQe[4], aOi[4];
#pragma unroll
  for (int n = 0; n < 4; ++n) {
    aG[n] = f32x4{0, 0, 0, 0}; aU[n] = f32x4{0, 0, 0, 0};
    aQe[n] = f32x4{0, 0, 0, 0}; aOi[n] = f32x4{0, 0, 0, 0};
  }
  {
    bf16x8 aKd[2], aWv[2], aMq[2];
#pragma unroll
    for (int kk = 0; kk < 2; ++kk) {
      aKd[kk] = __builtin_bit_cast(bf16x8, *(const u16x8*)&KdT[ar * 64 + swz(ar, kk * 32 + fq * 8)]);
      aWv[kk] = __builtin_bit_cast(bf16x8, *(const u16x8*)&WTs[ar * 64 + swz(ar, kk * 32 + fq * 8)]);
      aMq[kk] = __builtin_bit_cast(bf16x8, *(const u16x8*)&MqS[ar * 64 + swz(ar, kk * 32 + fq * 8)]);
    }
#pragma unroll
    for (int n = 0; n < 4; ++n) {
      const int br = n * 16 + fr;
#pragma unroll
      for (int kk = 0; kk < 2; ++kk) {
        bf16x8 bTw = __builtin_bit_cast(bf16x8, *(const u16x8*)&WTs[(64 + br) * 64 + swz(64 + br, kk * 32 + fq * 8)]);
        bf16x8 bKd = __builtin_bit_cast(bf16x8, *(const u16x8*)&KdT[br * 64 + swz(br, kk * 32 + fq * 8)]);
        bf16x8 bWv = __builtin_bit_cast(bf16x8, *(const u16x8*)&WTs[br * 64 + swz(br, kk * 32 + fq * 8)]);
        aG[n]  = __builtin_amdgcn_mfma_f32_16x16x32_bf16(aKd[kk], bTw, aG[n], 0, 0, 0);
        aU[n]  = __builtin_amdgcn_mfma_f32_16x16x32_bf16(aWv[kk], bKd, aU[n], 0, 0, 0);
        aQe[n] = __builtin_amdgcn_mfma_f32_16x16x32_bf16(aMq[kk], bTw, aQe[n], 0, 0, 0);
        aOi[n] = __builtin_amdgcn_mfma_f32_16x16x32_bf16(aMq[kk], bWv, aOi[n], 0, 0, 0);
      }
    }
  }
  // ---- P8: direct scattered stores into L2-hot contiguous slots; O_intra via Ks ----
  asm volatile("s_waitcnt vmcnt(0)" ::: "memory");   // qpre loaded before slot overwrite
  __builtin_amdgcn_sched_barrier(0);
#pragma unroll
  for (int n = 0; n < 4; ++n)
#pragma unroll
    for (int r = 0; r < 4; ++r) {
      const int i = w * 16 + fq * 4 + r;
      const int cn = n * 16 + fr;
      const int sw = swz(i, cn);
      qkv[qkvT_idx(0, h, t0 + i, sw)] = f2bf(Avec[i] * nqinv[i] * bf2f(qpre[n][r]) - aQe[n][r]);
      qkv[qkvT_idx(1, h, t0 + i, sw)] = f2bf(-aG[n][r]);
      qkv[qkvT_idx(2, h, t0 + i, sw)] = f2bf(aU[n][r]);
      Ks[i * 64 + cn] = f2bf(aOi[n][r]);   // Ks dead since P3
    }
  __syncthreads();
#pragma unroll
  for (int p = 0; p < 2; ++p) {
    const int idx = p * 256 + tid;
    const int row = idx >> 3, seg = (idx & 7) * 8;
    *(u16x8*)&oi[(long)unit * 4096 + row * 64 + seg] = *(const u16x8*)&Ks[row * 64 + seg];
  }
}

// ---------------- sequential chunk recurrence (4-buffer, 3-chunk-deep async) --
// 64 blocks x 256 threads; 64 sequential chunk steps. Depth-3 prefetch:
// stg[4] buffers, steady-state wait vmcnt(24) (=3 chunks x 8 loads/thread in
// flight; trailing epilogue stores absorbed by slight over-drain).
__global__ __launch_bounds__(256) void k_seq(const u16* __restrict__ qkv,
                                             const u16* __restrict__ oi,
                                             const float* __restrict__ A63G,
                                             u16* __restrict__ ob) {
  __shared__ __align__(16) u16 Sb[64 * 64];
  __shared__ __align__(16) u16 Obs[64 * 64];         // O writeout staging
  __shared__ __align__(16) u16 stg[4][4][64 * 64];   // [buf][Qe,G,U,Oi][..] 128KB
  __shared__ float a63s[64];
  const int pair = blockIdx.x;
  const int b = pair >> 4, h = pair & 15;
  const int tid = threadIdx.x, l = tid & 63, w = tid >> 6;
  const int fr = l & 15, fq = l >> 4;
  const int ar = w * 16 + fr;

  auto stage = [&](int c, int bi) {
    const long tg = (long)b * NT + (long)c * CC;
#pragma unroll
    for (int m = 0; m < 4; ++m)
#pragma unroll
      for (int p = 0; p < 2; ++p) {
        int idx = p * 256 + tid;
        int row = idx >> 3, seg = (idx & 7) * 8;
        const u16* src = (m < 3)
          ? &qkv[qkvT_idx(m, h, tg + row, seg)]
          : &oi[(long)(pair * 64 + c) * 4096 + row * 64 + seg];
        gload_lds16(src, &stg[bi][m][p * 2048 + w * 512]);
      }
  };

  if (tid < 64) a63s[tid] = A63G[pair * 64 + tid];
  for (int i = tid; i < 4096; i += 256) Sb[i] = 0;
  stage(0, 0); stage(1, 1); stage(2, 2);
  f32x4 sacc[4];
#pragma unroll
  for (int n = 0; n < 4; ++n) sacc[n] = f32x4{0, 0, 0, 0};
  asm volatile("s_waitcnt lgkmcnt(0)" ::: "memory");
  __builtin_amdgcn_sched_barrier(0);

  for (int c = 0; c < NCH; ++c) {
    const int bi = c & 3;
    const long tg = (long)b * NT + (long)c * CC;
    // depth-3 counted waits (vmcnt retires oldest-first; stores over-drained)
    if (c + 3 < NCH) {
      stage(c + 3, (c + 3) & 3);
      asm volatile("s_waitcnt vmcnt(24)" ::: "memory");
    } else if (c + 2 < NCH) {
      asm volatile("s_waitcnt vmcnt(16)" ::: "memory");
    } else if (c + 1 < NCH) {
      asm volatile("s_waitcnt vmcnt(8)" ::: "memory");
    } else {
      asm volatile("s_waitcnt vmcnt(0)" ::: "memory");
    }
    __builtin_amdgcn_sched_barrier(0);
    __builtin_amdgcn_s_barrier();
    __builtin_amdgcn_sched_barrier(0);

    const u16* Qe = stg[bi][0];
    const u16* Gm = stg[bi][1];
    const u16* Um = stg[bi][2];
    const u16* Obl = stg[bi][3];

    // O_cross[t][d] = sum_j Qeff[t][j] S[d][j]
    bf16x8 aq[2];
#pragma unroll
    for (int kk = 0; kk < 2; ++kk)
      aq[kk] = __builtin_bit_cast(bf16x8, *(const u16x8*)&Qe[ar * 64 + swz(ar, kk * 32 + fq * 8)]);
    f32x4 ao[4];
#pragma unroll
    for (int n = 0; n < 4; ++n) ao[n] = f32x4{0, 0, 0, 0};
#pragma unroll
    for (int n = 0; n < 4; ++n) {
      const int br = n * 16 + fr;
#pragma unroll
      for (int kk = 0; kk < 2; ++kk) {
        bf16x8 sb = __builtin_bit_cast(bf16x8, *(const u16x8*)&Sb[br * 64 + swz(br, kk * 32 + fq * 8)]);
        ao[n] = __builtin_amdgcn_mfma_f32_16x16x32_bf16(aq[kk], sb, ao[n], 0, 0, 0);
      }
    }
    // S update: sacc = A63*sacc + S.G (+U below)
    bf16x8 as_[2];
#pragma unroll
    for (int kk = 0; kk < 2; ++kk)
      as_[kk] = __builtin_bit_cast(bf16x8, *(const u16x8*)&Sb[ar * 64 + swz(ar, kk * 32 + fq * 8)]);
    const float A63 = a63s[c];
#pragma unroll
    for (int n = 0; n < 4; ++n) {
#pragma unroll
      for (int r = 0; r < 4; ++r) sacc[n][r] *= A63;
      const int br = n * 16 + fr;
#pragma unroll
      for (int kk = 0; kk < 2; ++kk) {
        bf16x8 g = __builtin_bit_cast(bf16x8, *(const u16x8*)&Gm[br * 64 + swz(br, kk * 32 + fq * 8)]);
        sacc[n] = __builtin_amdgcn_mfma_f32_16x16x32_bf16(as_[kk], g, sacc[n], 0, 0, 0);
      }
    }
    // +U, O -> Obs staging
#pragma unroll
    for (int n = 0; n < 4; ++n)
#pragma unroll
      for (int r = 0; r < 4; ++r) {
        const int i = w * 16 + fq * 4 + r;
        const int cn = n * 16 + fr;
        sacc[n][r] += bf2f(Um[i * 64 + swz(i, cn)]);
        Obs[i * 64 + cn] = f2bf(bf2f(Obl[i * 64 + cn]) + ao[n][r]);
      }
    asm volatile("s_waitcnt lgkmcnt(0)" ::: "memory");
    __builtin_amdgcn_s_barrier();   // all waves done reading Sb; Obs visible
#pragma unroll
    for (int n = 0; n < 4; ++n)
#pragma unroll
      for (int r = 0; r < 4; ++r) {
        const int d = w * 16 + fq * 4 + r, j = n * 16 + fr;
        Sb[d * 64 + swz(d, j)] = f2bf(sacc[n][r]);
      }
    // vectorized O writeout (full 128B rows)
#pragma unroll
    for (int p = 0; p < 2; ++p) {
      const int idx = p * 256 + tid;
      const int row = idx >> 3, seg = (idx & 7) * 8;
      *(u16x8*)&ob[(tg + row) * 1024 + h * 64 + seg] = *(const u16x8*)&Obs[row * 64 + seg];
    }
    asm volatile("s_waitcnt lgkmcnt(0)" ::: "memory");
    __builtin_amdgcn_sched_barrier(0);
  }
}

extern "C" void kernel_launch(void* const* d_in, const int* in_sizes, int n_in,
                              void* d_out, int out_size, void* d_ws, size_t ws_size,
                              hipStream_t stream) {
  const float* x    = (const float*)d_in[0];
  const float* Wqkv = (const float*)d_in[1];
  const float* Wg   = (const float*)d_in[2];
  const float* bg   = (const float*)d_in[3];
  const float* Wb   = (const float*)d_in[4];
  const float* bb   = (const float*)d_in[5];
  const float* Wout = (const float*)d_in[6];
  float* out = (float*)d_out;

  char* ws = (char*)d_ws;
  u16* xb    = (u16*)ws;                               // 16384*1024   (32MB)
  u16* wqkvb = xb    + (long)BT * NDIM;                // 3072*1024    (6MB)
  u16* woutb = wqkvb + (long)3072 * 1024;              // 1024*1024    (2MB)
  u16* wgbb  = woutb + (long)1024 * 1024;              // 128*1024
  u16* qkvb  = wgbb  + (long)128 * 1024;               // [48][BT][64] (96MB)
  u16* ob    = qkvb  + (long)BT * 3072;                // 16384*1024   (32MB)
  float* graw  = (float*)(ob + (long)BT * NDIM);       // 16384*128    (8MB)
  float* alpha = graw + (long)BT * 128;                // 16384*16     (1MB)
  float* beta  = alpha + (long)BT * NH;                // 16384*16     (1MB)
  float* A63G  = graw;   // reuse: graw dead after k_gates_fin (needs 16KB)
  u16*   oi    = xb;     // reuse: xb dead after gates GEMM; NU*4096 u16 = 32MB exact

  // 1. converts
  k_f32_to_bf16<<<(BT * (long)NDIM / 4 + 255) / 256, 256, 0, stream>>>(x, xb, BT * (long)NDIM / 4);
  k_f32_to_bf16<<<(3072L * 1024 / 4 + 255) / 256, 256, 0, stream>>>(Wqkv, wqkvb, 3072L * 1024 / 4);
  k_f32_to_bf16<<<(1024L * 1024 / 4 + 255) / 256, 256, 0, stream>>>(Wout, woutb, 1024L * 1024 / 4);
  k_build_wgb<<<(128 * 1024) / 256, 256, 0, stream>>>(Wg, Wb, wgbb);

  // 2. qkv GEMM (256^2 8-phase, head-major output)
  k_gemm256<u16, true><<<64 * 12, 512, 0, stream>>>(xb, wqkvb, qkvb, BT, 3072, NDIM);

  // 3. gates GEMM (N=128, old path) + finalize
  k_gemm_bt<float><<<dim3(1, BT / 128), 256, 0, stream>>>(xb, wgbb, graw, BT, 128, NDIM);
  k_gates_fin<<<(BT * NH + 255) / 256, 256, 0, stream>>>(graw, bg, bb, alpha, beta);

  // 4. chunked WY: parallel precompute + sequential chunk GEMMs (deep pipeline)
  k_prep<<<NU, 256, 0, stream>>>(qkvb, alpha, beta, A63G, oi);
  k_seq<<<NPAIR, 256, 0, stream>>>(qkvb, oi, A63G, ob);

  // 5. out GEMM (256^2 8-phase): 16384x1024 = ob @ woutb^T (fp32 out)
  k_gemm256<float, false><<<64 * 4, 512, 0, stream>>>(ob, woutb, out, BT, NDIM, NDIM);
}

// Round 11
// 388.392 us; speedup vs baseline: 1.2519x; 1.0844x over previous
//
#include <hip/hip_runtime.h>
#include <hip/hip_bf16.h>

// Problem constants
#define NB   4
#define NT   4096
#define BT   16384   // NB*NT
#define NDIM 1024
#define NH   16
#define NDH  64
#define CC   64              // chunk size (time steps)
#define NCH  (NT / CC)       // 64 chunks per pair
#define NPAIR 64             // B*H
#define NU   (NPAIR * NCH)   // 4096 units
#define DBS  24              // Db row stride (u16 elems), padded for banks

using u16 = unsigned short;
typedef __bf16 bf16x8 __attribute__((ext_vector_type(8)));
typedef float f32x4 __attribute__((ext_vector_type(4)));
typedef unsigned short u16x8 __attribute__((ext_vector_type(8)));
typedef unsigned short u16x4 __attribute__((ext_vector_type(4)));

__device__ __forceinline__ float bf2f(u16 b) { return __uint_as_float(((unsigned)b) << 16); }
__device__ __forceinline__ u16 f2bf(float f) {
  return __builtin_bit_cast(u16, __float2bfloat16(f));
}
// LDS row swizzle (u16-element index, 8-elem granular): breaks stride-128B bank conflicts
__device__ __forceinline__ int swz(int row, int e) { return e ^ ((row & 7) << 3); }
__device__ __forceinline__ bf16x8 zfrag() {
  u16x8 z = {0, 0, 0, 0, 0, 0, 0, 0};
  return __builtin_bit_cast(bf16x8, z);
}
// head-major qkv layout: [slot(3)][head(16)][bt(BT)][d(64)] — per-(h,chunk) tile contiguous
__device__ __forceinline__ long qkvT_idx(int s, int h, long bt, int d) {
  return ((long)(s * 16 + h) * BT + bt) * 64 + d;
}

// ---------------- convert fp32 -> bf16 (vectorized) ----------------
__global__ __launch_bounds__(256) void k_f32_to_bf16(const float* __restrict__ in,
                                                     u16* __restrict__ out, long n4) {
  long i = (long)blockIdx.x * blockDim.x + threadIdx.x;
  if (i >= n4) return;
  float4 f = reinterpret_cast<const float4*>(in)[i];
  u16x4 o;
  o.x = f2bf(f.x); o.y = f2bf(f.y); o.z = f2bf(f.z); o.w = f2bf(f.w);
  reinterpret_cast<u16x4*>(out)[i] = o;
}

// ---------------- build padded gate weight matrix (128 x 1024 bf16) ----------------
__global__ __launch_bounds__(256) void k_build_wgb(const float* __restrict__ Wg,
                                                   const float* __restrict__ Wb,
                                                   u16* __restrict__ out) {
  int i = blockIdx.x * 256 + threadIdx.x;
  int row = i >> 10, col = i & 1023;
  float f = 0.f;
  if (row < 16)       f = Wg[row * 1024 + col];
  else if (row < 32)  f = Wb[(row - 16) * 1024 + col];
  out[i] = f2bf(f);
}

// ---------------- global_load_lds helper ----------------
typedef unsigned int u32_as1 __attribute__((address_space(1)));
typedef unsigned int u32_as3 __attribute__((address_space(3)));
__device__ __forceinline__ void gload_lds16(const void* g, void* l) {
  __builtin_amdgcn_global_load_lds((const u32_as1*)g, (u32_as3*)l, 16, 0, 0);
}

// ---------------- bf16 GEMM (small-N path): C(MxN) = A(MxK) @ B(NxK)^T -------
template <typename OutT>
__global__ __launch_bounds__(256) void k_gemm_bt(const u16* __restrict__ A,
                                                 const u16* __restrict__ B,
                                                 OutT* __restrict__ C,
                                                 int M, int N, int K) {
  constexpr int BM = 128, BN = 128, BK = 32;
  __shared__ __align__(16) u16 As[BM * BK];
  __shared__ __align__(16) u16 Bs[BN * BK];
  const int tid = threadIdx.x;
  const int l = tid & 63, w = tid >> 6;
  const int tn = blockIdx.x, tm = blockIdx.y;
  const long a0 = (long)tm * BM * K;
  const long b0 = (long)tn * BN * K;
  const int srow = tid >> 2;
  const int scol = (tid & 3) << 3;
  const int wrow = (w >> 1) << 6;
  const int wcol = (w & 1) << 6;
  const int fr = l & 15, fq = l >> 4;

  f32x4 acc[4][4];
#pragma unroll
  for (int m = 0; m < 4; ++m)
#pragma unroll
    for (int n = 0; n < 4; ++n) acc[m][n] = f32x4{0.f, 0.f, 0.f, 0.f};

  for (int kk = 0; kk < K; kk += BK) {
    __syncthreads();
    const u16* gA = A + a0 + (long)srow * K + kk + scol;
    const u16* gB = B + b0 + (long)srow * K + kk + scol;
    gload_lds16(gA,                &As[(w * 16) * BK]);
    gload_lds16(gA + 64 * (long)K, &As[(64 + w * 16) * BK]);
    gload_lds16(gB,                &Bs[(w * 16) * BK]);
    gload_lds16(gB + 64 * (long)K, &Bs[(64 + w * 16) * BK]);
    __syncthreads();

    bf16x8 af[4], bfv[4];
#pragma unroll
    for (int m = 0; m < 4; ++m)
      af[m] = *(const bf16x8*)&As[(wrow + m * 16 + fr) * BK + (fq << 3)];
#pragma unroll
    for (int n = 0; n < 4; ++n)
      bfv[n] = *(const bf16x8*)&Bs[(wcol + n * 16 + fr) * BK + (fq << 3)];
#pragma unroll
    for (int m = 0; m < 4; ++m)
#pragma unroll
      for (int n = 0; n < 4; ++n)
        acc[m][n] = __builtin_amdgcn_mfma_f32_16x16x32_bf16(af[m], bfv[n], acc[m][n], 0, 0, 0);
  }

#pragma unroll
  for (int m = 0; m < 4; ++m) {
#pragma unroll
    for (int n = 0; n < 4; ++n) {
      const int r0 = tm * BM + wrow + m * 16 + fq * 4;
      const int c  = tn * BN + wcol + n * 16 + fr;
#pragma unroll
      for (int r = 0; r < 4; ++r) {
        float v = acc[m][n][r];
        long idx = (long)(r0 + r) * N + c;
        if constexpr (sizeof(OutT) == 2) C[idx] = f2bf(v);
        else                             C[idx] = v;
      }
    }
  }
}

// ============ 256x256-tile 8-phase bf16 GEMM: C = A(MxK) @ B(NxK)^T ==========
// QKVT=true: write head-major qkv layout [48][BT][64] instead of [BT][3072].
template <typename OutT, bool QKVT>
__global__ __launch_bounds__(512, 2) void k_gemm256(const u16* __restrict__ A,
                                                    const u16* __restrict__ B,
                                                    OutT* __restrict__ C,
                                                    int M, int N, int K) {
  __shared__ __align__(16) u16 As[2][2][256 * 32];
  __shared__ __align__(16) u16 Bs[2][2][256 * 32];
  const int tid = threadIdx.x;
  const int l = tid & 63, w = tid >> 6;
  const int wm = w >> 2, wn = w & 3;          // 2 x 4 wave grid
  const int fr = l & 15, fq = l >> 4;
  const int nwg = gridDim.x;
  const int cpx = nwg >> 3;
  const int bid = blockIdx.x;
  const int sbid = (bid & 7) * cpx + (bid >> 3);
  const int ntn = N >> 8;
  const int tm = sbid / ntn, tn = sbid - tm * ntn;
  const long a0 = (long)tm * 256 * K;
  const long b0 = (long)tn * 256 * K;
  const int srow0 = tid >> 2;
  const int scol8 = (((tid & 3) ^ ((tid >> 4) & 3)) << 3);
  const int cswz = ((fq ^ ((fr >> 2) & 3)) << 3);
  const int NKT = K >> 6;

  auto stage_half = [&](int kt, int buf, int hf) {
    const int ks = hf >> 1;
    const u16* Gp = (hf & 1) ? B : A;
    const long g0 = ((hf & 1) ? b0 : a0) + (long)kt * 64 + ks * 32 + scol8;
    u16* lb = (hf & 1) ? &Bs[buf][ks][w * 512] : &As[buf][ks][w * 512];
#pragma unroll
    for (int r = 0; r < 2; ++r)
      gload_lds16(Gp + g0 + (long)(r * 128 + srow0) * K, lb + r * 4096);
  };

  f32x4 acc[8][4];
#pragma unroll
  for (int m = 0; m < 8; ++m)
#pragma unroll
    for (int n = 0; n < 4; ++n) acc[m][n] = f32x4{0.f, 0.f, 0.f, 0.f};

  stage_half(0, 0, 0); stage_half(0, 0, 1); stage_half(0, 0, 2); stage_half(0, 0, 3);

  for (int kt = 0; kt < NKT; ++kt) {
    const int bi = kt & 1;
    const bool pf = (kt + 1 < NKT);
    asm volatile("s_waitcnt vmcnt(4)" ::: "memory");
    __builtin_amdgcn_sched_barrier(0);
    __builtin_amdgcn_s_barrier();
    __builtin_amdgcn_sched_barrier(0);
    {
      const u16* ap = &As[bi][0][(wm * 128 + fr) * 32 + cswz];
      const u16* bp = &Bs[bi][0][(wn * 64 + fr) * 32 + cswz];
      bf16x8 bfr[4], afr[4];
#pragma unroll
      for (int n = 0; n < 4; ++n) bfr[n] = *(const bf16x8*)(bp + n * 512);
#pragma unroll
      for (int m = 0; m < 4; ++m) afr[m] = *(const bf16x8*)(ap + m * 512);
      if (pf) stage_half(kt + 1, bi ^ 1, 0);
      __builtin_amdgcn_s_setprio(1);
#pragma unroll
      for (int m = 0; m < 4; ++m)
#pragma unroll
        for (int n = 0; n < 4; ++n)
          acc[m][n] = __builtin_amdgcn_mfma_f32_16x16x32_bf16(afr[m], bfr[n], acc[m][n], 0, 0, 0);
      __builtin_amdgcn_s_setprio(0);
#pragma unroll
      for (int m = 0; m < 4; ++m) afr[m] = *(const bf16x8*)(ap + (4 + m) * 512);
      if (pf) stage_half(kt + 1, bi ^ 1, 1);
      __builtin_amdgcn_s_setprio(1);
#pragma unroll
      for (int m = 0; m < 4; ++m)
#pragma unroll
        for (int n = 0; n < 4; ++n)
          acc[4 + m][n] = __builtin_amdgcn_mfma_f32_16x16x32_bf16(afr[m], bfr[n], acc[4 + m][n], 0, 0, 0);
      __builtin_amdgcn_s_setprio(0);
    }
    if (pf) { asm volatile("s_waitcnt vmcnt(4)" ::: "memory"); }
    else    { asm volatile("s_waitcnt vmcnt(0)" ::: "memory"); }
    __builtin_amdgcn_sched_barrier(0);
    __builtin_amdgcn_s_barrier();
    __builtin_amdgcn_sched_barrier(0);
    {
      const u16* ap = &As[bi][1][(wm * 128 + fr) * 32 + cswz];
      const u16* bp = &Bs[bi][1][(wn * 64 + fr) * 32 + cswz];
      bf16x8 bfr[4], afr[4];
#pragma unroll
      for (int n = 0; n < 4; ++n) bfr[n] = *(const bf16x8*)(bp + n * 512);
#pragma unroll
      for (int m = 0; m < 4; ++m) afr[m] = *(const bf16x8*)(ap + m * 512);
      if (pf) stage_half(kt + 1, bi ^ 1, 2);
      __builtin_amdgcn_s_setprio(1);
#pragma unroll
      for (int m = 0; m < 4; ++m)
#pragma unroll
        for (int n = 0; n < 4; ++n)
          acc[m][n] = __builtin_amdgcn_mfma_f32_16x16x32_bf16(afr[m], bfr[n], acc[m][n], 0, 0, 0);
      __builtin_amdgcn_s_setprio(0);
#pragma unroll
      for (int m = 0; m < 4; ++m) afr[m] = *(const bf16x8*)(ap + (4 + m) * 512);
      if (pf) stage_half(kt + 1, bi ^ 1, 3);
      __builtin_amdgcn_s_setprio(1);
#pragma unroll
      for (int m = 0; m < 4; ++m)
#pragma unroll
        for (int n = 0; n < 4; ++n)
          acc[4 + m][n] = __builtin_amdgcn_mfma_f32_16x16x32_bf16(afr[m], bfr[n], acc[4 + m][n], 0, 0, 0);
      __builtin_amdgcn_s_setprio(0);
    }
  }

#pragma unroll
  for (int m = 0; m < 8; ++m)
#pragma unroll
    for (int n = 0; n < 4; ++n) {
      const int row0 = tm * 256 + wm * 128 + m * 16 + fq * 4;
      const int col  = tn * 256 + wn * 64 + n * 16 + fr;
#pragma unroll
      for (int r = 0; r < 4; ++r) {
        if constexpr (QKVT) {
          const int hb = (tn * 256 + wn * 64) >> 6;
          long idx = ((long)hb * BT + (row0 + r)) * 64 + (n * 16 + fr);
          C[idx] = (OutT)f2bf(acc[m][n][r]);
        } else {
          long idx = (long)(row0 + r) * N + col;
          if constexpr (sizeof(OutT) == 2) C[idx] = f2bf(acc[m][n][r]);
          else                             C[idx] = acc[m][n][r];
        }
      }
    }
}

// ---------------- gate finalize: sigmoid(raw + bias) ----------------
__global__ __launch_bounds__(256) void k_gates_fin(const float* __restrict__ raw,
                                                   const float* __restrict__ bg,
                                                   const float* __restrict__ bb,
                                                   float* __restrict__ alpha,
                                                   float* __restrict__ beta) {
  int i = blockIdx.x * 256 + threadIdx.x;
  if (i >= BT * NH) return;
  int bt = i >> 4, h = i & 15;
  float ga = raw[(long)bt * 128 + h] + bg[h];
  float gb = raw[(long)bt * 128 + 16 + h] + bb[h];
  alpha[i] = 1.f / (1.f + __expf(-ga));
  beta[i]  = 1.f / (1.f + __expf(-gb));
}

// ================= chunked WY scan (MFMA block-solve, fused l2norm) =======
// R8-proven version (unchanged): scattered qkv-slot stores inline in epilogue,
// qpre loaded in P7, O_intra via dead-Ks staging to contiguous oi.
__global__ __launch_bounds__(256, 3) void k_prep(u16* __restrict__ qkv,
                                                 const float* __restrict__ alpha,
                                                 const float* __restrict__ beta,
                                                 float* __restrict__ A63G,
                                                 u16* __restrict__ oi) {
  __shared__ __align__(16) u16 Ks[64 * 64];
  __shared__ __align__(16) u16 WTs[128 * 64];   // rows 0-63: VbT->WvT; 64-127: KbT->TwT
  __shared__ __align__(16) u16 Lb[64 * 64];     // L (b-scaled), later -L~ in 6 sub-blocks
  __shared__ __align__(16) u16 MqS[64 * 64];
  __shared__ __align__(16) u16 KdT[64 * 64];
  __shared__ __align__(16) u16 Db[4 * 16 * DBS];
  __shared__ float cvec[64], Avec[64], bvec[64], nkinv[64], nqinv[64];

  const int unit = blockIdx.x;
  const int pair = unit >> 6, ch = unit & 63;
  const int b = pair >> 4, h = pair & 15;
  const int tid = threadIdx.x, l = tid & 63, w = tid >> 6;
  const int fr = l & 15, fq = l >> 4;
  const long t0 = (long)b * NT + (long)ch * CC;

  // ---- P0: issue global loads into regs; wave0 cumsum ----
  u16x8 kreg[2], vreg[2], qreg[2];
  int srow_[2], sseg_[2];
#pragma unroll
  for (int p = 0; p < 2; ++p) {
    int idx = p * 256 + tid;
    srow_[p] = idx >> 3; sseg_[p] = (idx & 7) * 8;
    qreg[p] = *(const u16x8*)&qkv[qkvT_idx(0, h, t0 + srow_[p], sseg_[p])];
    kreg[p] = *(const u16x8*)&qkv[qkvT_idx(1, h, t0 + srow_[p], sseg_[p])];
    vreg[p] = *(const u16x8*)&qkv[qkvT_idx(2, h, t0 + srow_[p], sseg_[p])];
  }
  const int ar = w * 16 + fr;
  u16x8 qa[2];
#pragma unroll
  for (int kk = 0; kk < 2; ++kk)
    qa[kk] = *(const u16x8*)&qkv[qkvT_idx(0, h, t0 + ar, kk * 32 + fq * 8)];

  if (w == 0) {
    float av = alpha[(t0 + l) * 16 + h];
    float bv = beta[(t0 + l) * 16 + h];
    float cl = __log2f(av);
#pragma unroll
    for (int d = 1; d < 64; d <<= 1) {
      float up = __shfl_up(cl, d);
      if (l >= d) cl += up;
    }
    float A = exp2f(cl);
    cvec[l] = cl; Avec[l] = A; bvec[l] = bv;
    if (l == 63) A63G[unit] = A;
  }
  __syncthreads();

  // ---- P1: stage Ks rows + VbT (b-scaled, transposed); norms via shuffle ----
#pragma unroll
  for (int p = 0; p < 2; ++p) {
    int row = srow_[p], seg = sseg_[p];
    *(u16x8*)&Ks[row * 64 + swz(row, seg)] = kreg[p];
    float kss = 0.f, qss = 0.f;
    const float bs = bvec[row];
#pragma unroll
    for (int e = 0; e < 8; ++e) {
      float kf = bf2f(kreg[p][e]), qf = bf2f(qreg[p][e]);
      kss += kf * kf; qss += qf * qf;
      int c = seg + e;
      WTs[c * 64 + swz(c, row)] = f2bf(bs * bf2f(vreg[p][e]));
    }
    kss += __shfl_xor(kss, 1); kss += __shfl_xor(kss, 2); kss += __shfl_xor(kss, 4);
    qss += __shfl_xor(qss, 1); qss += __shfl_xor(qss, 2); qss += __shfl_xor(qss, 4);
    if ((tid & 7) == 0) { nkinv[row] = kss; nqinv[row] = qss; }
  }
  __syncthreads();

  // ---- P2: inverse norms ----
  if (tid < 64)       nkinv[tid] = rsqrtf(fmaxf(nkinv[tid], 1e-24f));
  else if (tid < 128) nqinv[tid - 64] = rsqrtf(fmaxf(nqinv[tid - 64], 1e-24f));
  __syncthreads();

  // ---- P3: KK^T + QK^T MFMA; build KbT & KdT; L/Mq epilogue ----
  f32x4 akk[4], aqk[4];
#pragma unroll
  for (int n = 0; n < 4; ++n) { akk[n] = f32x4{0, 0, 0, 0}; aqk[n] = f32x4{0, 0, 0, 0}; }
  {
    bf16x8 afK[2], afQ[2];
#pragma unroll
    for (int kk = 0; kk < 2; ++kk) {
      afK[kk] = __builtin_bit_cast(bf16x8, *(const u16x8*)&Ks[ar * 64 + swz(ar, kk * 32 + fq * 8)]);
      afQ[kk] = __builtin_bit_cast(bf16x8, qa[kk]);
    }
#pragma unroll
    for (int n = 0; n < 4; ++n) {
      const int br = n * 16 + fr;
#pragma unroll
      for (int kk = 0; kk < 2; ++kk) {
        bf16x8 bk = __builtin_bit_cast(bf16x8, *(const u16x8*)&Ks[br * 64 + swz(br, kk * 32 + fq * 8)]);
        akk[n] = __builtin_amdgcn_mfma_f32_16x16x32_bf16(afK[kk], bk, akk[n], 0, 0, 0);
        aqk[n] = __builtin_amdgcn_mfma_f32_16x16x32_bf16(afQ[kk], bk, aqk[n], 0, 0, 0);
      }
    }
  }
  {
    const int j = tid & 63, tg4 = tid >> 6;
    const float c63 = cvec[63];
    u16 kb[16], kd[16];
#pragma unroll
    for (int tt = 0; tt < 16; ++tt) {
      int t = tg4 * 16 + tt;
      float kv = bf2f(Ks[t * 64 + swz(t, j)]) * nkinv[t];
      kb[tt] = f2bf(bvec[t] * Avec[t] * kv);
      kd[tt] = f2bf(exp2f(c63 - cvec[t]) * kv);
    }
#pragma unroll
    for (int g8 = 0; g8 < 2; ++g8) {
      u16x8 o1, o2;
#pragma unroll
      for (int e = 0; e < 8; ++e) { o1[e] = kb[g8 * 8 + e]; o2[e] = kd[g8 * 8 + e]; }
      int colg = tg4 * 16 + g8 * 8;
      *(u16x8*)&WTs[(64 + j) * 64 + swz(64 + j, colg)] = o1;
      *(u16x8*)&KdT[j * 64 + swz(j, colg)] = o2;
    }
  }
#pragma unroll
  for (int n = 0; n < 4; ++n)
#pragma unroll
    for (int r = 0; r < 4; ++r) {
      const int t = w * 16 + fq * 4 + r;
      const int s = n * 16 + fr;
      const float e = exp2f(cvec[t] - cvec[s]);
      Lb[t * 64 + swz(t, s)] = (s < t) ? f2bf(bvec[t] * e * nkinv[t] * nkinv[s] * akk[n][r]) : (u16)0;
      MqS[t * 64 + swz(t, s)] = (s <= t) ? f2bf(e * nqinv[t] * nkinv[s] * aqk[n][r]) : (u16)0;
    }
  __syncthreads();

  // ---- P4: Dinv of the 4 diagonal 16x16 blocks (wave w owns block w) ----
  if (l < 16) {
    const int c = l;
    const int rb = w * 16;
    float x[16];
#pragma unroll
    for (int u = 0; u < 16; ++u) {
      float a2 = (u == c) ? 1.f : 0.f;
#pragma unroll
      for (int s = 0; s < u; ++s)
        a2 -= bf2f(Lb[(rb + u) * 64 + swz(rb + u, rb + s)]) * x[s];
      x[u] = a2;
    }
#pragma unroll
    for (int u = 0; u < 16; ++u)
      Db[w * 16 * DBS + u * DBS + c] = f2bf(x[u]);
  }
  __syncthreads();

  // ---- P5: L~ = Dinv.L (scalar, store NEGATED); R~T = RT.DinvT (MFMA) ----
  float ltil[6];
  {
    const int pbi[6] = {1, 2, 2, 3, 3, 3}, pbj[6] = {0, 0, 1, 0, 1, 2};
    const int tt = tid >> 4, s = tid & 15;
#pragma unroll
    for (int e = 0; e < 6; ++e) {
      int bi = pbi[e], bj = pbj[e];
      float a2 = 0.f;
#pragma unroll
      for (int u = 0; u < 16; ++u)
        a2 += bf2f(Db[bi * 16 * DBS + tt * DBS + u]) *
              bf2f(Lb[(bi * 16 + u) * 64 + swz(bi * 16 + u, bj * 16 + s)]);
      ltil[e] = a2;
    }
  }
  f32x4 rtacc[2][4];
#pragma unroll
  for (int rt2 = 0; rt2 < 2; ++rt2) {
    const int rrow = (w * 2 + rt2) * 16 + fr;
#pragma unroll
    for (int bi = 0; bi < 4; ++bi) {
      bf16x8 a2 = (fq < 2)
        ? __builtin_bit_cast(bf16x8, *(const u16x8*)&WTs[rrow * 64 + swz(rrow, bi * 16 + fq * 8)])
        : zfrag();
      bf16x8 b2 = (fq < 2)
        ? __builtin_bit_cast(bf16x8, *(const u16x8*)&Db[bi * 16 * DBS + fr * DBS + fq * 8])
        : zfrag();
      rtacc[rt2][bi] = __builtin_amdgcn_mfma_f32_16x16x32_bf16(a2, b2, f32x4{0, 0, 0, 0}, 0, 0, 0);
    }
  }
  __syncthreads();   // all L~/R~ reads done before overwrites
  {
    const int pbi[6] = {1, 2, 2, 3, 3, 3}, pbj[6] = {0, 0, 1, 0, 1, 2};
    const int tt = tid >> 4, s = tid & 15;
#pragma unroll
    for (int e = 0; e < 6; ++e)
      Lb[(pbi[e] * 16 + tt) * 64 + swz(pbi[e] * 16 + tt, pbj[e] * 16 + s)] = f2bf(-ltil[e]);
  }
#pragma unroll
  for (int rt2 = 0; rt2 < 2; ++rt2)
#pragma unroll
    for (int bi = 0; bi < 4; ++bi)
#pragma unroll
      for (int r = 0; r < 4; ++r) {
        int rr = (w * 2 + rt2) * 16 + fq * 4 + r;
        WTs[rr * 64 + swz(rr, bi * 16 + fr)] = f2bf(rtacc[rt2][bi][r]);
      }
  __syncthreads();

  // ---- P6: 3-step MFMA substitution (row-tiles wave-exclusive, no barriers) ----
#pragma unroll
  for (int rt2 = 0; rt2 < 2; ++rt2) {
    const int rrow = (w * 2 + rt2) * 16 + fr;
    const int wr0 = (w * 2 + rt2) * 16 + fq * 4;
#pragma unroll
    for (int i = 1; i < 4; ++i) {
      f32x4 a2;
#pragma unroll
      for (int r = 0; r < 4; ++r)
        a2[r] = bf2f(WTs[(wr0 + r) * 64 + swz(wr0 + r, i * 16 + fr)]);
      {
        bf16x8 af = __builtin_bit_cast(bf16x8, *(const u16x8*)&WTs[rrow * 64 + swz(rrow, fq * 8)]);
        bf16x8 bf_;
        if (i == 1) bf_ = (fq < 2)
          ? __builtin_bit_cast(bf16x8, *(const u16x8*)&Lb[(16 + fr) * 64 + swz(16 + fr, fq * 8)])
          : zfrag();
        else bf_ = __builtin_bit_cast(bf16x8, *(const u16x8*)&Lb[(i * 16 + fr) * 64 + swz(i * 16 + fr, fq * 8)]);
        a2 = __builtin_amdgcn_mfma_f32_16x16x32_bf16(af, bf_, a2, 0, 0, 0);
      }
      if (i == 3) {
        bf16x8 af = __builtin_bit_cast(bf16x8, *(const u16x8*)&WTs[rrow * 64 + swz(rrow, 32 + fq * 8)]);
        bf16x8 bf_ = (fq < 2)
          ? __builtin_bit_cast(bf16x8, *(const u16x8*)&Lb[(48 + fr) * 64 + swz(48 + fr, 32 + fq * 8)])
          : zfrag();
        a2 = __builtin_amdgcn_mfma_f32_16x16x32_bf16(af, bf_, a2, 0, 0, 0);
      }
#pragma unroll
      for (int r = 0; r < 4; ++r)
        WTs[(wr0 + r) * 64 + swz(wr0 + r, i * 16 + fr)] = f2bf(a2[r]);
    }
  }
  __syncthreads();

  // ---- P7: final 4 GEMMs ----
  u16 qpre[4][4];
#pragma unroll
  for (int n = 0; n < 4; ++n)
#pragma unroll
    for (int r = 0; r < 4; ++r)
      qpre[n][r] = qkv[qkvT_idx(0, h, t0 + w * 16 + fq * 4 + r, n * 16 + fr)];

  f32x4 aG[4], aU[4], aQe[4], aOi[4];
#pragma unroll
  for (int n = 0; n < 4; ++n) {
    aG[n] = f32x4{0, 0, 0, 0}; aU[n] = f32x4{0, 0, 0, 0};
    aQe[n] = f32x4{0, 0, 0, 0}; aOi[n] = f32x4{0, 0, 0, 0};
  }
  {
    bf16x8 aKd[2], aWv[2], aMq[2];
#pragma unroll
    for (int kk = 0; kk < 2; ++kk) {
      aKd[kk] = __builtin_bit_cast(bf16x8, *(const u16x8*)&KdT[ar * 64 + swz(ar, kk * 32 + fq * 8)]);
      aWv[kk] = __builtin_bit_cast(bf16x8, *(const u16x8*)&WTs[ar * 64 + swz(ar, kk * 32 + fq * 8)]);
      aMq[kk] = __builtin_bit_cast(bf16x8, *(const u16x8*)&MqS[ar * 64 + swz(ar, kk * 32 + fq * 8)]);
    }
#pragma unroll
    for (int n = 0; n < 4; ++n) {
      const int br = n * 16 + fr;
#pragma unroll
      for (int kk = 0; kk < 2; ++kk) {
        bf16x8 bTw = __builtin_bit_cast(bf16x8, *(const u16x8*)&WTs[(64 + br) * 64 + swz(64 + br, kk * 32 + fq * 8)]);
        bf16x8 bKd = __builtin_bit_cast(bf16x8, *(const u16x8*)&KdT[br * 64 + swz(br, kk * 32 + fq * 8)]);
        bf16x8 bWv = __builtin_bit_cast(bf16x8, *(const u16x8*)&WTs[br * 64 + swz(br, kk * 32 + fq * 8)]);
        aG[n]  = __builtin_amdgcn_mfma_f32_16x16x32_bf16(aKd[kk], bTw, aG[n], 0, 0, 0);
        aU[n]  = __builtin_amdgcn_mfma_f32_16x16x32_bf16(aWv[kk], bKd, aU[n], 0, 0, 0);
        aQe[n] = __builtin_amdgcn_mfma_f32_16x16x32_bf16(aMq[kk], bTw, aQe[n], 0, 0, 0);
        aOi[n] = __builtin_amdgcn_mfma_f32_16x16x32_bf16(aMq[kk], bWv, aOi[n], 0, 0, 0);
      }
    }
  }
  // ---- P8: direct scattered stores into L2-hot contiguous slots; O_intra via Ks ----
  asm volatile("s_waitcnt vmcnt(0)" ::: "memory");   // qpre loaded before slot overwrite
  __builtin_amdgcn_sched_barrier(0);
#pragma unroll
  for (int n = 0; n < 4; ++n)
#pragma unroll
    for (int r = 0; r < 4; ++r) {
      const int i = w * 16 + fq * 4 + r;
      const int cn = n * 16 + fr;
      const int sw = swz(i, cn);
      qkv[qkvT_idx(0, h, t0 + i, sw)] = f2bf(Avec[i] * nqinv[i] * bf2f(qpre[n][r]) - aQe[n][r]);
      qkv[qkvT_idx(1, h, t0 + i, sw)] = f2bf(-aG[n][r]);
      qkv[qkvT_idx(2, h, t0 + i, sw)] = f2bf(aU[n][r]);
      Ks[i * 64 + cn] = f2bf(aOi[n][r]);   // Ks dead since P3
    }
  __syncthreads();
#pragma unroll
  for (int p = 0; p < 2; ++p) {
    const int idx = p * 256 + tid;
    const int row = idx >> 3, seg = (idx & 7) * 8;
    *(u16x8*)&oi[(long)unit * 4096 + row * 64 + seg] = *(const u16x8*)&Ks[row * 64 + seg];
  }
}

// ---------------- sequential chunk recurrence (16 waves, 1-tile-per-wave) -----
// 64 blocks x 1024 threads (16 waves = 4/SIMD for latency hiding).
// Wave w owns output tile (tw=w>>2, td=w&3) of BOTH O_cross[64t x 64d] and
// S[64d x 64j]; per-chunk per-wave work: 4 MFMAs + ~12 LDS ops.
// Staging: depth-2 double buffer, counted vmcnt(4) (proven R8 scheme);
// waves 0-7 issue the 4 gload_lds/thread, waves 8-15 sync via barrier.
__global__ __launch_bounds__(1024) void k_seq(const u16* __restrict__ qkv,
                                              const u16* __restrict__ oi,
                                              const float* __restrict__ A63G,
                                              u16* __restrict__ ob) {
  __shared__ __align__(16) u16 Sb[64 * 64];
  __shared__ __align__(16) u16 Obs[64 * 64];         // O writeout staging
  __shared__ __align__(16) u16 stg[2][4][64 * 64];   // [buf][Qe,G,U,Oi][..]
  __shared__ float a63s[64];
  const int pair = blockIdx.x;
  const int b = pair >> 4, h = pair & 15;
  const int tid = threadIdx.x, l = tid & 63, w = tid >> 6;   // w 0..15
  const int fr = l & 15, fq = l >> 4;
  const int tw = w >> 2, td = w & 3;    // tile coords (also used as (dw,jw))

  auto stage = [&](int c, int bi) {
    const long tg = (long)b * NT + (long)c * CC;
    if (tid < 512) {
      const int row = tid >> 3, seg = (tid & 7) * 8;
#pragma unroll
      for (int m = 0; m < 4; ++m) {
        const u16* src = (m < 3)
          ? &qkv[qkvT_idx(m, h, tg + row, seg)]
          : &oi[(long)(pair * 64 + c) * 4096 + row * 64 + seg];
        gload_lds16(src, &stg[bi][m][row * 64 + seg]);
      }
    }
  };

  if (tid < 64) a63s[tid] = A63G[pair * 64 + tid];
  for (int i = tid; i < 4096; i += 1024) Sb[i] = 0;
  stage(0, 0);
  f32x4 sacc = f32x4{0, 0, 0, 0};
  asm volatile("s_waitcnt lgkmcnt(0)" ::: "memory");
  __builtin_amdgcn_sched_barrier(0);

  for (int c = 0; c < NCH; ++c) {
    const int bi = c & 1;
    const long tg = (long)b * NT + (long)c * CC;
    if (c + 1 < NCH) {
      stage(c + 1, bi ^ 1);
      asm volatile("s_waitcnt vmcnt(4)" ::: "memory");
    } else {
      asm volatile("s_waitcnt vmcnt(0)" ::: "memory");
    }
    __builtin_amdgcn_sched_barrier(0);
    __builtin_amdgcn_s_barrier();
    __builtin_amdgcn_sched_barrier(0);

    const u16* Qe = stg[bi][0];
    const u16* Gm = stg[bi][1];
    const u16* Um = stg[bi][2];
    const u16* Obl = stg[bi][3];

    // O_cross tile (tw,td): ao[t][d] = sum_j Qe[t][j] S[d][j]
    const int at = tw * 16 + fr;   // Qe row (t) ; also S row (d) for update
    const int bd = td * 16 + fr;   // Sb row (d) ; also G row (j) for update
    f32x4 ao = f32x4{0, 0, 0, 0};
    const float A63 = a63s[c];
#pragma unroll
    for (int r = 0; r < 4; ++r) sacc[r] *= A63;
#pragma unroll
    for (int kk = 0; kk < 2; ++kk) {
      bf16x8 aq = __builtin_bit_cast(bf16x8, *(const u16x8*)&Qe[at * 64 + swz(at, kk * 32 + fq * 8)]);
      bf16x8 sb = __builtin_bit_cast(bf16x8, *(const u16x8*)&Sb[bd * 64 + swz(bd, kk * 32 + fq * 8)]);
      ao = __builtin_amdgcn_mfma_f32_16x16x32_bf16(aq, sb, ao, 0, 0, 0);
      // S-update tile (dw=tw, jw=td): sacc += S[d][j'] G[j][j'] over j'
      bf16x8 as_ = __builtin_bit_cast(bf16x8, *(const u16x8*)&Sb[at * 64 + swz(at, kk * 32 + fq * 8)]);
      bf16x8 g  = __builtin_bit_cast(bf16x8, *(const u16x8*)&Gm[bd * 64 + swz(bd, kk * 32 + fq * 8)]);
      sacc = __builtin_amdgcn_mfma_f32_16x16x32_bf16(as_, g, sacc, 0, 0, 0);
    }
    // +U and Obs staging (same index arithmetic for both tiles)
#pragma unroll
    for (int r = 0; r < 4; ++r) {
      const int ri = tw * 16 + fq * 4 + r;   // t for Obs, d for sacc
      const int cj = td * 16 + fr;           // d for Obs, j for sacc
      sacc[r] += bf2f(Um[ri * 64 + swz(ri, cj)]);
      Obs[ri * 64 + cj] = f2bf(bf2f(Obl[ri * 64 + cj]) + ao[r]);
    }
    asm volatile("s_waitcnt lgkmcnt(0)" ::: "memory");
    __builtin_amdgcn_s_barrier();   // all waves done reading Sb; Obs visible
    // Sb <- new S (bf16)
#pragma unroll
    for (int r = 0; r < 4; ++r) {
      const int d = tw * 16 + fq * 4 + r, j = td * 16 + fr;
      Sb[d * 64 + swz(d, j)] = f2bf(sacc[r]);
    }
    // vectorized O writeout (full 128B rows)
    if (tid < 512) {
      const int row = tid >> 3, seg = (tid & 7) * 8;
      *(u16x8*)&ob[(tg + row) * 1024 + h * 64 + seg] = *(const u16x8*)&Obs[row * 64 + seg];
    }
    asm volatile("s_waitcnt lgkmcnt(0)" ::: "memory");
    __builtin_amdgcn_sched_barrier(0);
  }
}

extern "C" void kernel_launch(void* const* d_in, const int* in_sizes, int n_in,
                              void* d_out, int out_size, void* d_ws, size_t ws_size,
                              hipStream_t stream) {
  const float* x    = (const float*)d_in[0];
  const float* Wqkv = (const float*)d_in[1];
  const float* Wg   = (const float*)d_in[2];
  const float* bg   = (const float*)d_in[3];
  const float* Wb   = (const float*)d_in[4];
  const float* bb   = (const float*)d_in[5];
  const float* Wout = (const float*)d_in[6];
  float* out = (float*)d_out;

  char* ws = (char*)d_ws;
  u16* xb    = (u16*)ws;                               // 16384*1024   (32MB)
  u16* wqkvb = xb    + (long)BT * NDIM;                // 3072*1024    (6MB)
  u16* woutb = wqkvb + (long)3072 * 1024;              // 1024*1024    (2MB)
  u16* wgbb  = woutb + (long)1024 * 1024;              // 128*1024
  u16* qkvb  = wgbb  + (long)128 * 1024;               // [48][BT][64] (96MB)
  u16* ob    = qkvb  + (long)BT * 3072;                // 16384*1024   (32MB)
  float* graw  = (float*)(ob + (long)BT * NDIM);       // 16384*128    (8MB)
  float* alpha = graw + (long)BT * 128;                // 16384*16     (1MB)
  float* beta  = alpha + (long)BT * NH;                // 16384*16     (1MB)
  float* A63G  = graw;   // reuse: graw dead after k_gates_fin (needs 16KB)
  u16*   oi    = xb;     // reuse: xb dead after gates GEMM; NU*4096 u16 = 32MB exact

  // 1. converts
  k_f32_to_bf16<<<(BT * (long)NDIM / 4 + 255) / 256, 256, 0, stream>>>(x, xb, BT * (long)NDIM / 4);
  k_f32_to_bf16<<<(3072L * 1024 / 4 + 255) / 256, 256, 0, stream>>>(Wqkv, wqkvb, 3072L * 1024 / 4);
  k_f32_to_bf16<<<(1024L * 1024 / 4 + 255) / 256, 256, 0, stream>>>(Wout, woutb, 1024L * 1024 / 4);
  k_build_wgb<<<(128 * 1024) / 256, 256, 0, stream>>>(Wg, Wb, wgbb);

  // 2. qkv GEMM (256^2 8-phase, head-major output)
  k_gemm256<u16, true><<<64 * 12, 512, 0, stream>>>(xb, wqkvb, qkvb, BT, 3072, NDIM);

  // 3. gates GEMM (N=128, old path) + finalize
  k_gemm_bt<float><<<dim3(1, BT / 128), 256, 0, stream>>>(xb, wgbb, graw, BT, 128, NDIM);
  k_gates_fin<<<(BT * NH + 255) / 256, 256, 0, stream>>>(graw, bg, bb, alpha, beta);

  // 4. chunked WY: parallel precompute + sequential chunk GEMMs (16-wave)
  k_prep<<<NU, 256, 0, stream>>>(qkvb, alpha, beta, A63G, oi);
  k_seq<<<NPAIR, 1024, 0, stream>>>(qkvb, oi, A63G, ob);

  // 5. out GEMM (256^2 8-phase): 16384x1024 = ob @ woutb^T (fp32 out)
  k_gemm256<float, false><<<64 * 4, 512, 0, stream>>>(ob, woutb, out, BT, NDIM, NDIM);
}

// Round 12
// 362.884 us; speedup vs baseline: 1.3399x; 1.0703x over previous
//
#include <hip/hip_runtime.h>
#include <hip/hip_bf16.h>

// Problem constants
#define NB   4
#define NT   4096
#define BT   16384   // NB*NT
#define NDIM 1024
#define NH   16
#define NDH  64
#define CC   64              // chunk size (time steps)
#define NCH  (NT / CC)       // 64 chunks per pair
#define NPAIR 64             // B*H
#define NU   (NPAIR * NCH)   // 4096 units
#define DBS  24              // Db row stride (u16 elems), padded for banks

using u16 = unsigned short;
typedef __bf16 bf16x8 __attribute__((ext_vector_type(8)));
typedef float f32x4 __attribute__((ext_vector_type(4)));
typedef unsigned short u16x8 __attribute__((ext_vector_type(8)));
typedef unsigned short u16x4 __attribute__((ext_vector_type(4)));

__device__ __forceinline__ float bf2f(u16 b) { return __uint_as_float(((unsigned)b) << 16); }
__device__ __forceinline__ u16 f2bf(float f) {
  return __builtin_bit_cast(u16, __float2bfloat16(f));
}
// LDS row swizzle (u16-element index, 8-elem granular): breaks stride-128B bank conflicts
__device__ __forceinline__ int swz(int row, int e) { return e ^ ((row & 7) << 3); }
__device__ __forceinline__ bf16x8 zfrag() {
  u16x8 z = {0, 0, 0, 0, 0, 0, 0, 0};
  return __builtin_bit_cast(bf16x8, z);
}
// head-major qkv layout: [slot(3)][head(16)][bt(BT)][d(64)] — per-(h,chunk) tile contiguous
__device__ __forceinline__ long qkvT_idx(int s, int h, long bt, int d) {
  return ((long)(s * 16 + h) * BT + bt) * 64 + d;
}

// ---------------- convert fp32 -> bf16 (vectorized) ----------------
__global__ __launch_bounds__(256) void k_f32_to_bf16(const float* __restrict__ in,
                                                     u16* __restrict__ out, long n4) {
  long i = (long)blockIdx.x * blockDim.x + threadIdx.x;
  if (i >= n4) return;
  float4 f = reinterpret_cast<const float4*>(in)[i];
  u16x4 o;
  o.x = f2bf(f.x); o.y = f2bf(f.y); o.z = f2bf(f.z); o.w = f2bf(f.w);
  reinterpret_cast<u16x4*>(out)[i] = o;
}

// ---------------- build padded gate weight matrix (128 x 1024 bf16) ----------------
__global__ __launch_bounds__(256) void k_build_wgb(const float* __restrict__ Wg,
                                                   const float* __restrict__ Wb,
                                                   u16* __restrict__ out) {
  int i = blockIdx.x * 256 + threadIdx.x;
  int row = i >> 10, col = i & 1023;
  float f = 0.f;
  if (row < 16)       f = Wg[row * 1024 + col];
  else if (row < 32)  f = Wb[(row - 16) * 1024 + col];
  out[i] = f2bf(f);
}

// ---------------- global_load_lds helper ----------------
typedef unsigned int u32_as1 __attribute__((address_space(1)));
typedef unsigned int u32_as3 __attribute__((address_space(3)));
__device__ __forceinline__ void gload_lds16(const void* g, void* l) {
  __builtin_amdgcn_global_load_lds((const u32_as1*)g, (u32_as3*)l, 16, 0, 0);
}

// ============ 256x256-tile 8-phase bf16 GEMM: C = A(MxK) @ B(NxK)^T ==========
// QKVT=true: write head-major qkv layout [48][BT][64] instead of [BT][3072].
template <typename OutT, bool QKVT>
__global__ __launch_bounds__(512, 2) void k_gemm256(const u16* __restrict__ A,
                                                    const u16* __restrict__ B,
                                                    OutT* __restrict__ C,
                                                    int M, int N, int K) {
  __shared__ __align__(16) u16 As[2][2][256 * 32];
  __shared__ __align__(16) u16 Bs[2][2][256 * 32];
  const int tid = threadIdx.x;
  const int l = tid & 63, w = tid >> 6;
  const int wm = w >> 2, wn = w & 3;          // 2 x 4 wave grid
  const int fr = l & 15, fq = l >> 4;
  const int nwg = gridDim.x;
  const int cpx = nwg >> 3;
  const int bid = blockIdx.x;
  const int sbid = (bid & 7) * cpx + (bid >> 3);
  const int ntn = N >> 8;
  const int tm = sbid / ntn, tn = sbid - tm * ntn;
  const long a0 = (long)tm * 256 * K;
  const long b0 = (long)tn * 256 * K;
  const int srow0 = tid >> 2;
  const int scol8 = (((tid & 3) ^ ((tid >> 4) & 3)) << 3);
  const int cswz = ((fq ^ ((fr >> 2) & 3)) << 3);
  const int NKT = K >> 6;

  auto stage_half = [&](int kt, int buf, int hf) {
    const int ks = hf >> 1;
    const u16* Gp = (hf & 1) ? B : A;
    const long g0 = ((hf & 1) ? b0 : a0) + (long)kt * 64 + ks * 32 + scol8;
    u16* lb = (hf & 1) ? &Bs[buf][ks][w * 512] : &As[buf][ks][w * 512];
#pragma unroll
    for (int r = 0; r < 2; ++r)
      gload_lds16(Gp + g0 + (long)(r * 128 + srow0) * K, lb + r * 4096);
  };

  f32x4 acc[8][4];
#pragma unroll
  for (int m = 0; m < 8; ++m)
#pragma unroll
    for (int n = 0; n < 4; ++n) acc[m][n] = f32x4{0.f, 0.f, 0.f, 0.f};

  stage_half(0, 0, 0); stage_half(0, 0, 1); stage_half(0, 0, 2); stage_half(0, 0, 3);

  for (int kt = 0; kt < NKT; ++kt) {
    const int bi = kt & 1;
    const bool pf = (kt + 1 < NKT);
    asm volatile("s_waitcnt vmcnt(4)" ::: "memory");
    __builtin_amdgcn_sched_barrier(0);
    __builtin_amdgcn_s_barrier();
    __builtin_amdgcn_sched_barrier(0);
    {
      const u16* ap = &As[bi][0][(wm * 128 + fr) * 32 + cswz];
      const u16* bp = &Bs[bi][0][(wn * 64 + fr) * 32 + cswz];
      bf16x8 bfr[4], afr[4];
#pragma unroll
      for (int n = 0; n < 4; ++n) bfr[n] = *(const bf16x8*)(bp + n * 512);
#pragma unroll
      for (int m = 0; m < 4; ++m) afr[m] = *(const bf16x8*)(ap + m * 512);
      if (pf) stage_half(kt + 1, bi ^ 1, 0);
      __builtin_amdgcn_s_setprio(1);
#pragma unroll
      for (int m = 0; m < 4; ++m)
#pragma unroll
        for (int n = 0; n < 4; ++n)
          acc[m][n] = __builtin_amdgcn_mfma_f32_16x16x32_bf16(afr[m], bfr[n], acc[m][n], 0, 0, 0);
      __builtin_amdgcn_s_setprio(0);
#pragma unroll
      for (int m = 0; m < 4; ++m) afr[m] = *(const bf16x8*)(ap + (4 + m) * 512);
      if (pf) stage_half(kt + 1, bi ^ 1, 1);
      __builtin_amdgcn_s_setprio(1);
#pragma unroll
      for (int m = 0; m < 4; ++m)
#pragma unroll
        for (int n = 0; n < 4; ++n)
          acc[4 + m][n] = __builtin_amdgcn_mfma_f32_16x16x32_bf16(afr[m], bfr[n], acc[4 + m][n], 0, 0, 0);
      __builtin_amdgcn_s_setprio(0);
    }
    if (pf) { asm volatile("s_waitcnt vmcnt(4)" ::: "memory"); }
    else    { asm volatile("s_waitcnt vmcnt(0)" ::: "memory"); }
    __builtin_amdgcn_sched_barrier(0);
    __builtin_amdgcn_s_barrier();
    __builtin_amdgcn_sched_barrier(0);
    {
      const u16* ap = &As[bi][1][(wm * 128 + fr) * 32 + cswz];
      const u16* bp = &Bs[bi][1][(wn * 64 + fr) * 32 + cswz];
      bf16x8 bfr[4], afr[4];
#pragma unroll
      for (int n = 0; n < 4; ++n) bfr[n] = *(const bf16x8*)(bp + n * 512);
#pragma unroll
      for (int m = 0; m < 4; ++m) afr[m] = *(const bf16x8*)(ap + m * 512);
      if (pf) stage_half(kt + 1, bi ^ 1, 2);
      __builtin_amdgcn_s_setprio(1);
#pragma unroll
      for (int m = 0; m < 4; ++m)
#pragma unroll
        for (int n = 0; n < 4; ++n)
          acc[m][n] = __builtin_amdgcn_mfma_f32_16x16x32_bf16(afr[m], bfr[n], acc[m][n], 0, 0, 0);
      __builtin_amdgcn_s_setprio(0);
#pragma unroll
      for (int m = 0; m < 4; ++m) afr[m] = *(const bf16x8*)(ap + (4 + m) * 512);
      if (pf) stage_half(kt + 1, bi ^ 1, 3);
      __builtin_amdgcn_s_setprio(1);
#pragma unroll
      for (int m = 0; m < 4; ++m)
#pragma unroll
        for (int n = 0; n < 4; ++n)
          acc[4 + m][n] = __builtin_amdgcn_mfma_f32_16x16x32_bf16(afr[m], bfr[n], acc[4 + m][n], 0, 0, 0);
      __builtin_amdgcn_s_setprio(0);
    }
  }

#pragma unroll
  for (int m = 0; m < 8; ++m)
#pragma unroll
    for (int n = 0; n < 4; ++n) {
      const int row0 = tm * 256 + wm * 128 + m * 16 + fq * 4;
      const int col  = tn * 256 + wn * 64 + n * 16 + fr;
#pragma unroll
      for (int r = 0; r < 4; ++r) {
        if constexpr (QKVT) {
          const int hb = (tn * 256 + wn * 64) >> 6;
          long idx = ((long)hb * BT + (row0 + r)) * 64 + (n * 16 + fr);
          C[idx] = (OutT)f2bf(acc[m][n][r]);
        } else {
          long idx = (long)(row0 + r) * N + col;
          if constexpr (sizeof(OutT) == 2) C[idx] = f2bf(acc[m][n][r]);
          else                             C[idx] = acc[m][n][r];
        }
      }
    }
}

// ---------------- fused gates GEMM: sigmoid(x @ Wgb[0:32]^T + bias) ----------
// M-tile 128, N=32, K=1024 (BK=64). 128 blocks x 256 threads (4 waves).
// Wave w owns rows w*32..w*32+32; n=0 -> alpha (h=fr), n=1 -> beta.
__global__ __launch_bounds__(256) void k_gates(const u16* __restrict__ xb,
                                               const u16* __restrict__ wgb,
                                               const float* __restrict__ bg,
                                               const float* __restrict__ bb,
                                               float* __restrict__ alpha,
                                               float* __restrict__ beta) {
  __shared__ __align__(16) u16 As[128 * 64];   // 16KB
  __shared__ __align__(16) u16 Bs[32 * 64];    // 4KB
  const int tid = threadIdx.x, l = tid & 63, w = tid >> 6;
  const int fr = l & 15, fq = l >> 4;
  const int tm = blockIdx.x;
  const long a0 = (long)tm * 128 * 1024;

  f32x4 acc[2][2];
#pragma unroll
  for (int m = 0; m < 2; ++m)
#pragma unroll
    for (int n = 0; n < 2; ++n) acc[m][n] = f32x4{0.f, 0.f, 0.f, 0.f};

  for (int kk = 0; kk < 1024; kk += 64) {
    __syncthreads();
    // stage A 128x64 (pre-swizzled source -> linear LDS = swizzled layout)
#pragma unroll
    for (int p = 0; p < 4; ++p) {
      const int idx = p * 256 + tid;
      const int row = idx >> 3;
      const int c8 = ((idx & 7) ^ (row & 7)) << 3;
      gload_lds16(&xb[a0 + (long)row * 1024 + kk + c8], &As[p * 2048 + w * 512]);
    }
    // stage B 32x64
    {
      const int row = tid >> 3;
      const int c8 = ((tid & 7) ^ (row & 7)) << 3;
      gload_lds16(&wgb[(long)row * 1024 + kk + c8], &Bs[w * 512]);
    }
    asm volatile("s_waitcnt vmcnt(0)" ::: "memory");
    __syncthreads();
#pragma unroll
    for (int ks = 0; ks < 2; ++ks) {
      bf16x8 af[2], bfv[2];
#pragma unroll
      for (int m = 0; m < 2; ++m) {
        const int row = w * 32 + m * 16 + fr;
        af[m] = __builtin_bit_cast(bf16x8, *(const u16x8*)&As[row * 64 + swz(row, ks * 32 + fq * 8)]);
      }
#pragma unroll
      for (int n = 0; n < 2; ++n) {
        const int row = n * 16 + fr;
        bfv[n] = __builtin_bit_cast(bf16x8, *(const u16x8*)&Bs[row * 64 + swz(row, ks * 32 + fq * 8)]);
      }
#pragma unroll
      for (int m = 0; m < 2; ++m)
#pragma unroll
        for (int n = 0; n < 2; ++n)
          acc[m][n] = __builtin_amdgcn_mfma_f32_16x16x32_bf16(af[m], bfv[n], acc[m][n], 0, 0, 0);
    }
  }
  const float bgv = bg[fr], bbv = bb[fr];
#pragma unroll
  for (int m = 0; m < 2; ++m)
#pragma unroll
    for (int r = 0; r < 4; ++r) {
      const long row = (long)tm * 128 + w * 32 + m * 16 + fq * 4 + r;
      alpha[row * 16 + fr] = 1.f / (1.f + __expf(-(acc[m][0][r] + bgv)));
      beta[row * 16 + fr]  = 1.f / (1.f + __expf(-(acc[m][1][r] + bbv)));
    }
}

// ================= chunked WY scan (MFMA block-solve, fused l2norm) =======
// R8-proven structure; this round: exp2f -> Avec*Ainv table products, and P8
// stores reordered r-outer (4 line-covering stores issued back-to-back).
__global__ __launch_bounds__(256, 3) void k_prep(u16* __restrict__ qkv,
                                                 const float* __restrict__ alpha,
                                                 const float* __restrict__ beta,
                                                 float* __restrict__ A63G,
                                                 u16* __restrict__ oi) {
  __shared__ __align__(16) u16 Ks[64 * 64];
  __shared__ __align__(16) u16 WTs[128 * 64];   // rows 0-63: VbT->WvT; 64-127: KbT->TwT
  __shared__ __align__(16) u16 Lb[64 * 64];     // L (b-scaled), later -L~ in 6 sub-blocks
  __shared__ __align__(16) u16 MqS[64 * 64];
  __shared__ __align__(16) u16 KdT[64 * 64];
  __shared__ __align__(16) u16 Db[4 * 16 * DBS];
  __shared__ float cvec[64], Avec[64], Ainvv[64], bvec[64], nkinv[64], nqinv[64];

  const int unit = blockIdx.x;
  const int pair = unit >> 6, ch = unit & 63;
  const int b = pair >> 4, h = pair & 15;
  const int tid = threadIdx.x, l = tid & 63, w = tid >> 6;
  const int fr = l & 15, fq = l >> 4;
  const long t0 = (long)b * NT + (long)ch * CC;

  // ---- P0: issue global loads into regs; wave0 cumsum ----
  u16x8 kreg[2], vreg[2], qreg[2];
  int srow_[2], sseg_[2];
#pragma unroll
  for (int p = 0; p < 2; ++p) {
    int idx = p * 256 + tid;
    srow_[p] = idx >> 3; sseg_[p] = (idx & 7) * 8;
    qreg[p] = *(const u16x8*)&qkv[qkvT_idx(0, h, t0 + srow_[p], sseg_[p])];
    kreg[p] = *(const u16x8*)&qkv[qkvT_idx(1, h, t0 + srow_[p], sseg_[p])];
    vreg[p] = *(const u16x8*)&qkv[qkvT_idx(2, h, t0 + srow_[p], sseg_[p])];
  }
  const int ar = w * 16 + fr;
  u16x8 qa[2];
#pragma unroll
  for (int kk = 0; kk < 2; ++kk)
    qa[kk] = *(const u16x8*)&qkv[qkvT_idx(0, h, t0 + ar, kk * 32 + fq * 8)];

  if (w == 0) {
    float av = alpha[(t0 + l) * 16 + h];
    float bv = beta[(t0 + l) * 16 + h];
    float cl = __log2f(av);
#pragma unroll
    for (int d = 1; d < 64; d <<= 1) {
      float up = __shfl_up(cl, d);
      if (l >= d) cl += up;
    }
    float A = exp2f(cl);
    cvec[l] = cl; Avec[l] = A; Ainvv[l] = exp2f(-cl); bvec[l] = bv;
    if (l == 63) A63G[unit] = A;
  }
  __syncthreads();

  // ---- P1: stage Ks rows + VbT (b-scaled, transposed); norms via shuffle ----
#pragma unroll
  for (int p = 0; p < 2; ++p) {
    int row = srow_[p], seg = sseg_[p];
    *(u16x8*)&Ks[row * 64 + swz(row, seg)] = kreg[p];
    float kss = 0.f, qss = 0.f;
    const float bs = bvec[row];
#pragma unroll
    for (int e = 0; e < 8; ++e) {
      float kf = bf2f(kreg[p][e]), qf = bf2f(qreg[p][e]);
      kss += kf * kf; qss += qf * qf;
      int c = seg + e;
      WTs[c * 64 + swz(c, row)] = f2bf(bs * bf2f(vreg[p][e]));
    }
    kss += __shfl_xor(kss, 1); kss += __shfl_xor(kss, 2); kss += __shfl_xor(kss, 4);
    qss += __shfl_xor(qss, 1); qss += __shfl_xor(qss, 2); qss += __shfl_xor(qss, 4);
    if ((tid & 7) == 0) { nkinv[row] = kss; nqinv[row] = qss; }
  }
  __syncthreads();

  // ---- P2: inverse norms ----
  if (tid < 64)       nkinv[tid] = rsqrtf(fmaxf(nkinv[tid], 1e-24f));
  else if (tid < 128) nqinv[tid - 64] = rsqrtf(fmaxf(nqinv[tid - 64], 1e-24f));
  __syncthreads();

  // ---- P3: KK^T + QK^T MFMA; build KbT & KdT; L/Mq epilogue ----
  f32x4 akk[4], aqk[4];
#pragma unroll
  for (int n = 0; n < 4; ++n) { akk[n] = f32x4{0, 0, 0, 0}; aqk[n] = f32x4{0, 0, 0, 0}; }
  {
    bf16x8 afK[2], afQ[2];
#pragma unroll
    for (int kk = 0; kk < 2; ++kk) {
      afK[kk] = __builtin_bit_cast(bf16x8, *(const u16x8*)&Ks[ar * 64 + swz(ar, kk * 32 + fq * 8)]);
      afQ[kk] = __builtin_bit_cast(bf16x8, qa[kk]);
    }
#pragma unroll
    for (int n = 0; n < 4; ++n) {
      const int br = n * 16 + fr;
#pragma unroll
      for (int kk = 0; kk < 2; ++kk) {
        bf16x8 bk = __builtin_bit_cast(bf16x8, *(const u16x8*)&Ks[br * 64 + swz(br, kk * 32 + fq * 8)]);
        akk[n] = __builtin_amdgcn_mfma_f32_16x16x32_bf16(afK[kk], bk, akk[n], 0, 0, 0);
        aqk[n] = __builtin_amdgcn_mfma_f32_16x16x32_bf16(afQ[kk], bk, aqk[n], 0, 0, 0);
      }
    }
  }
  {
    const int j = tid & 63, tg4 = tid >> 6;
    const float A63v = Avec[63];
    u16 kb[16], kd[16];
#pragma unroll
    for (int tt = 0; tt < 16; ++tt) {
      int t = tg4 * 16 + tt;
      float kv = bf2f(Ks[t * 64 + swz(t, j)]) * nkinv[t];
      kb[tt] = f2bf(bvec[t] * Avec[t] * kv);
      kd[tt] = f2bf(A63v * Ainvv[t] * kv);
    }
#pragma unroll
    for (int g8 = 0; g8 < 2; ++g8) {
      u16x8 o1, o2;
#pragma unroll
      for (int e = 0; e < 8; ++e) { o1[e] = kb[g8 * 8 + e]; o2[e] = kd[g8 * 8 + e]; }
      int colg = tg4 * 16 + g8 * 8;
      *(u16x8*)&WTs[(64 + j) * 64 + swz(64 + j, colg)] = o1;
      *(u16x8*)&KdT[j * 64 + swz(j, colg)] = o2;
    }
  }
#pragma unroll
  for (int n = 0; n < 4; ++n)
#pragma unroll
    for (int r = 0; r < 4; ++r) {
      const int t = w * 16 + fq * 4 + r;
      const int s = n * 16 + fr;
      const float e = Avec[t] * Ainvv[s];
      Lb[t * 64 + swz(t, s)] = (s < t) ? f2bf(bvec[t] * e * nkinv[t] * nkinv[s] * akk[n][r]) : (u16)0;
      MqS[t * 64 + swz(t, s)] = (s <= t) ? f2bf(e * nqinv[t] * nkinv[s] * aqk[n][r]) : (u16)0;
    }
  __syncthreads();

  // ---- P4: Dinv of the 4 diagonal 16x16 blocks (wave w owns block w) ----
  if (l < 16) {
    const int c = l;
    const int rb = w * 16;
    float x[16];
#pragma unroll
    for (int u = 0; u < 16; ++u) {
      float a2 = (u == c) ? 1.f : 0.f;
#pragma unroll
      for (int s = 0; s < u; ++s)
        a2 -= bf2f(Lb[(rb + u) * 64 + swz(rb + u, rb + s)]) * x[s];
      x[u] = a2;
    }
#pragma unroll
    for (int u = 0; u < 16; ++u)
      Db[w * 16 * DBS + u * DBS + c] = f2bf(x[u]);
  }
  __syncthreads();

  // ---- P5: L~ = Dinv.L (scalar, store NEGATED); R~T = RT.DinvT (MFMA) ----
  float ltil[6];
  {
    const int pbi[6] = {1, 2, 2, 3, 3, 3}, pbj[6] = {0, 0, 1, 0, 1, 2};
    const int tt = tid >> 4, s = tid & 15;
#pragma unroll
    for (int e = 0; e < 6; ++e) {
      int bi = pbi[e], bj = pbj[e];
      float a2 = 0.f;
#pragma unroll
      for (int u = 0; u < 16; ++u)
        a2 += bf2f(Db[bi * 16 * DBS + tt * DBS + u]) *
              bf2f(Lb[(bi * 16 + u) * 64 + swz(bi * 16 + u, bj * 16 + s)]);
      ltil[e] = a2;
    }
  }
  f32x4 rtacc[2][4];
#pragma unroll
  for (int rt2 = 0; rt2 < 2; ++rt2) {
    const int rrow = (w * 2 + rt2) * 16 + fr;
#pragma unroll
    for (int bi = 0; bi < 4; ++bi) {
      bf16x8 a2 = (fq < 2)
        ? __builtin_bit_cast(bf16x8, *(const u16x8*)&WTs[rrow * 64 + swz(rrow, bi * 16 + fq * 8)])
        : zfrag();
      bf16x8 b2 = (fq < 2)
        ? __builtin_bit_cast(bf16x8, *(const u16x8*)&Db[bi * 16 * DBS + fr * DBS + fq * 8])
        : zfrag();
      rtacc[rt2][bi] = __builtin_amdgcn_mfma_f32_16x16x32_bf16(a2, b2, f32x4{0, 0, 0, 0}, 0, 0, 0);
    }
  }
  __syncthreads();   // all L~/R~ reads done before overwrites
  {
    const int pbi[6] = {1, 2, 2, 3, 3, 3}, pbj[6] = {0, 0, 1, 0, 1, 2};
    const int tt = tid >> 4, s = tid & 15;
#pragma unroll
    for (int e = 0; e < 6; ++e)
      Lb[(pbi[e] * 16 + tt) * 64 + swz(pbi[e] * 16 + tt, pbj[e] * 16 + s)] = f2bf(-ltil[e]);
  }
#pragma unroll
  for (int rt2 = 0; rt2 < 2; ++rt2)
#pragma unroll
    for (int bi = 0; bi < 4; ++bi)
#pragma unroll
      for (int r = 0; r < 4; ++r) {
        int rr = (w * 2 + rt2) * 16 + fq * 4 + r;
        WTs[rr * 64 + swz(rr, bi * 16 + fr)] = f2bf(rtacc[rt2][bi][r]);
      }
  __syncthreads();

  // ---- P6: 3-step MFMA substitution (row-tiles wave-exclusive, no barriers) ----
#pragma unroll
  for (int rt2 = 0; rt2 < 2; ++rt2) {
    const int rrow = (w * 2 + rt2) * 16 + fr;
    const int wr0 = (w * 2 + rt2) * 16 + fq * 4;
#pragma unroll
    for (int i = 1; i < 4; ++i) {
      f32x4 a2;
#pragma unroll
      for (int r = 0; r < 4; ++r)
        a2[r] = bf2f(WTs[(wr0 + r) * 64 + swz(wr0 + r, i * 16 + fr)]);
      {
        bf16x8 af = __builtin_bit_cast(bf16x8, *(const u16x8*)&WTs[rrow * 64 + swz(rrow, fq * 8)]);
        bf16x8 bf_;
        if (i == 1) bf_ = (fq < 2)
          ? __builtin_bit_cast(bf16x8, *(const u16x8*)&Lb[(16 + fr) * 64 + swz(16 + fr, fq * 8)])
          : zfrag();
        else bf_ = __builtin_bit_cast(bf16x8, *(const u16x8*)&Lb[(i * 16 + fr) * 64 + swz(i * 16 + fr, fq * 8)]);
        a2 = __builtin_amdgcn_mfma_f32_16x16x32_bf16(af, bf_, a2, 0, 0, 0);
      }
      if (i == 3) {
        bf16x8 af = __builtin_bit_cast(bf16x8, *(const u16x8*)&WTs[rrow * 64 + swz(rrow, 32 + fq * 8)]);
        bf16x8 bf_ = (fq < 2)
          ? __builtin_bit_cast(bf16x8, *(const u16x8*)&Lb[(48 + fr) * 64 + swz(48 + fr, 32 + fq * 8)])
          : zfrag();
        a2 = __builtin_amdgcn_mfma_f32_16x16x32_bf16(af, bf_, a2, 0, 0, 0);
      }
#pragma unroll
      for (int r = 0; r < 4; ++r)
        WTs[(wr0 + r) * 64 + swz(wr0 + r, i * 16 + fr)] = f2bf(a2[r]);
    }
  }
  __syncthreads();

  // ---- P7: final 4 GEMMs ----
  u16 qpre[4][4];
#pragma unroll
  for (int n = 0; n < 4; ++n)
#pragma unroll
    for (int r = 0; r < 4; ++r)
      qpre[n][r] = qkv[qkvT_idx(0, h, t0 + w * 16 + fq * 4 + r, n * 16 + fr)];

  f32x4 aG[4], aU[4], aQe[4], aOi[4];
#pragma unroll
  for (int n = 0; n < 4; ++n) {
    aG[n] = f32x4{0, 0, 0, 0}; aU[n] = f32x4{0, 0, 0, 0};
    aQe[n] = f32x4{0, 0, 0, 0}; aOi[n] = f32x4{0, 0, 0, 0};
  }
  {
    bf16x8 aKd[2], aWv[2], aMq[2];
#pragma unroll
    for (int kk = 0; kk < 2; ++kk) {
      aKd[kk] = __builtin_bit_cast(bf16x8, *(const u16x8*)&KdT[ar * 64 + swz(ar, kk * 32 + fq * 8)]);
      aWv[kk] = __builtin_bit_cast(bf16x8, *(const u16x8*)&WTs[ar * 64 + swz(ar, kk * 32 + fq * 8)]);
      aMq[kk] = __builtin_bit_cast(bf16x8, *(const u16x8*)&MqS[ar * 64 + swz(ar, kk * 32 + fq * 8)]);
    }
#pragma unroll
    for (int n = 0; n < 4; ++n) {
      const int br = n * 16 + fr;
#pragma unroll
      for (int kk = 0; kk < 2; ++kk) {
        bf16x8 bTw = __builtin_bit_cast(bf16x8, *(const u16x8*)&WTs[(64 + br) * 64 + swz(64 + br, kk * 32 + fq * 8)]);
        bf16x8 bKd = __builtin_bit_cast(bf16x8, *(const u16x8*)&KdT[br * 64 + swz(br, kk * 32 + fq * 8)]);
        bf16x8 bWv = __builtin_bit_cast(bf16x8, *(const u16x8*)&WTs[br * 64 + swz(br, kk * 32 + fq * 8)]);
        aG[n]  = __builtin_amdgcn_mfma_f32_16x16x32_bf16(aKd[kk], bTw, aG[n], 0, 0, 0);
        aU[n]  = __builtin_amdgcn_mfma_f32_16x16x32_bf16(aWv[kk], bKd, aU[n], 0, 0, 0);
        aQe[n] = __builtin_amdgcn_mfma_f32_16x16x32_bf16(aMq[kk], bTw, aQe[n], 0, 0, 0);
        aOi[n] = __builtin_amdgcn_mfma_f32_16x16x32_bf16(aMq[kk], bWv, aOi[n], 0, 0, 0);
      }
    }
  }
  // ---- P8: scattered stores, r-outer so the 4 stores covering one 128B line
  //          issue back-to-back (write-combine); O_intra via dead Ks ----
  asm volatile("s_waitcnt vmcnt(0)" ::: "memory");   // qpre loaded before slot overwrite
  __builtin_amdgcn_sched_barrier(0);
#pragma unroll
  for (int r = 0; r < 4; ++r) {
    const int i = w * 16 + fq * 4 + r;
#pragma unroll
    for (int n = 0; n < 4; ++n)
      qkv[qkvT_idx(0, h, t0 + i, swz(i, n * 16 + fr))] =
        f2bf(Avec[i] * nqinv[i] * bf2f(qpre[n][r]) - aQe[n][r]);
    __builtin_amdgcn_sched_barrier(0);
#pragma unroll
    for (int n = 0; n < 4; ++n)
      qkv[qkvT_idx(1, h, t0 + i, swz(i, n * 16 + fr))] = f2bf(-aG[n][r]);
    __builtin_amdgcn_sched_barrier(0);
#pragma unroll
    for (int n = 0; n < 4; ++n)
      qkv[qkvT_idx(2, h, t0 + i, swz(i, n * 16 + fr))] = f2bf(aU[n][r]);
    __builtin_amdgcn_sched_barrier(0);
#pragma unroll
    for (int n = 0; n < 4; ++n)
      Ks[i * 64 + n * 16 + fr] = f2bf(aOi[n][r]);   // Ks dead since P3
  }
  __syncthreads();
#pragma unroll
  for (int p = 0; p < 2; ++p) {
    const int idx = p * 256 + tid;
    const int row = idx >> 3, seg = (idx & 7) * 8;
    *(u16x8*)&oi[(long)unit * 4096 + row * 64 + seg] = *(const u16x8*)&Ks[row * 64 + seg];
  }
}

// ---------------- sequential chunk recurrence (16 waves, 1 barrier/chunk) -----
// 64 blocks x 1024 threads. Wave w owns tile (tw,td) of O_cross and S.
// Single barrier per chunk: Sb & Obs double-buffered, stg triple-buffered.
// Per-iter VMEM program order (waves 0-7): [writeout store x1][stage x4].
// vmcnt derivation: c in {0,1} -> 4; c in [2,NCH-2] -> 5; c=NCH-1 -> 1.
__global__ __launch_bounds__(1024) void k_seq(const u16* __restrict__ qkv,
                                              const u16* __restrict__ oi,
                                              const float* __restrict__ A63G,
                                              u16* __restrict__ ob) {
  __shared__ __align__(16) u16 Sb[2][64 * 64];
  __shared__ __align__(16) u16 Obs[2][64 * 64];
  __shared__ __align__(16) u16 stg[3][4][64 * 64];   // 96KB
  __shared__ float a63s[64];
  const int pair = blockIdx.x;
  const int b = pair >> 4, h = pair & 15;
  const int tid = threadIdx.x, l = tid & 63, w = tid >> 6;   // w 0..15
  const int fr = l & 15, fq = l >> 4;
  const int tw = w >> 2, td = w & 3;

  auto stage = [&](int c) {
    const int s = c % 3;
    const long tg = (long)b * NT + (long)c * CC;
    if (tid < 512) {
      const int row = tid >> 3, seg = (tid & 7) * 8;
#pragma unroll
      for (int m = 0; m < 4; ++m) {
        const u16* src = (m < 3)
          ? &qkv[qkvT_idx(m, h, tg + row, seg)]
          : &oi[(long)(pair * 64 + c) * 4096 + row * 64 + seg];
        gload_lds16(src, &stg[s][m][row * 64 + seg]);
      }
    }
  };

  if (tid < 64) a63s[tid] = A63G[pair * 64 + tid];
  for (int i = tid; i < 4096; i += 1024) Sb[0][i] = 0;
  stage(0); stage(1);
  f32x4 sacc = f32x4{0, 0, 0, 0};
  asm volatile("s_waitcnt lgkmcnt(0)" ::: "memory");
  __builtin_amdgcn_sched_barrier(0);

  for (int c = 0; c < NCH; ++c) {
    const int sb = c & 1, st = c % 3;
    const long tg = (long)b * NT + (long)c * CC;
    if (c <= 1)             { asm volatile("s_waitcnt vmcnt(4)" ::: "memory"); }
    else if (c < NCH - 1)   { asm volatile("s_waitcnt vmcnt(5)" ::: "memory"); }
    else                    { asm volatile("s_waitcnt vmcnt(1)" ::: "memory"); }
    __builtin_amdgcn_sched_barrier(0);
    __builtin_amdgcn_s_barrier();
    __builtin_amdgcn_sched_barrier(0);

    // writeout previous chunk's O (Obs[(c-1)&1], visible since last iter's drain)
    if (c > 0 && tid < 512) {
      const int row = tid >> 3, seg = (tid & 7) * 8;
      *(u16x8*)&ob[(tg - CC + row) * 1024 + h * 64 + seg] = *(const u16x8*)&Obs[sb ^ 1][row * 64 + seg];
    }
    if (c + 2 < NCH) stage(c + 2);

    const u16* Qe = stg[st][0];
    const u16* Gm = stg[st][1];
    const u16* Um = stg[st][2];
    const u16* Obl = stg[st][3];

    const int at = tw * 16 + fr;   // Qe row (t); also S row (d) for update
    const int bd = td * 16 + fr;   // Sb row (d); also G row (j) for update
    f32x4 ao = f32x4{0, 0, 0, 0};
    const float A63 = a63s[c];
#pragma unroll
    for (int r = 0; r < 4; ++r) sacc[r] *= A63;
#pragma unroll
    for (int kk = 0; kk < 2; ++kk) {
      bf16x8 aq = __builtin_bit_cast(bf16x8, *(const u16x8*)&Qe[at * 64 + swz(at, kk * 32 + fq * 8)]);
      bf16x8 sbf = __builtin_bit_cast(bf16x8, *(const u16x8*)&Sb[sb][bd * 64 + swz(bd, kk * 32 + fq * 8)]);
      ao = __builtin_amdgcn_mfma_f32_16x16x32_bf16(aq, sbf, ao, 0, 0, 0);
      bf16x8 as_ = __builtin_bit_cast(bf16x8, *(const u16x8*)&Sb[sb][at * 64 + swz(at, kk * 32 + fq * 8)]);
      bf16x8 g  = __builtin_bit_cast(bf16x8, *(const u16x8*)&Gm[bd * 64 + swz(bd, kk * 32 + fq * 8)]);
      sacc = __builtin_amdgcn_mfma_f32_16x16x32_bf16(as_, g, sacc, 0, 0, 0);
    }
    // +U, Obs[cur] staging, Sb[next] write
#pragma unroll
    for (int r = 0; r < 4; ++r) {
      const int ri = tw * 16 + fq * 4 + r;   // t for Obs, d for sacc
      const int cj = td * 16 + fr;           // d for Obs, j for sacc
      sacc[r] += bf2f(Um[ri * 64 + swz(ri, cj)]);
      Obs[sb][ri * 64 + cj] = f2bf(bf2f(Obl[ri * 64 + cj]) + ao[r]);
      Sb[sb ^ 1][ri * 64 + swz(ri, cj)] = f2bf(sacc[r]);
    }
    asm volatile("s_waitcnt lgkmcnt(0)" ::: "memory");
    __builtin_amdgcn_sched_barrier(0);
  }
  // final writeout (chunk NCH-1)
  __builtin_amdgcn_s_barrier();
  if (tid < 512) {
    const int row = tid >> 3, seg = (tid & 7) * 8;
    const long tg = (long)b * NT + (long)(NCH - 1) * CC;
    *(u16x8*)&ob[(tg + row) * 1024 + h * 64 + seg] = *(const u16x8*)&Obs[(NCH - 1) & 1][row * 64 + seg];
  }
}

extern "C" void kernel_launch(void* const* d_in, const int* in_sizes, int n_in,
                              void* d_out, int out_size, void* d_ws, size_t ws_size,
                              hipStream_t stream) {
  const float* x    = (const float*)d_in[0];
  const float* Wqkv = (const float*)d_in[1];
  const float* Wg   = (const float*)d_in[2];
  const float* bg   = (const float*)d_in[3];
  const float* Wb   = (const float*)d_in[4];
  const float* bb   = (const float*)d_in[5];
  const float* Wout = (const float*)d_in[6];
  float* out = (float*)d_out;

  char* ws = (char*)d_ws;
  u16* xb    = (u16*)ws;                               // 16384*1024   (32MB)
  u16* wqkvb = xb    + (long)BT * NDIM;                // 3072*1024    (6MB)
  u16* woutb = wqkvb + (long)3072 * 1024;              // 1024*1024    (2MB)
  u16* wgbb  = woutb + (long)1024 * 1024;              // 128*1024
  u16* qkvb  = wgbb  + (long)128 * 1024;               // [48][BT][64] (96MB)
  u16* ob    = qkvb  + (long)BT * 3072;                // 16384*1024   (32MB)
  float* graw  = (float*)(ob + (long)BT * NDIM);       // 16384*128    (8MB, A63G home)
  float* alpha = graw + (long)BT * 128;                // 16384*16     (1MB)
  float* beta  = alpha + (long)BT * NH;                // 16384*16     (1MB)
  float* A63G  = graw;
  u16*   oi    = xb;     // reuse: xb dead after k_gates; NU*4096 u16 = 32MB exact

  // 1. converts
  k_f32_to_bf16<<<(BT * (long)NDIM / 4 + 255) / 256, 256, 0, stream>>>(x, xb, BT * (long)NDIM / 4);
  k_f32_to_bf16<<<(3072L * 1024 / 4 + 255) / 256, 256, 0, stream>>>(Wqkv, wqkvb, 3072L * 1024 / 4);
  k_f32_to_bf16<<<(1024L * 1024 / 4 + 255) / 256, 256, 0, stream>>>(Wout, woutb, 1024L * 1024 / 4);
  k_build_wgb<<<(128 * 1024) / 256, 256, 0, stream>>>(Wg, Wb, wgbb);

  // 2. qkv GEMM (256^2 8-phase, head-major output)
  k_gemm256<u16, true><<<64 * 12, 512, 0, stream>>>(xb, wqkvb, qkvb, BT, 3072, NDIM);

  // 3. fused gates GEMM + sigmoid
  k_gates<<<BT / 128, 256, 0, stream>>>(xb, wgbb, bg, bb, alpha, beta);

  // 4. chunked WY: parallel precompute + sequential chunk GEMMs (16-wave)
  k_prep<<<NU, 256, 0, stream>>>(qkvb, alpha, beta, A63G, oi);
  k_seq<<<NPAIR, 1024, 0, stream>>>(qkvb, oi, A63G, ob);

  // 5. out GEMM (256^2 8-phase): 16384x1024 = ob @ woutb^T (fp32 out)
  k_gemm256<float, false><<<64 * 4, 512, 0, stream>>>(ob, woutb, out, BT, NDIM, NDIM);
}

// Round 13
// 362.024 us; speedup vs baseline: 1.3431x; 1.0024x over previous
//
#include <hip/hip_runtime.h>
#include <hip/hip_bf16.h>

// Problem constants
#define NB   4
#define NT   4096
#define BT   16384   // NB*NT
#define NDIM 1024
#define NH   16
#define NDH  64
#define CC   64              // chunk size (time steps)
#define NCH  (NT / CC)       // 64 chunks per pair
#define NPAIR 64             // B*H
#define NU   (NPAIR * NCH)   // 4096 units
#define DBS  24              // Db row stride (u16 elems), padded for banks

using u16 = unsigned short;
typedef __bf16 bf16x8 __attribute__((ext_vector_type(8)));
typedef float f32x4 __attribute__((ext_vector_type(4)));
typedef unsigned short u16x8 __attribute__((ext_vector_type(8)));
typedef unsigned short u16x4 __attribute__((ext_vector_type(4)));

__device__ __forceinline__ float bf2f(u16 b) { return __uint_as_float(((unsigned)b) << 16); }
__device__ __forceinline__ u16 f2bf(float f) {
  return __builtin_bit_cast(u16, __float2bfloat16(f));
}
// LDS row swizzle (u16-element index, 8-elem granular): breaks stride-128B bank conflicts
__device__ __forceinline__ int swz(int row, int e) { return e ^ ((row & 7) << 3); }
__device__ __forceinline__ bf16x8 zfrag() {
  u16x8 z = {0, 0, 0, 0, 0, 0, 0, 0};
  return __builtin_bit_cast(bf16x8, z);
}
// head-major qkv layout: [slot(3)][head(16)][bt(BT)][d(64)] — per-(h,chunk) tile contiguous
__device__ __forceinline__ long qkvT_idx(int s, int h, long bt, int d) {
  return ((long)(s * 16 + h) * BT + bt) * 64 + d;
}

// ---------------- convert fp32 -> bf16 (vectorized) ----------------
__global__ __launch_bounds__(256) void k_f32_to_bf16(const float* __restrict__ in,
                                                     u16* __restrict__ out, long n4) {
  long i = (long)blockIdx.x * blockDim.x + threadIdx.x;
  if (i >= n4) return;
  float4 f = reinterpret_cast<const float4*>(in)[i];
  u16x4 o;
  o.x = f2bf(f.x); o.y = f2bf(f.y); o.z = f2bf(f.z); o.w = f2bf(f.w);
  reinterpret_cast<u16x4*>(out)[i] = o;
}

// ---------------- build padded gate weight matrix (128 x 1024 bf16) ----------------
__global__ __launch_bounds__(256) void k_build_wgb(const float* __restrict__ Wg,
                                                   const float* __restrict__ Wb,
                                                   u16* __restrict__ out) {
  int i = blockIdx.x * 256 + threadIdx.x;
  int row = i >> 10, col = i & 1023;
  float f = 0.f;
  if (row < 16)       f = Wg[row * 1024 + col];
  else if (row < 32)  f = Wb[(row - 16) * 1024 + col];
  out[i] = f2bf(f);
}

// ---------------- global_load_lds helper ----------------
typedef unsigned int u32_as1 __attribute__((address_space(1)));
typedef unsigned int u32_as3 __attribute__((address_space(3)));
__device__ __forceinline__ void gload_lds16(const void* g, void* l) {
  __builtin_amdgcn_global_load_lds((const u32_as1*)g, (u32_as3*)l, 16, 0, 0);
}

// ============ 256x256-tile 8-phase bf16 GEMM: C = A(MxK) @ B(NxK)^T ==========
// QKVT=true: swapped-operand MFMA (acc holds D^T) + head-major vector epilogue
// [48][BT][64] with u16x4 stores (reg dim = contiguous d).
template <typename OutT, bool QKVT>
__global__ __launch_bounds__(512, 2) void k_gemm256(const u16* __restrict__ A,
                                                    const u16* __restrict__ B,
                                                    OutT* __restrict__ C,
                                                    int M, int N, int K) {
  __shared__ __align__(16) u16 As[2][2][256 * 32];
  __shared__ __align__(16) u16 Bs[2][2][256 * 32];
  const int tid = threadIdx.x;
  const int l = tid & 63, w = tid >> 6;
  const int wm = w >> 2, wn = w & 3;          // 2 x 4 wave grid
  const int fr = l & 15, fq = l >> 4;
  const int nwg = gridDim.x;
  const int cpx = nwg >> 3;
  const int bid = blockIdx.x;
  const int sbid = (bid & 7) * cpx + (bid >> 3);
  const int ntn = N >> 8;
  const int tm = sbid / ntn, tn = sbid - tm * ntn;
  const long a0 = (long)tm * 256 * K;
  const long b0 = (long)tn * 256 * K;
  const int srow0 = tid >> 2;
  const int scol8 = (((tid & 3) ^ ((tid >> 4) & 3)) << 3);
  const int cswz = ((fq ^ ((fr >> 2) & 3)) << 3);
  const int NKT = K >> 6;

  auto stage_half = [&](int kt, int buf, int hf) {
    const int ks = hf >> 1;
    const u16* Gp = (hf & 1) ? B : A;
    const long g0 = ((hf & 1) ? b0 : a0) + (long)kt * 64 + ks * 32 + scol8;
    u16* lb = (hf & 1) ? &Bs[buf][ks][w * 512] : &As[buf][ks][w * 512];
#pragma unroll
    for (int r = 0; r < 2; ++r)
      gload_lds16(Gp + g0 + (long)(r * 128 + srow0) * K, lb + r * 4096);
  };

  f32x4 acc[8][4];
#pragma unroll
  for (int m = 0; m < 8; ++m)
#pragma unroll
    for (int n = 0; n < 4; ++n) acc[m][n] = f32x4{0.f, 0.f, 0.f, 0.f};

  auto domfma = [&](f32x4& a, const bf16x8& af, const bf16x8& bf_) {
    if constexpr (QKVT) a = __builtin_amdgcn_mfma_f32_16x16x32_bf16(bf_, af, a, 0, 0, 0);
    else                a = __builtin_amdgcn_mfma_f32_16x16x32_bf16(af, bf_, a, 0, 0, 0);
  };

  stage_half(0, 0, 0); stage_half(0, 0, 1); stage_half(0, 0, 2); stage_half(0, 0, 3);

  for (int kt = 0; kt < NKT; ++kt) {
    const int bi = kt & 1;
    const bool pf = (kt + 1 < NKT);
    asm volatile("s_waitcnt vmcnt(4)" ::: "memory");
    __builtin_amdgcn_sched_barrier(0);
    __builtin_amdgcn_s_barrier();
    __builtin_amdgcn_sched_barrier(0);
    {
      const u16* ap = &As[bi][0][(wm * 128 + fr) * 32 + cswz];
      const u16* bp = &Bs[bi][0][(wn * 64 + fr) * 32 + cswz];
      bf16x8 bfr[4], afr[4];
#pragma unroll
      for (int n = 0; n < 4; ++n) bfr[n] = *(const bf16x8*)(bp + n * 512);
#pragma unroll
      for (int m = 0; m < 4; ++m) afr[m] = *(const bf16x8*)(ap + m * 512);
      if (pf) stage_half(kt + 1, bi ^ 1, 0);
      __builtin_amdgcn_s_setprio(1);
#pragma unroll
      for (int m = 0; m < 4; ++m)
#pragma unroll
        for (int n = 0; n < 4; ++n) domfma(acc[m][n], afr[m], bfr[n]);
      __builtin_amdgcn_s_setprio(0);
#pragma unroll
      for (int m = 0; m < 4; ++m) afr[m] = *(const bf16x8*)(ap + (4 + m) * 512);
      if (pf) stage_half(kt + 1, bi ^ 1, 1);
      __builtin_amdgcn_s_setprio(1);
#pragma unroll
      for (int m = 0; m < 4; ++m)
#pragma unroll
        for (int n = 0; n < 4; ++n) domfma(acc[4 + m][n], afr[m], bfr[n]);
      __builtin_amdgcn_s_setprio(0);
    }
    if (pf) { asm volatile("s_waitcnt vmcnt(4)" ::: "memory"); }
    else    { asm volatile("s_waitcnt vmcnt(0)" ::: "memory"); }
    __builtin_amdgcn_sched_barrier(0);
    __builtin_amdgcn_s_barrier();
    __builtin_amdgcn_sched_barrier(0);
    {
      const u16* ap = &As[bi][1][(wm * 128 + fr) * 32 + cswz];
      const u16* bp = &Bs[bi][1][(wn * 64 + fr) * 32 + cswz];
      bf16x8 bfr[4], afr[4];
#pragma unroll
      for (int n = 0; n < 4; ++n) bfr[n] = *(const bf16x8*)(bp + n * 512);
#pragma unroll
      for (int m = 0; m < 4; ++m) afr[m] = *(const bf16x8*)(ap + m * 512);
      if (pf) stage_half(kt + 1, bi ^ 1, 2);
      __builtin_amdgcn_s_setprio(1);
#pragma unroll
      for (int m = 0; m < 4; ++m)
#pragma unroll
        for (int n = 0; n < 4; ++n) domfma(acc[m][n], afr[m], bfr[n]);
      __builtin_amdgcn_s_setprio(0);
#pragma unroll
      for (int m = 0; m < 4; ++m) afr[m] = *(const bf16x8*)(ap + (4 + m) * 512);
      if (pf) stage_half(kt + 1, bi ^ 1, 3);
      __builtin_amdgcn_s_setprio(1);
#pragma unroll
      for (int m = 0; m < 4; ++m)
#pragma unroll
        for (int n = 0; n < 4; ++n) domfma(acc[4 + m][n], afr[m], bfr[n]);
      __builtin_amdgcn_s_setprio(0);
    }
  }

  if constexpr (QKVT) {
    // acc[m][n] holds D^T: lane row = d (n*16+fq*4+reg), col = bt (m*16+fr)
    const int hb = (tn * 256 + wn * 64) >> 6;
#pragma unroll
    for (int m = 0; m < 8; ++m) {
      const long bt = (long)tm * 256 + wm * 128 + m * 16 + fr;
#pragma unroll
      for (int n = 0; n < 4; ++n) {
        u16x4 o;
#pragma unroll
        for (int r = 0; r < 4; ++r) o[r] = f2bf(acc[m][n][r]);
        *(u16x4*)&C[((long)hb * BT + bt) * 64 + n * 16 + fq * 4] = o;
      }
    }
  } else {
#pragma unroll
    for (int m = 0; m < 8; ++m)
#pragma unroll
      for (int n = 0; n < 4; ++n) {
        const int row0 = tm * 256 + wm * 128 + m * 16 + fq * 4;
        const int col  = tn * 256 + wn * 64 + n * 16 + fr;
#pragma unroll
        for (int r = 0; r < 4; ++r) {
          long idx = (long)(row0 + r) * N + col;
          if constexpr (sizeof(OutT) == 2) C[idx] = f2bf(acc[m][n][r]);
          else                             C[idx] = acc[m][n][r];
        }
      }
  }
}

// ---------------- fused gates GEMM: sigmoid(x @ Wgb[0:32]^T + bias) ----------
__global__ __launch_bounds__(256) void k_gates(const u16* __restrict__ xb,
                                               const u16* __restrict__ wgb,
                                               const float* __restrict__ bg,
                                               const float* __restrict__ bb,
                                               float* __restrict__ alpha,
                                               float* __restrict__ beta) {
  __shared__ __align__(16) u16 As[128 * 64];   // 16KB
  __shared__ __align__(16) u16 Bs[32 * 64];    // 4KB
  const int tid = threadIdx.x, l = tid & 63, w = tid >> 6;
  const int fr = l & 15, fq = l >> 4;
  const int tm = blockIdx.x;
  const long a0 = (long)tm * 128 * 1024;

  f32x4 acc[2][2];
#pragma unroll
  for (int m = 0; m < 2; ++m)
#pragma unroll
    for (int n = 0; n < 2; ++n) acc[m][n] = f32x4{0.f, 0.f, 0.f, 0.f};

  for (int kk = 0; kk < 1024; kk += 64) {
    __syncthreads();
#pragma unroll
    for (int p = 0; p < 4; ++p) {
      const int idx = p * 256 + tid;
      const int row = idx >> 3;
      const int c8 = ((idx & 7) ^ (row & 7)) << 3;
      gload_lds16(&xb[a0 + (long)row * 1024 + kk + c8], &As[p * 2048 + w * 512]);
    }
    {
      const int row = tid >> 3;
      const int c8 = ((tid & 7) ^ (row & 7)) << 3;
      gload_lds16(&wgb[(long)row * 1024 + kk + c8], &Bs[w * 512]);
    }
    asm volatile("s_waitcnt vmcnt(0)" ::: "memory");
    __syncthreads();
#pragma unroll
    for (int ks = 0; ks < 2; ++ks) {
      bf16x8 af[2], bfv[2];
#pragma unroll
      for (int m = 0; m < 2; ++m) {
        const int row = w * 32 + m * 16 + fr;
        af[m] = __builtin_bit_cast(bf16x8, *(const u16x8*)&As[row * 64 + swz(row, ks * 32 + fq * 8)]);
      }
#pragma unroll
      for (int n = 0; n < 2; ++n) {
        const int row = n * 16 + fr;
        bfv[n] = __builtin_bit_cast(bf16x8, *(const u16x8*)&Bs[row * 64 + swz(row, ks * 32 + fq * 8)]);
      }
#pragma unroll
      for (int m = 0; m < 2; ++m)
#pragma unroll
        for (int n = 0; n < 2; ++n)
          acc[m][n] = __builtin_amdgcn_mfma_f32_16x16x32_bf16(af[m], bfv[n], acc[m][n], 0, 0, 0);
    }
  }
  const float bgv = bg[fr], bbv = bb[fr];
#pragma unroll
  for (int m = 0; m < 2; ++m)
#pragma unroll
    for (int r = 0; r < 4; ++r) {
      const long row = (long)tm * 128 + w * 32 + m * 16 + fq * 4 + r;
      alpha[row * 16 + fr] = 1.f / (1.f + __expf(-(acc[m][0][r] + bgv)));
      beta[row * 16 + fr]  = 1.f / (1.f + __expf(-(acc[m][1][r] + bbv)));
    }
}

// ================= chunked WY scan (MFMA block-solve, fused l2norm) =======
// This round: P7 GEMMs use swapped operands (outputs transposed so the reg
// dim runs along contiguous columns) -> u16x4 vector stores in P8.
__global__ __launch_bounds__(256, 3) void k_prep(u16* __restrict__ qkv,
                                                 const float* __restrict__ alpha,
                                                 const float* __restrict__ beta,
                                                 float* __restrict__ A63G,
                                                 u16* __restrict__ oi) {
  __shared__ __align__(16) u16 Ks[64 * 64];
  __shared__ __align__(16) u16 WTs[128 * 64];   // rows 0-63: VbT->WvT; 64-127: KbT->TwT
  __shared__ __align__(16) u16 Lb[64 * 64];     // L (b-scaled), later -L~ in 6 sub-blocks
  __shared__ __align__(16) u16 MqS[64 * 64];
  __shared__ __align__(16) u16 KdT[64 * 64];
  __shared__ __align__(16) u16 Db[4 * 16 * DBS];
  __shared__ float cvec[64], Avec[64], Ainvv[64], bvec[64], nkinv[64], nqinv[64];

  const int unit = blockIdx.x;
  const int pair = unit >> 6, ch = unit & 63;
  const int b = pair >> 4, h = pair & 15;
  const int tid = threadIdx.x, l = tid & 63, w = tid >> 6;
  const int fr = l & 15, fq = l >> 4;
  const long t0 = (long)b * NT + (long)ch * CC;

  // ---- P0: issue global loads into regs; wave0 cumsum ----
  u16x8 kreg[2], vreg[2], qreg[2];
  int srow_[2], sseg_[2];
#pragma unroll
  for (int p = 0; p < 2; ++p) {
    int idx = p * 256 + tid;
    srow_[p] = idx >> 3; sseg_[p] = (idx & 7) * 8;
    qreg[p] = *(const u16x8*)&qkv[qkvT_idx(0, h, t0 + srow_[p], sseg_[p])];
    kreg[p] = *(const u16x8*)&qkv[qkvT_idx(1, h, t0 + srow_[p], sseg_[p])];
    vreg[p] = *(const u16x8*)&qkv[qkvT_idx(2, h, t0 + srow_[p], sseg_[p])];
  }
  const int ar = w * 16 + fr;
  u16x8 qa[2];
#pragma unroll
  for (int kk = 0; kk < 2; ++kk)
    qa[kk] = *(const u16x8*)&qkv[qkvT_idx(0, h, t0 + ar, kk * 32 + fq * 8)];

  if (w == 0) {
    float av = alpha[(t0 + l) * 16 + h];
    float bv = beta[(t0 + l) * 16 + h];
    float cl = __log2f(av);
#pragma unroll
    for (int d = 1; d < 64; d <<= 1) {
      float up = __shfl_up(cl, d);
      if (l >= d) cl += up;
    }
    float A = exp2f(cl);
    cvec[l] = cl; Avec[l] = A; Ainvv[l] = exp2f(-cl); bvec[l] = bv;
    if (l == 63) A63G[unit] = A;
  }
  __syncthreads();

  // ---- P1: stage Ks rows + VbT (b-scaled, transposed); norms via shuffle ----
#pragma unroll
  for (int p = 0; p < 2; ++p) {
    int row = srow_[p], seg = sseg_[p];
    *(u16x8*)&Ks[row * 64 + swz(row, seg)] = kreg[p];
    float kss = 0.f, qss = 0.f;
    const float bs = bvec[row];
#pragma unroll
    for (int e = 0; e < 8; ++e) {
      float kf = bf2f(kreg[p][e]), qf = bf2f(qreg[p][e]);
      kss += kf * kf; qss += qf * qf;
      int c = seg + e;
      WTs[c * 64 + swz(c, row)] = f2bf(bs * bf2f(vreg[p][e]));
    }
    kss += __shfl_xor(kss, 1); kss += __shfl_xor(kss, 2); kss += __shfl_xor(kss, 4);
    qss += __shfl_xor(qss, 1); qss += __shfl_xor(qss, 2); qss += __shfl_xor(qss, 4);
    if ((tid & 7) == 0) { nkinv[row] = kss; nqinv[row] = qss; }
  }
  __syncthreads();

  // ---- P2: inverse norms ----
  if (tid < 64)       nkinv[tid] = rsqrtf(fmaxf(nkinv[tid], 1e-24f));
  else if (tid < 128) nqinv[tid - 64] = rsqrtf(fmaxf(nqinv[tid - 64], 1e-24f));
  __syncthreads();

  // ---- P3: KK^T + QK^T MFMA; build KbT & KdT; L/Mq epilogue ----
  f32x4 akk[4], aqk[4];
#pragma unroll
  for (int n = 0; n < 4; ++n) { akk[n] = f32x4{0, 0, 0, 0}; aqk[n] = f32x4{0, 0, 0, 0}; }
  {
    bf16x8 afK[2], afQ[2];
#pragma unroll
    for (int kk = 0; kk < 2; ++kk) {
      afK[kk] = __builtin_bit_cast(bf16x8, *(const u16x8*)&Ks[ar * 64 + swz(ar, kk * 32 + fq * 8)]);
      afQ[kk] = __builtin_bit_cast(bf16x8, qa[kk]);
    }
#pragma unroll
    for (int n = 0; n < 4; ++n) {
      const int br = n * 16 + fr;
#pragma unroll
      for (int kk = 0; kk < 2; ++kk) {
        bf16x8 bk = __builtin_bit_cast(bf16x8, *(const u16x8*)&Ks[br * 64 + swz(br, kk * 32 + fq * 8)]);
        akk[n] = __builtin_amdgcn_mfma_f32_16x16x32_bf16(afK[kk], bk, akk[n], 0, 0, 0);
        aqk[n] = __builtin_amdgcn_mfma_f32_16x16x32_bf16(afQ[kk], bk, aqk[n], 0, 0, 0);
      }
    }
  }
  {
    const int j = tid & 63, tg4 = tid >> 6;
    const float A63v = Avec[63];
    u16 kb[16], kd[16];
#pragma unroll
    for (int tt = 0; tt < 16; ++tt) {
      int t = tg4 * 16 + tt;
      float kv = bf2f(Ks[t * 64 + swz(t, j)]) * nkinv[t];
      kb[tt] = f2bf(bvec[t] * Avec[t] * kv);
      kd[tt] = f2bf(A63v * Ainvv[t] * kv);
    }
#pragma unroll
    for (int g8 = 0; g8 < 2; ++g8) {
      u16x8 o1, o2;
#pragma unroll
      for (int e = 0; e < 8; ++e) { o1[e] = kb[g8 * 8 + e]; o2[e] = kd[g8 * 8 + e]; }
      int colg = tg4 * 16 + g8 * 8;
      *(u16x8*)&WTs[(64 + j) * 64 + swz(64 + j, colg)] = o1;
      *(u16x8*)&KdT[j * 64 + swz(j, colg)] = o2;
    }
  }
#pragma unroll
  for (int n = 0; n < 4; ++n)
#pragma unroll
    for (int r = 0; r < 4; ++r) {
      const int t = w * 16 + fq * 4 + r;
      const int s = n * 16 + fr;
      const float e = Avec[t] * Ainvv[s];
      Lb[t * 64 + swz(t, s)] = (s < t) ? f2bf(bvec[t] * e * nkinv[t] * nkinv[s] * akk[n][r]) : (u16)0;
      MqS[t * 64 + swz(t, s)] = (s <= t) ? f2bf(e * nqinv[t] * nkinv[s] * aqk[n][r]) : (u16)0;
    }
  __syncthreads();

  // ---- P4: Dinv of the 4 diagonal 16x16 blocks (wave w owns block w) ----
  if (l < 16) {
    const int c = l;
    const int rb = w * 16;
    float x[16];
#pragma unroll
    for (int u = 0; u < 16; ++u) {
      float a2 = (u == c) ? 1.f : 0.f;
#pragma unroll
      for (int s = 0; s < u; ++s)
        a2 -= bf2f(Lb[(rb + u) * 64 + swz(rb + u, rb + s)]) * x[s];
      x[u] = a2;
    }
#pragma unroll
    for (int u = 0; u < 16; ++u)
      Db[w * 16 * DBS + u * DBS + c] = f2bf(x[u]);
  }
  __syncthreads();

  // ---- P5: L~ = Dinv.L (scalar, store NEGATED); R~T = RT.DinvT (MFMA) ----
  float ltil[6];
  {
    const int pbi[6] = {1, 2, 2, 3, 3, 3}, pbj[6] = {0, 0, 1, 0, 1, 2};
    const int tt = tid >> 4, s = tid & 15;
#pragma unroll
    for (int e = 0; e < 6; ++e) {
      int bi = pbi[e], bj = pbj[e];
      float a2 = 0.f;
#pragma unroll
      for (int u = 0; u < 16; ++u)
        a2 += bf2f(Db[bi * 16 * DBS + tt * DBS + u]) *
              bf2f(Lb[(bi * 16 + u) * 64 + swz(bi * 16 + u, bj * 16 + s)]);
      ltil[e] = a2;
    }
  }
  f32x4 rtacc[2][4];
#pragma unroll
  for (int rt2 = 0; rt2 < 2; ++rt2) {
    const int rrow = (w * 2 + rt2) * 16 + fr;
#pragma unroll
    for (int bi = 0; bi < 4; ++bi) {
      bf16x8 a2 = (fq < 2)
        ? __builtin_bit_cast(bf16x8, *(const u16x8*)&WTs[rrow * 64 + swz(rrow, bi * 16 + fq * 8)])
        : zfrag();
      bf16x8 b2 = (fq < 2)
        ? __builtin_bit_cast(bf16x8, *(const u16x8*)&Db[bi * 16 * DBS + fr * DBS + fq * 8])
        : zfrag();
      rtacc[rt2][bi] = __builtin_amdgcn_mfma_f32_16x16x32_bf16(a2, b2, f32x4{0, 0, 0, 0}, 0, 0, 0);
    }
  }
  __syncthreads();   // all L~/R~ reads done before overwrites
  {
    const int pbi[6] = {1, 2, 2, 3, 3, 3}, pbj[6] = {0, 0, 1, 0, 1, 2};
    const int tt = tid >> 4, s = tid & 15;
#pragma unroll
    for (int e = 0; e < 6; ++e)
      Lb[(pbi[e] * 16 + tt) * 64 + swz(pbi[e] * 16 + tt, pbj[e] * 16 + s)] = f2bf(-ltil[e]);
  }
#pragma unroll
  for (int rt2 = 0; rt2 < 2; ++rt2)
#pragma unroll
    for (int bi = 0; bi < 4; ++bi)
#pragma unroll
      for (int r = 0; r < 4; ++r) {
        int rr = (w * 2 + rt2) * 16 + fq * 4 + r;
        WTs[rr * 64 + swz(rr, bi * 16 + fr)] = f2bf(rtacc[rt2][bi][r]);
      }
  __syncthreads();

  // ---- P6: 3-step MFMA substitution (row-tiles wave-exclusive, no barriers) ----
#pragma unroll
  for (int rt2 = 0; rt2 < 2; ++rt2) {
    const int rrow = (w * 2 + rt2) * 16 + fr;
    const int wr0 = (w * 2 + rt2) * 16 + fq * 4;
#pragma unroll
    for (int i = 1; i < 4; ++i) {
      f32x4 a2;
#pragma unroll
      for (int r = 0; r < 4; ++r)
        a2[r] = bf2f(WTs[(wr0 + r) * 64 + swz(wr0 + r, i * 16 + fr)]);
      {
        bf16x8 af = __builtin_bit_cast(bf16x8, *(const u16x8*)&WTs[rrow * 64 + swz(rrow, fq * 8)]);
        bf16x8 bf_;
        if (i == 1) bf_ = (fq < 2)
          ? __builtin_bit_cast(bf16x8, *(const u16x8*)&Lb[(16 + fr) * 64 + swz(16 + fr, fq * 8)])
          : zfrag();
        else bf_ = __builtin_bit_cast(bf16x8, *(const u16x8*)&Lb[(i * 16 + fr) * 64 + swz(i * 16 + fr, fq * 8)]);
        a2 = __builtin_amdgcn_mfma_f32_16x16x32_bf16(af, bf_, a2, 0, 0, 0);
      }
      if (i == 3) {
        bf16x8 af = __builtin_bit_cast(bf16x8, *(const u16x8*)&WTs[rrow * 64 + swz(rrow, 32 + fq * 8)]);
        bf16x8 bf_ = (fq < 2)
          ? __builtin_bit_cast(bf16x8, *(const u16x8*)&Lb[(48 + fr) * 64 + swz(48 + fr, 32 + fq * 8)])
          : zfrag();
        a2 = __builtin_amdgcn_mfma_f32_16x16x32_bf16(af, bf_, a2, 0, 0, 0);
      }
#pragma unroll
      for (int r = 0; r < 4; ++r)
        WTs[(wr0 + r) * 64 + swz(wr0 + r, i * 16 + fr)] = f2bf(a2[r]);
    }
  }
  __syncthreads();

  // ---- P7: final 4 GEMMs, SWAPPED operands (outputs transposed) ----
  // Lane holds: row(w*16+fr fixed), cols n*16+fq*4+reg consecutive.
  const int prow = w * 16 + fr;
  u16x4 qpre4[4];
#pragma unroll
  for (int n = 0; n < 4; ++n)
    qpre4[n] = *(const u16x4*)&qkv[qkvT_idx(0, h, t0 + prow, n * 16 + fq * 4)];

  f32x4 aG[4], aU[4], aQe[4], aOi[4];
#pragma unroll
  for (int n = 0; n < 4; ++n) {
    aG[n] = f32x4{0, 0, 0, 0}; aU[n] = f32x4{0, 0, 0, 0};
    aQe[n] = f32x4{0, 0, 0, 0}; aOi[n] = f32x4{0, 0, 0, 0};
  }
  {
    bf16x8 aKd[2], aWv[2], aMq[2];   // B-operands: rows ar
#pragma unroll
    for (int kk = 0; kk < 2; ++kk) {
      aKd[kk] = __builtin_bit_cast(bf16x8, *(const u16x8*)&KdT[ar * 64 + swz(ar, kk * 32 + fq * 8)]);
      aWv[kk] = __builtin_bit_cast(bf16x8, *(const u16x8*)&WTs[ar * 64 + swz(ar, kk * 32 + fq * 8)]);
      aMq[kk] = __builtin_bit_cast(bf16x8, *(const u16x8*)&MqS[ar * 64 + swz(ar, kk * 32 + fq * 8)]);
    }
#pragma unroll
    for (int n = 0; n < 4; ++n) {
      const int br = n * 16 + fr;
#pragma unroll
      for (int kk = 0; kk < 2; ++kk) {
        bf16x8 bTw = __builtin_bit_cast(bf16x8, *(const u16x8*)&WTs[(64 + br) * 64 + swz(64 + br, kk * 32 + fq * 8)]);
        bf16x8 bKd = __builtin_bit_cast(bf16x8, *(const u16x8*)&KdT[br * 64 + swz(br, kk * 32 + fq * 8)]);
        bf16x8 bWv = __builtin_bit_cast(bf16x8, *(const u16x8*)&WTs[br * 64 + swz(br, kk * 32 + fq * 8)]);
        // D[xrow][yrow]: xrow = n*16+fq*4+reg (cols of output), yrow = prow
        aG[n]  = __builtin_amdgcn_mfma_f32_16x16x32_bf16(bTw, aKd[kk], aG[n], 0, 0, 0);  // (Kd^T Tw)[j][j']
        aU[n]  = __builtin_amdgcn_mfma_f32_16x16x32_bf16(bKd, aWv[kk], aU[n], 0, 0, 0);  // U[d][j]
        aQe[n] = __builtin_amdgcn_mfma_f32_16x16x32_bf16(bTw, aMq[kk], aQe[n], 0, 0, 0); // (MqTw)[t][j']
        aOi[n] = __builtin_amdgcn_mfma_f32_16x16x32_bf16(bWv, aMq[kk], aOi[n], 0, 0, 0); // Oi[t][d]
      }
    }
  }
  // ---- P8: u16x4 vector stores (row = prow, 4 consecutive swizzled cols) ----
  asm volatile("s_waitcnt vmcnt(0)" ::: "memory");   // qpre4 data arrived before overwrite
  __builtin_amdgcn_sched_barrier(0);
  const float aqs = Avec[prow] * nqinv[prow];
#pragma unroll
  for (int n = 0; n < 4; ++n) {
    u16x4 vq, vg, vu, vo;
#pragma unroll
    for (int r = 0; r < 4; ++r) {
      vq[r] = f2bf(aqs * bf2f(qpre4[n][r]) - aQe[n][r]);
      vg[r] = f2bf(-aG[n][r]);
      vu[r] = f2bf(aU[n][r]);
      vo[r] = f2bf(aOi[n][r]);
    }
    const int scol = swz(prow, n * 16 + fq * 4);
    *(u16x4*)&qkv[qkvT_idx(0, h, t0 + prow, scol)] = vq;
    *(u16x4*)&qkv[qkvT_idx(1, h, t0 + prow, scol)] = vg;
    *(u16x4*)&qkv[qkvT_idx(2, h, t0 + prow, scol)] = vu;
    *(u16x4*)&Ks[prow * 64 + scol] = vo;   // Ks dead since P3; swizzled (bank spread)
  }
  __syncthreads();
#pragma unroll
  for (int p = 0; p < 2; ++p) {
    const int idx = p * 256 + tid;
    const int row = idx >> 3, seg = (idx & 7) * 8;
    *(u16x8*)&oi[(long)unit * 4096 + row * 64 + seg] = *(const u16x8*)&Ks[row * 64 + swz(row, seg)];
  }
}

// ---------------- sequential chunk recurrence (16 waves, 1 barrier/chunk) -----
__global__ __launch_bounds__(1024) void k_seq(const u16* __restrict__ qkv,
                                              const u16* __restrict__ oi,
                                              const float* __restrict__ A63G,
                                              u16* __restrict__ ob) {
  __shared__ __align__(16) u16 Sb[2][64 * 64];
  __shared__ __align__(16) u16 Obs[2][64 * 64];
  __shared__ __align__(16) u16 stg[3][4][64 * 64];   // 96KB
  __shared__ float a63s[64];
  const int pair = blockIdx.x;
  const int b = pair >> 4, h = pair & 15;
  const int tid = threadIdx.x, l = tid & 63, w = tid >> 6;   // w 0..15
  const int fr = l & 15, fq = l >> 4;
  const int tw = w >> 2, td = w & 3;

  auto stage = [&](int c) {
    const int s = c % 3;
    const long tg = (long)b * NT + (long)c * CC;
    if (tid < 512) {
      const int row = tid >> 3, seg = (tid & 7) * 8;
#pragma unroll
      for (int m = 0; m < 4; ++m) {
        const u16* src = (m < 3)
          ? &qkv[qkvT_idx(m, h, tg + row, seg)]
          : &oi[(long)(pair * 64 + c) * 4096 + row * 64 + seg];
        gload_lds16(src, &stg[s][m][row * 64 + seg]);
      }
    }
  };

  if (tid < 64) a63s[tid] = A63G[pair * 64 + tid];
  for (int i = tid; i < 4096; i += 1024) Sb[0][i] = 0;
  stage(0); stage(1);
  f32x4 sacc = f32x4{0, 0, 0, 0};
  asm volatile("s_waitcnt lgkmcnt(0)" ::: "memory");
  __builtin_amdgcn_sched_barrier(0);

  for (int c = 0; c < NCH; ++c) {
    const int sb = c & 1, st = c % 3;
    const long tg = (long)b * NT + (long)c * CC;
    if (c <= 1)             { asm volatile("s_waitcnt vmcnt(4)" ::: "memory"); }
    else if (c < NCH - 1)   { asm volatile("s_waitcnt vmcnt(5)" ::: "memory"); }
    else                    { asm volatile("s_waitcnt vmcnt(1)" ::: "memory"); }
    __builtin_amdgcn_sched_barrier(0);
    __builtin_amdgcn_s_barrier();
    __builtin_amdgcn_sched_barrier(0);

    if (c > 0 && tid < 512) {
      const int row = tid >> 3, seg = (tid & 7) * 8;
      *(u16x8*)&ob[(tg - CC + row) * 1024 + h * 64 + seg] = *(const u16x8*)&Obs[sb ^ 1][row * 64 + seg];
    }
    if (c + 2 < NCH) stage(c + 2);

    const u16* Qe = stg[st][0];
    const u16* Gm = stg[st][1];
    const u16* Um = stg[st][2];
    const u16* Obl = stg[st][3];

    const int at = tw * 16 + fr;
    const int bd = td * 16 + fr;
    f32x4 ao = f32x4{0, 0, 0, 0};
    const float A63 = a63s[c];
#pragma unroll
    for (int r = 0; r < 4; ++r) sacc[r] *= A63;
#pragma unroll
    for (int kk = 0; kk < 2; ++kk) {
      bf16x8 aq = __builtin_bit_cast(bf16x8, *(const u16x8*)&Qe[at * 64 + swz(at, kk * 32 + fq * 8)]);
      bf16x8 sbf = __builtin_bit_cast(bf16x8, *(const u16x8*)&Sb[sb][bd * 64 + swz(bd, kk * 32 + fq * 8)]);
      ao = __builtin_amdgcn_mfma_f32_16x16x32_bf16(aq, sbf, ao, 0, 0, 0);
      bf16x8 as_ = __builtin_bit_cast(bf16x8, *(const u16x8*)&Sb[sb][at * 64 + swz(at, kk * 32 + fq * 8)]);
      bf16x8 g  = __builtin_bit_cast(bf16x8, *(const u16x8*)&Gm[bd * 64 + swz(bd, kk * 32 + fq * 8)]);
      sacc = __builtin_amdgcn_mfma_f32_16x16x32_bf16(as_, g, sacc, 0, 0, 0);
    }
#pragma unroll
    for (int r = 0; r < 4; ++r) {
      const int ri = tw * 16 + fq * 4 + r;
      const int cj = td * 16 + fr;
      sacc[r] += bf2f(Um[ri * 64 + swz(ri, cj)]);
      Obs[sb][ri * 64 + cj] = f2bf(bf2f(Obl[ri * 64 + cj]) + ao[r]);
      Sb[sb ^ 1][ri * 64 + swz(ri, cj)] = f2bf(sacc[r]);
    }
    asm volatile("s_waitcnt lgkmcnt(0)" ::: "memory");
    __builtin_amdgcn_sched_barrier(0);
  }
  __builtin_amdgcn_s_barrier();
  if (tid < 512) {
    const int row = tid >> 3, seg = (tid & 7) * 8;
    const long tg = (long)b * NT + (long)(NCH - 1) * CC;
    *(u16x8*)&ob[(tg + row) * 1024 + h * 64 + seg] = *(const u16x8*)&Obs[(NCH - 1) & 1][row * 64 + seg];
  }
}

extern "C" void kernel_launch(void* const* d_in, const int* in_sizes, int n_in,
                              void* d_out, int out_size, void* d_ws, size_t ws_size,
                              hipStream_t stream) {
  const float* x    = (const float*)d_in[0];
  const float* Wqkv = (const float*)d_in[1];
  const float* Wg   = (const float*)d_in[2];
  const float* bg   = (const float*)d_in[3];
  const float* Wb   = (const float*)d_in[4];
  const float* bb   = (const float*)d_in[5];
  const float* Wout = (const float*)d_in[6];
  float* out = (float*)d_out;

  char* ws = (char*)d_ws;
  u16* xb    = (u16*)ws;                               // 16384*1024   (32MB)
  u16* wqkvb = xb    + (long)BT * NDIM;                // 3072*1024    (6MB)
  u16* woutb = wqkvb + (long)3072 * 1024;              // 1024*1024    (2MB)
  u16* wgbb  = woutb + (long)1024 * 1024;              // 128*1024
  u16* qkvb  = wgbb  + (long)128 * 1024;               // [48][BT][64] (96MB)
  u16* ob    = qkvb  + (long)BT * 3072;                // 16384*1024   (32MB)
  float* graw  = (float*)(ob + (long)BT * NDIM);       // 16384*128    (8MB, A63G home)
  float* alpha = graw + (long)BT * 128;                // 16384*16     (1MB)
  float* beta  = alpha + (long)BT * NH;                // 16384*16     (1MB)
  float* A63G  = graw;
  u16*   oi    = xb;     // reuse: xb dead after k_gates; NU*4096 u16 = 32MB exact

  // 1. converts
  k_f32_to_bf16<<<(BT * (long)NDIM / 4 + 255) / 256, 256, 0, stream>>>(x, xb, BT * (long)NDIM / 4);
  k_f32_to_bf16<<<(3072L * 1024 / 4 + 255) / 256, 256, 0, stream>>>(Wqkv, wqkvb, 3072L * 1024 / 4);
  k_f32_to_bf16<<<(1024L * 1024 / 4 + 255) / 256, 256, 0, stream>>>(Wout, woutb, 1024L * 1024 / 4);
  k_build_wgb<<<(128 * 1024) / 256, 256, 0, stream>>>(Wg, Wb, wgbb);

  // 2. qkv GEMM (256^2 8-phase, head-major vector-store output)
  k_gemm256<u16, true><<<64 * 12, 512, 0, stream>>>(xb, wqkvb, qkvb, BT, 3072, NDIM);

  // 3. fused gates GEMM + sigmoid
  k_gates<<<BT / 128, 256, 0, stream>>>(xb, wgbb, bg, bb, alpha, beta);

  // 4. chunked WY: parallel precompute + sequential chunk GEMMs (16-wave)
  k_prep<<<NU, 256, 0, stream>>>(qkvb, alpha, beta, A63G, oi);
  k_seq<<<NPAIR, 1024, 0, stream>>>(qkvb, oi, A63G, ob);

  // 5. out GEMM (256^2 8-phase): 16384x1024 = ob @ woutb^T (fp32 out)
  k_gemm256<float, false><<<64 * 4, 512, 0, stream>>>(ob, woutb, out, BT, NDIM, NDIM);
}

// Round 14
// 358.722 us; speedup vs baseline: 1.3554x; 1.0092x over previous
//
#include <hip/hip_runtime.h>
#include <hip/hip_bf16.h>

// Problem constants
#define NB   4
#define NT   4096
#define BT   16384   // NB*NT
#define NDIM 1024
#define NH   16
#define NDH  64
#define CC   64              // chunk size (time steps)
#define NCH  (NT / CC)       // 64 chunks per pair
#define NPAIR 64             // B*H
#define NU   (NPAIR * NCH)   // 4096 units
#define DBS  24              // Db row stride (u16 elems), padded for banks

using u16 = unsigned short;
typedef __bf16 bf16x8 __attribute__((ext_vector_type(8)));
typedef float f32x4 __attribute__((ext_vector_type(4)));
typedef unsigned short u16x8 __attribute__((ext_vector_type(8)));
typedef unsigned short u16x4 __attribute__((ext_vector_type(4)));

__device__ __forceinline__ float bf2f(u16 b) { return __uint_as_float(((unsigned)b) << 16); }
__device__ __forceinline__ u16 f2bf(float f) {
  return __builtin_bit_cast(u16, __float2bfloat16(f));
}
// LDS row swizzle (u16-element index, 8-elem granular): breaks stride-128B bank conflicts
__device__ __forceinline__ int swz(int row, int e) { return e ^ ((row & 7) << 3); }
__device__ __forceinline__ bf16x8 zfrag() {
  u16x8 z = {0, 0, 0, 0, 0, 0, 0, 0};
  return __builtin_bit_cast(bf16x8, z);
}
// head-major qkv layout: [slot(3)][head(16)][bt(BT)][d(64)] — per-(h,chunk) tile contiguous
__device__ __forceinline__ long qkvT_idx(int s, int h, long bt, int d) {
  return ((long)(s * 16 + h) * BT + bt) * 64 + d;
}

// ---------------- convert fp32 -> bf16 (vectorized) ----------------
__global__ __launch_bounds__(256) void k_f32_to_bf16(const float* __restrict__ in,
                                                     u16* __restrict__ out, long n4) {
  long i = (long)blockIdx.x * blockDim.x + threadIdx.x;
  if (i >= n4) return;
  float4 f = reinterpret_cast<const float4*>(in)[i];
  u16x4 o;
  o.x = f2bf(f.x); o.y = f2bf(f.y); o.z = f2bf(f.z); o.w = f2bf(f.w);
  reinterpret_cast<u16x4*>(out)[i] = o;
}

// ---------------- build padded gate weight matrix (128 x 1024 bf16) ----------------
__global__ __launch_bounds__(256) void k_build_wgb(const float* __restrict__ Wg,
                                                   const float* __restrict__ Wb,
                                                   u16* __restrict__ out) {
  int i = blockIdx.x * 256 + threadIdx.x;
  int row = i >> 10, col = i & 1023;
  float f = 0.f;
  if (row < 16)       f = Wg[row * 1024 + col];
  else if (row < 32)  f = Wb[(row - 16) * 1024 + col];
  out[i] = f2bf(f);
}

// ---------------- global_load_lds helper ----------------
typedef unsigned int u32_as1 __attribute__((address_space(1)));
typedef unsigned int u32_as3 __attribute__((address_space(3)));
__device__ __forceinline__ void gload_lds16(const void* g, void* l) {
  __builtin_amdgcn_global_load_lds((const u32_as1*)g, (u32_as3*)l, 16, 0, 0);
}

// ============ 256x256-tile bf16 GEMM, ring-4 half-tile pipeline ==============
// 32 half-sections (kt,ks); one barrier per section; counted vmcnt(8) keeps
// 2 half-tiles (8 loads) in flight. QKVT=true: swapped-operand MFMA (acc=D^T)
// + head-major [48][BT][64] u16x4-vector epilogue.
template <typename OutT, bool QKVT>
__global__ __launch_bounds__(512, 2) void k_gemm256(const u16* __restrict__ A,
                                                    const u16* __restrict__ B,
                                                    OutT* __restrict__ C,
                                                    int M, int N, int K) {
  __shared__ __align__(16) u16 As[4][256 * 32];   // ring of A half-tiles (64KB)
  __shared__ __align__(16) u16 Bs[4][256 * 32];   // ring of B half-tiles (64KB)
  const int tid = threadIdx.x;
  const int l = tid & 63, w = tid >> 6;
  const int wm = w >> 2, wn = w & 3;          // 2 x 4 wave grid
  const int fr = l & 15, fq = l >> 4;
  const int nwg = gridDim.x;
  const int cpx = nwg >> 3;
  const int bid = blockIdx.x;
  const int sbid = (bid & 7) * cpx + (bid >> 3);
  const int ntn = N >> 8;
  const int tm = sbid / ntn, tn = sbid - tm * ntn;
  const long a0 = (long)tm * 256 * K;
  const long b0 = (long)tn * 256 * K;
  const int srow0 = tid >> 2;
  const int scol8 = (((tid & 3) ^ ((tid >> 4) & 3)) << 3);
  const int cswz = ((fq ^ ((fr >> 2) & 3)) << 3);
  const int NKT = K >> 6;
  const int NHALF = NKT * 2;

  // stage one operand (part 0=A, 1=B) of half-tile j into ring slot j&3
  auto stage_part = [&](int j, int part) {
    const int slot = j & 3;
    const int kt = j >> 1, ks = j & 1;
    const u16* Gp = part ? B : A;
    const long g0 = (part ? b0 : a0) + (long)kt * 64 + ks * 32 + scol8;
    u16* lb = part ? &Bs[slot][w * 512] : &As[slot][w * 512];
#pragma unroll
    for (int r = 0; r < 2; ++r)
      gload_lds16(Gp + g0 + (long)(r * 128 + srow0) * K, lb + r * 4096);
  };

  f32x4 acc[8][4];
#pragma unroll
  for (int m = 0; m < 8; ++m)
#pragma unroll
    for (int n = 0; n < 4; ++n) acc[m][n] = f32x4{0.f, 0.f, 0.f, 0.f};

  auto domfma = [&](f32x4& a, const bf16x8& af, const bf16x8& bf_) {
    if constexpr (QKVT) a = __builtin_amdgcn_mfma_f32_16x16x32_bf16(bf_, af, a, 0, 0, 0);
    else                a = __builtin_amdgcn_mfma_f32_16x16x32_bf16(af, bf_, a, 0, 0, 0);
  };

  // prologue: 3 half-tiles in flight
  stage_part(0, 0); stage_part(0, 1);
  stage_part(1, 0); stage_part(1, 1);
  stage_part(2, 0); stage_part(2, 1);

  for (int j = 0; j < NHALF; ++j) {
    const int slot = j & 3;
    if (j + 2 < NHALF)      { asm volatile("s_waitcnt vmcnt(8)" ::: "memory"); }
    else if (j + 1 < NHALF) { asm volatile("s_waitcnt vmcnt(4)" ::: "memory"); }
    else                    { asm volatile("s_waitcnt vmcnt(0)" ::: "memory"); }
    __builtin_amdgcn_sched_barrier(0);
    __builtin_amdgcn_s_barrier();
    __builtin_amdgcn_sched_barrier(0);

    const u16* ap = &As[slot][(wm * 128 + fr) * 32 + cswz];
    const u16* bp = &Bs[slot][(wn * 64 + fr) * 32 + cswz];
    bf16x8 bfr[4], afr[4];
#pragma unroll
    for (int n = 0; n < 4; ++n) bfr[n] = *(const bf16x8*)(bp + n * 512);
#pragma unroll
    for (int m = 0; m < 4; ++m) afr[m] = *(const bf16x8*)(ap + m * 512);
    if (j + 3 < NHALF) stage_part(j + 3, 0);
    __builtin_amdgcn_s_setprio(1);
#pragma unroll
    for (int m = 0; m < 4; ++m)
#pragma unroll
      for (int n = 0; n < 4; ++n) domfma(acc[m][n], afr[m], bfr[n]);
    __builtin_amdgcn_s_setprio(0);
#pragma unroll
    for (int m = 0; m < 4; ++m) afr[m] = *(const bf16x8*)(ap + (4 + m) * 512);
    if (j + 3 < NHALF) stage_part(j + 3, 1);
    __builtin_amdgcn_s_setprio(1);
#pragma unroll
    for (int m = 0; m < 4; ++m)
#pragma unroll
      for (int n = 0; n < 4; ++n) domfma(acc[4 + m][n], afr[m], bfr[n]);
    __builtin_amdgcn_s_setprio(0);
  }

  if constexpr (QKVT) {
    // acc[m][n] holds D^T: lane row = d (n*16+fq*4+reg), col = bt (m*16+fr)
    const int hb = (tn * 256 + wn * 64) >> 6;
#pragma unroll
    for (int m = 0; m < 8; ++m) {
      const long bt = (long)tm * 256 + wm * 128 + m * 16 + fr;
#pragma unroll
      for (int n = 0; n < 4; ++n) {
        u16x4 o;
#pragma unroll
        for (int r = 0; r < 4; ++r) o[r] = f2bf(acc[m][n][r]);
        *(u16x4*)&C[((long)hb * BT + bt) * 64 + n * 16 + fq * 4] = o;
      }
    }
  } else {
#pragma unroll
    for (int m = 0; m < 8; ++m)
#pragma unroll
      for (int n = 0; n < 4; ++n) {
        const int row0 = tm * 256 + wm * 128 + m * 16 + fq * 4;
        const int col  = tn * 256 + wn * 64 + n * 16 + fr;
#pragma unroll
        for (int r = 0; r < 4; ++r) {
          long idx = (long)(row0 + r) * N + col;
          if constexpr (sizeof(OutT) == 2) C[idx] = f2bf(acc[m][n][r]);
          else                             C[idx] = acc[m][n][r];
        }
      }
  }
}

// ---------------- fused gates GEMM: sigmoid(x @ Wgb[0:32]^T + bias) ----------
__global__ __launch_bounds__(256) void k_gates(const u16* __restrict__ xb,
                                               const u16* __restrict__ wgb,
                                               const float* __restrict__ bg,
                                               const float* __restrict__ bb,
                                               float* __restrict__ alpha,
                                               float* __restrict__ beta) {
  __shared__ __align__(16) u16 As[128 * 64];   // 16KB
  __shared__ __align__(16) u16 Bs[32 * 64];    // 4KB
  const int tid = threadIdx.x, l = tid & 63, w = tid >> 6;
  const int fr = l & 15, fq = l >> 4;
  const int tm = blockIdx.x;
  const long a0 = (long)tm * 128 * 1024;

  f32x4 acc[2][2];
#pragma unroll
  for (int m = 0; m < 2; ++m)
#pragma unroll
    for (int n = 0; n < 2; ++n) acc[m][n] = f32x4{0.f, 0.f, 0.f, 0.f};

  for (int kk = 0; kk < 1024; kk += 64) {
    __syncthreads();
#pragma unroll
    for (int p = 0; p < 4; ++p) {
      const int idx = p * 256 + tid;
      const int row = idx >> 3;
      const int c8 = ((idx & 7) ^ (row & 7)) << 3;
      gload_lds16(&xb[a0 + (long)row * 1024 + kk + c8], &As[p * 2048 + w * 512]);
    }
    {
      const int row = tid >> 3;
      const int c8 = ((tid & 7) ^ (row & 7)) << 3;
      gload_lds16(&wgb[(long)row * 1024 + kk + c8], &Bs[w * 512]);
    }
    asm volatile("s_waitcnt vmcnt(0)" ::: "memory");
    __syncthreads();
#pragma unroll
    for (int ks = 0; ks < 2; ++ks) {
      bf16x8 af[2], bfv[2];
#pragma unroll
      for (int m = 0; m < 2; ++m) {
        const int row = w * 32 + m * 16 + fr;
        af[m] = __builtin_bit_cast(bf16x8, *(const u16x8*)&As[row * 64 + swz(row, ks * 32 + fq * 8)]);
      }
#pragma unroll
      for (int n = 0; n < 2; ++n) {
        const int row = n * 16 + fr;
        bfv[n] = __builtin_bit_cast(bf16x8, *(const u16x8*)&Bs[row * 64 + swz(row, ks * 32 + fq * 8)]);
      }
#pragma unroll
      for (int m = 0; m < 2; ++m)
#pragma unroll
        for (int n = 0; n < 2; ++n)
          acc[m][n] = __builtin_amdgcn_mfma_f32_16x16x32_bf16(af[m], bfv[n], acc[m][n], 0, 0, 0);
    }
  }
  const float bgv = bg[fr], bbv = bb[fr];
#pragma unroll
  for (int m = 0; m < 2; ++m)
#pragma unroll
    for (int r = 0; r < 4; ++r) {
      const long row = (long)tm * 128 + w * 32 + m * 16 + fq * 4 + r;
      alpha[row * 16 + fr] = 1.f / (1.f + __expf(-(acc[m][0][r] + bgv)));
      beta[row * 16 + fr]  = 1.f / (1.f + __expf(-(acc[m][1][r] + bbv)));
    }
}

// ================= chunked WY scan (MFMA block-solve, fused l2norm) =======
// P7 GEMMs use swapped operands (outputs transposed) -> u16x4 vector stores.
__global__ __launch_bounds__(256, 3) void k_prep(u16* __restrict__ qkv,
                                                 const float* __restrict__ alpha,
                                                 const float* __restrict__ beta,
                                                 float* __restrict__ A63G,
                                                 u16* __restrict__ oi) {
  __shared__ __align__(16) u16 Ks[64 * 64];
  __shared__ __align__(16) u16 WTs[128 * 64];   // rows 0-63: VbT->WvT; 64-127: KbT->TwT
  __shared__ __align__(16) u16 Lb[64 * 64];     // L (b-scaled), later -L~ in 6 sub-blocks
  __shared__ __align__(16) u16 MqS[64 * 64];
  __shared__ __align__(16) u16 KdT[64 * 64];
  __shared__ __align__(16) u16 Db[4 * 16 * DBS];
  __shared__ float cvec[64], Avec[64], Ainvv[64], bvec[64], nkinv[64], nqinv[64];

  const int unit = blockIdx.x;
  const int pair = unit >> 6, ch = unit & 63;
  const int b = pair >> 4, h = pair & 15;
  const int tid = threadIdx.x, l = tid & 63, w = tid >> 6;
  const int fr = l & 15, fq = l >> 4;
  const long t0 = (long)b * NT + (long)ch * CC;

  // ---- P0: issue global loads into regs; wave0 cumsum ----
  u16x8 kreg[2], vreg[2], qreg[2];
  int srow_[2], sseg_[2];
#pragma unroll
  for (int p = 0; p < 2; ++p) {
    int idx = p * 256 + tid;
    srow_[p] = idx >> 3; sseg_[p] = (idx & 7) * 8;
    qreg[p] = *(const u16x8*)&qkv[qkvT_idx(0, h, t0 + srow_[p], sseg_[p])];
    kreg[p] = *(const u16x8*)&qkv[qkvT_idx(1, h, t0 + srow_[p], sseg_[p])];
    vreg[p] = *(const u16x8*)&qkv[qkvT_idx(2, h, t0 + srow_[p], sseg_[p])];
  }
  const int ar = w * 16 + fr;
  u16x8 qa[2];
#pragma unroll
  for (int kk = 0; kk < 2; ++kk)
    qa[kk] = *(const u16x8*)&qkv[qkvT_idx(0, h, t0 + ar, kk * 32 + fq * 8)];

  if (w == 0) {
    float av = alpha[(t0 + l) * 16 + h];
    float bv = beta[(t0 + l) * 16 + h];
    float cl = __log2f(av);
#pragma unroll
    for (int d = 1; d < 64; d <<= 1) {
      float up = __shfl_up(cl, d);
      if (l >= d) cl += up;
    }
    float A = exp2f(cl);
    cvec[l] = cl; Avec[l] = A; Ainvv[l] = exp2f(-cl); bvec[l] = bv;
    if (l == 63) A63G[unit] = A;
  }
  __syncthreads();

  // ---- P1: stage Ks rows + VbT (b-scaled, transposed); norms via shuffle ----
#pragma unroll
  for (int p = 0; p < 2; ++p) {
    int row = srow_[p], seg = sseg_[p];
    *(u16x8*)&Ks[row * 64 + swz(row, seg)] = kreg[p];
    float kss = 0.f, qss = 0.f;
    const float bs = bvec[row];
#pragma unroll
    for (int e = 0; e < 8; ++e) {
      float kf = bf2f(kreg[p][e]), qf = bf2f(qreg[p][e]);
      kss += kf * kf; qss += qf * qf;
      int c = seg + e;
      WTs[c * 64 + swz(c, row)] = f2bf(bs * bf2f(vreg[p][e]));
    }
    kss += __shfl_xor(kss, 1); kss += __shfl_xor(kss, 2); kss += __shfl_xor(kss, 4);
    qss += __shfl_xor(qss, 1); qss += __shfl_xor(qss, 2); qss += __shfl_xor(qss, 4);
    if ((tid & 7) == 0) { nkinv[row] = kss; nqinv[row] = qss; }
  }
  __syncthreads();

  // ---- P2: inverse norms ----
  if (tid < 64)       nkinv[tid] = rsqrtf(fmaxf(nkinv[tid], 1e-24f));
  else if (tid < 128) nqinv[tid - 64] = rsqrtf(fmaxf(nqinv[tid - 64], 1e-24f));
  __syncthreads();

  // ---- P3: KK^T + QK^T MFMA; build KbT & KdT; L/Mq epilogue ----
  f32x4 akk[4], aqk[4];
#pragma unroll
  for (int n = 0; n < 4; ++n) { akk[n] = f32x4{0, 0, 0, 0}; aqk[n] = f32x4{0, 0, 0, 0}; }
  {
    bf16x8 afK[2], afQ[2];
#pragma unroll
    for (int kk = 0; kk < 2; ++kk) {
      afK[kk] = __builtin_bit_cast(bf16x8, *(const u16x8*)&Ks[ar * 64 + swz(ar, kk * 32 + fq * 8)]);
      afQ[kk] = __builtin_bit_cast(bf16x8, qa[kk]);
    }
#pragma unroll
    for (int n = 0; n < 4; ++n) {
      const int br = n * 16 + fr;
#pragma unroll
      for (int kk = 0; kk < 2; ++kk) {
        bf16x8 bk = __builtin_bit_cast(bf16x8, *(const u16x8*)&Ks[br * 64 + swz(br, kk * 32 + fq * 8)]);
        akk[n] = __builtin_amdgcn_mfma_f32_16x16x32_bf16(afK[kk], bk, akk[n], 0, 0, 0);
        aqk[n] = __builtin_amdgcn_mfma_f32_16x16x32_bf16(afQ[kk], bk, aqk[n], 0, 0, 0);
      }
    }
  }
  {
    const int j = tid & 63, tg4 = tid >> 6;
    const float A63v = Avec[63];
    u16 kb[16], kd[16];
#pragma unroll
    for (int tt = 0; tt < 16; ++tt) {
      int t = tg4 * 16 + tt;
      float kv = bf2f(Ks[t * 64 + swz(t, j)]) * nkinv[t];
      kb[tt] = f2bf(bvec[t] * Avec[t] * kv);
      kd[tt] = f2bf(A63v * Ainvv[t] * kv);
    }
#pragma unroll
    for (int g8 = 0; g8 < 2; ++g8) {
      u16x8 o1, o2;
#pragma unroll
      for (int e = 0; e < 8; ++e) { o1[e] = kb[g8 * 8 + e]; o2[e] = kd[g8 * 8 + e]; }
      int colg = tg4 * 16 + g8 * 8;
      *(u16x8*)&WTs[(64 + j) * 64 + swz(64 + j, colg)] = o1;
      *(u16x8*)&KdT[j * 64 + swz(j, colg)] = o2;
    }
  }
#pragma unroll
  for (int n = 0; n < 4; ++n)
#pragma unroll
    for (int r = 0; r < 4; ++r) {
      const int t = w * 16 + fq * 4 + r;
      const int s = n * 16 + fr;
      const float e = Avec[t] * Ainvv[s];
      Lb[t * 64 + swz(t, s)] = (s < t) ? f2bf(bvec[t] * e * nkinv[t] * nkinv[s] * akk[n][r]) : (u16)0;
      MqS[t * 64 + swz(t, s)] = (s <= t) ? f2bf(e * nqinv[t] * nkinv[s] * aqk[n][r]) : (u16)0;
    }
  __syncthreads();

  // ---- P4: Dinv of the 4 diagonal 16x16 blocks (wave w owns block w) ----
  if (l < 16) {
    const int c = l;
    const int rb = w * 16;
    float x[16];
#pragma unroll
    for (int u = 0; u < 16; ++u) {
      float a2 = (u == c) ? 1.f : 0.f;
#pragma unroll
      for (int s = 0; s < u; ++s)
        a2 -= bf2f(Lb[(rb + u) * 64 + swz(rb + u, rb + s)]) * x[s];
      x[u] = a2;
    }
#pragma unroll
    for (int u = 0; u < 16; ++u)
      Db[w * 16 * DBS + u * DBS + c] = f2bf(x[u]);
  }
  __syncthreads();

  // ---- P5: L~ = Dinv.L (scalar, store NEGATED); R~T = RT.DinvT (MFMA) ----
  float ltil[6];
  {
    const int pbi[6] = {1, 2, 2, 3, 3, 3}, pbj[6] = {0, 0, 1, 0, 1, 2};
    const int tt = tid >> 4, s = tid & 15;
#pragma unroll
    for (int e = 0; e < 6; ++e) {
      int bi = pbi[e], bj = pbj[e];
      float a2 = 0.f;
#pragma unroll
      for (int u = 0; u < 16; ++u)
        a2 += bf2f(Db[bi * 16 * DBS + tt * DBS + u]) *
              bf2f(Lb[(bi * 16 + u) * 64 + swz(bi * 16 + u, bj * 16 + s)]);
      ltil[e] = a2;
    }
  }
  f32x4 rtacc[2][4];
#pragma unroll
  for (int rt2 = 0; rt2 < 2; ++rt2) {
    const int rrow = (w * 2 + rt2) * 16 + fr;
#pragma unroll
    for (int bi = 0; bi < 4; ++bi) {
      bf16x8 a2 = (fq < 2)
        ? __builtin_bit_cast(bf16x8, *(const u16x8*)&WTs[rrow * 64 + swz(rrow, bi * 16 + fq * 8)])
        : zfrag();
      bf16x8 b2 = (fq < 2)
        ? __builtin_bit_cast(bf16x8, *(const u16x8*)&Db[bi * 16 * DBS + fr * DBS + fq * 8])
        : zfrag();
      rtacc[rt2][bi] = __builtin_amdgcn_mfma_f32_16x16x32_bf16(a2, b2, f32x4{0, 0, 0, 0}, 0, 0, 0);
    }
  }
  __syncthreads();   // all L~/R~ reads done before overwrites
  {
    const int pbi[6] = {1, 2, 2, 3, 3, 3}, pbj[6] = {0, 0, 1, 0, 1, 2};
    const int tt = tid >> 4, s = tid & 15;
#pragma unroll
    for (int e = 0; e < 6; ++e)
      Lb[(pbi[e] * 16 + tt) * 64 + swz(pbi[e] * 16 + tt, pbj[e] * 16 + s)] = f2bf(-ltil[e]);
  }
#pragma unroll
  for (int rt2 = 0; rt2 < 2; ++rt2)
#pragma unroll
    for (int bi = 0; bi < 4; ++bi)
#pragma unroll
      for (int r = 0; r < 4; ++r) {
        int rr = (w * 2 + rt2) * 16 + fq * 4 + r;
        WTs[rr * 64 + swz(rr, bi * 16 + fr)] = f2bf(rtacc[rt2][bi][r]);
      }
  __syncthreads();

  // ---- P6: 3-step MFMA substitution (row-tiles wave-exclusive, no barriers) ----
#pragma unroll
  for (int rt2 = 0; rt2 < 2; ++rt2) {
    const int rrow = (w * 2 + rt2) * 16 + fr;
    const int wr0 = (w * 2 + rt2) * 16 + fq * 4;
#pragma unroll
    for (int i = 1; i < 4; ++i) {
      f32x4 a2;
#pragma unroll
      for (int r = 0; r < 4; ++r)
        a2[r] = bf2f(WTs[(wr0 + r) * 64 + swz(wr0 + r, i * 16 + fr)]);
      {
        bf16x8 af = __builtin_bit_cast(bf16x8, *(const u16x8*)&WTs[rrow * 64 + swz(rrow, fq * 8)]);
        bf16x8 bf_;
        if (i == 1) bf_ = (fq < 2)
          ? __builtin_bit_cast(bf16x8, *(const u16x8*)&Lb[(16 + fr) * 64 + swz(16 + fr, fq * 8)])
          : zfrag();
        else bf_ = __builtin_bit_cast(bf16x8, *(const u16x8*)&Lb[(i * 16 + fr) * 64 + swz(i * 16 + fr, fq * 8)]);
        a2 = __builtin_amdgcn_mfma_f32_16x16x32_bf16(af, bf_, a2, 0, 0, 0);
      }
      if (i == 3) {
        bf16x8 af = __builtin_bit_cast(bf16x8, *(const u16x8*)&WTs[rrow * 64 + swz(rrow, 32 + fq * 8)]);
        bf16x8 bf_ = (fq < 2)
          ? __builtin_bit_cast(bf16x8, *(const u16x8*)&Lb[(48 + fr) * 64 + swz(48 + fr, 32 + fq * 8)])
          : zfrag();
        a2 = __builtin_amdgcn_mfma_f32_16x16x32_bf16(af, bf_, a2, 0, 0, 0);
      }
#pragma unroll
      for (int r = 0; r < 4; ++r)
        WTs[(wr0 + r) * 64 + swz(wr0 + r, i * 16 + fr)] = f2bf(a2[r]);
    }
  }
  __syncthreads();

  // ---- P7: final 4 GEMMs, SWAPPED operands (outputs transposed) ----
  const int prow = w * 16 + fr;
  u16x4 qpre4[4];
#pragma unroll
  for (int n = 0; n < 4; ++n)
    qpre4[n] = *(const u16x4*)&qkv[qkvT_idx(0, h, t0 + prow, n * 16 + fq * 4)];

  f32x4 aG[4], aU[4], aQe[4], aOi[4];
#pragma unroll
  for (int n = 0; n < 4; ++n) {
    aG[n] = f32x4{0, 0, 0, 0}; aU[n] = f32x4{0, 0, 0, 0};
    aQe[n] = f32x4{0, 0, 0, 0}; aOi[n] = f32x4{0, 0, 0, 0};
  }
  {
    bf16x8 aKd[2], aWv[2], aMq[2];   // B-operands: rows ar
#pragma unroll
    for (int kk = 0; kk < 2; ++kk) {
      aKd[kk] = __builtin_bit_cast(bf16x8, *(const u16x8*)&KdT[ar * 64 + swz(ar, kk * 32 + fq * 8)]);
      aWv[kk] = __builtin_bit_cast(bf16x8, *(const u16x8*)&WTs[ar * 64 + swz(ar, kk * 32 + fq * 8)]);
      aMq[kk] = __builtin_bit_cast(bf16x8, *(const u16x8*)&MqS[ar * 64 + swz(ar, kk * 32 + fq * 8)]);
    }
#pragma unroll
    for (int n = 0; n < 4; ++n) {
      const int br = n * 16 + fr;
#pragma unroll
      for (int kk = 0; kk < 2; ++kk) {
        bf16x8 bTw = __builtin_bit_cast(bf16x8, *(const u16x8*)&WTs[(64 + br) * 64 + swz(64 + br, kk * 32 + fq * 8)]);
        bf16x8 bKd = __builtin_bit_cast(bf16x8, *(const u16x8*)&KdT[br * 64 + swz(br, kk * 32 + fq * 8)]);
        bf16x8 bWv = __builtin_bit_cast(bf16x8, *(const u16x8*)&WTs[br * 64 + swz(br, kk * 32 + fq * 8)]);
        aG[n]  = __builtin_amdgcn_mfma_f32_16x16x32_bf16(bTw, aKd[kk], aG[n], 0, 0, 0);  // (Kd^T Tw)[j][j']
        aU[n]  = __builtin_amdgcn_mfma_f32_16x16x32_bf16(bKd, aWv[kk], aU[n], 0, 0, 0);  // U[d][j]
        aQe[n] = __builtin_amdgcn_mfma_f32_16x16x32_bf16(bTw, aMq[kk], aQe[n], 0, 0, 0); // (MqTw)[t][j']
        aOi[n] = __builtin_amdgcn_mfma_f32_16x16x32_bf16(bWv, aMq[kk], aOi[n], 0, 0, 0); // Oi[t][d]
      }
    }
  }
  // ---- P8: u16x4 vector stores (row = prow, 4 consecutive swizzled cols) ----
  asm volatile("s_waitcnt vmcnt(0)" ::: "memory");   // qpre4 data arrived before overwrite
  __builtin_amdgcn_sched_barrier(0);
  const float aqs = Avec[prow] * nqinv[prow];
#pragma unroll
  for (int n = 0; n < 4; ++n) {
    u16x4 vq, vg, vu, vo;
#pragma unroll
    for (int r = 0; r < 4; ++r) {
      vq[r] = f2bf(aqs * bf2f(qpre4[n][r]) - aQe[n][r]);
      vg[r] = f2bf(-aG[n][r]);
      vu[r] = f2bf(aU[n][r]);
      vo[r] = f2bf(aOi[n][r]);
    }
    const int scol = swz(prow, n * 16 + fq * 4);
    *(u16x4*)&qkv[qkvT_idx(0, h, t0 + prow, scol)] = vq;
    *(u16x4*)&qkv[qkvT_idx(1, h, t0 + prow, scol)] = vg;
    *(u16x4*)&qkv[qkvT_idx(2, h, t0 + prow, scol)] = vu;
    *(u16x4*)&Ks[prow * 64 + scol] = vo;   // Ks dead since P3; swizzled (bank spread)
  }
  __syncthreads();
#pragma unroll
  for (int p = 0; p < 2; ++p) {
    const int idx = p * 256 + tid;
    const int row = idx >> 3, seg = (idx & 7) * 8;
    *(u16x8*)&oi[(long)unit * 4096 + row * 64 + seg] = *(const u16x8*)&Ks[row * 64 + swz(row, seg)];
  }
}

// ---------------- sequential chunk recurrence (16 waves, 1 barrier/chunk) -----
__global__ __launch_bounds__(1024) void k_seq(const u16* __restrict__ qkv,
                                              const u16* __restrict__ oi,
                                              const float* __restrict__ A63G,
                                              u16* __restrict__ ob) {
  __shared__ __align__(16) u16 Sb[2][64 * 64];
  __shared__ __align__(16) u16 Obs[2][64 * 64];
  __shared__ __align__(16) u16 stg[3][4][64 * 64];   // 96KB
  __shared__ float a63s[64];
  const int pair = blockIdx.x;
  const int b = pair >> 4, h = pair & 15;
  const int tid = threadIdx.x, l = tid & 63, w = tid >> 6;   // w 0..15
  const int fr = l & 15, fq = l >> 4;
  const int tw = w >> 2, td = w & 3;

  auto stage = [&](int c) {
    const int s = c % 3;
    const long tg = (long)b * NT + (long)c * CC;
    if (tid < 512) {
      const int row = tid >> 3, seg = (tid & 7) * 8;
#pragma unroll
      for (int m = 0; m < 4; ++m) {
        const u16* src = (m < 3)
          ? &qkv[qkvT_idx(m, h, tg + row, seg)]
          : &oi[(long)(pair * 64 + c) * 4096 + row * 64 + seg];
        gload_lds16(src, &stg[s][m][row * 64 + seg]);
      }
    }
  };

  if (tid < 64) a63s[tid] = A63G[pair * 64 + tid];
  for (int i = tid; i < 4096; i += 1024) Sb[0][i] = 0;
  stage(0); stage(1);
  f32x4 sacc = f32x4{0, 0, 0, 0};
  asm volatile("s_waitcnt lgkmcnt(0)" ::: "memory");
  __builtin_amdgcn_sched_barrier(0);

  for (int c = 0; c < NCH; ++c) {
    const int sb = c & 1, st = c % 3;
    const long tg = (long)b * NT + (long)c * CC;
    if (c <= 1)             { asm volatile("s_waitcnt vmcnt(4)" ::: "memory"); }
    else if (c < NCH - 1)   { asm volatile("s_waitcnt vmcnt(5)" ::: "memory"); }
    else                    { asm volatile("s_waitcnt vmcnt(1)" ::: "memory"); }
    __builtin_amdgcn_sched_barrier(0);
    __builtin_amdgcn_s_barrier();
    __builtin_amdgcn_sched_barrier(0);

    if (c > 0 && tid < 512) {
      const int row = tid >> 3, seg = (tid & 7) * 8;
      *(u16x8*)&ob[(tg - CC + row) * 1024 + h * 64 + seg] = *(const u16x8*)&Obs[sb ^ 1][row * 64 + seg];
    }
    if (c + 2 < NCH) stage(c + 2);

    const u16* Qe = stg[st][0];
    const u16* Gm = stg[st][1];
    const u16* Um = stg[st][2];
    const u16* Obl = stg[st][3];

    const int at = tw * 16 + fr;
    const int bd = td * 16 + fr;
    f32x4 ao = f32x4{0, 0, 0, 0};
    const float A63 = a63s[c];
#pragma unroll
    for (int r = 0; r < 4; ++r) sacc[r] *= A63;
#pragma unroll
    for (int kk = 0; kk < 2; ++kk) {
      bf16x8 aq = __builtin_bit_cast(bf16x8, *(const u16x8*)&Qe[at * 64 + swz(at, kk * 32 + fq * 8)]);
      bf16x8 sbf = __builtin_bit_cast(bf16x8, *(const u16x8*)&Sb[sb][bd * 64 + swz(bd, kk * 32 + fq * 8)]);
      ao = __builtin_amdgcn_mfma_f32_16x16x32_bf16(aq, sbf, ao, 0, 0, 0);
      bf16x8 as_ = __builtin_bit_cast(bf16x8, *(const u16x8*)&Sb[sb][at * 64 + swz(at, kk * 32 + fq * 8)]);
      bf16x8 g  = __builtin_bit_cast(bf16x8, *(const u16x8*)&Gm[bd * 64 + swz(bd, kk * 32 + fq * 8)]);
      sacc = __builtin_amdgcn_mfma_f32_16x16x32_bf16(as_, g, sacc, 0, 0, 0);
    }
#pragma unroll
    for (int r = 0; r < 4; ++r) {
      const int ri = tw * 16 + fq * 4 + r;
      const int cj = td * 16 + fr;
      sacc[r] += bf2f(Um[ri * 64 + swz(ri, cj)]);
      Obs[sb][ri * 64 + cj] = f2bf(bf2f(Obl[ri * 64 + cj]) + ao[r]);
      Sb[sb ^ 1][ri * 64 + swz(ri, cj)] = f2bf(sacc[r]);
    }
    asm volatile("s_waitcnt lgkmcnt(0)" ::: "memory");
    __builtin_amdgcn_sched_barrier(0);
  }
  __builtin_amdgcn_s_barrier();
  if (tid < 512) {
    const int row = tid >> 3, seg = (tid & 7) * 8;
    const long tg = (long)b * NT + (long)(NCH - 1) * CC;
    *(u16x8*)&ob[(tg + row) * 1024 + h * 64 + seg] = *(const u16x8*)&Obs[(NCH - 1) & 1][row * 64 + seg];
  }
}

extern "C" void kernel_launch(void* const* d_in, const int* in_sizes, int n_in,
                              void* d_out, int out_size, void* d_ws, size_t ws_size,
                              hipStream_t stream) {
  const float* x    = (const float*)d_in[0];
  const float* Wqkv = (const float*)d_in[1];
  const float* Wg   = (const float*)d_in[2];
  const float* bg   = (const float*)d_in[3];
  const float* Wb   = (const float*)d_in[4];
  const float* bb   = (const float*)d_in[5];
  const float* Wout = (const float*)d_in[6];
  float* out = (float*)d_out;

  char* ws = (char*)d_ws;
  u16* xb    = (u16*)ws;                               // 16384*1024   (32MB)
  u16* wqkvb = xb    + (long)BT * NDIM;                // 3072*1024    (6MB)
  u16* woutb = wqkvb + (long)3072 * 1024;              // 1024*1024    (2MB)
  u16* wgbb  = woutb + (long)1024 * 1024;              // 128*1024
  u16* qkvb  = wgbb  + (long)128 * 1024;               // [48][BT][64] (96MB)
  u16* ob    = qkvb  + (long)BT * 3072;                // 16384*1024   (32MB)
  float* graw  = (float*)(ob + (long)BT * NDIM);       // 16384*128    (8MB, A63G home)
  float* alpha = graw + (long)BT * 128;                // 16384*16     (1MB)
  float* beta  = alpha + (long)BT * NH;                // 16384*16     (1MB)
  float* A63G  = graw;
  u16*   oi    = xb;     // reuse: xb dead after k_gates; NU*4096 u16 = 32MB exact

  // 1. converts
  k_f32_to_bf16<<<(BT * (long)NDIM / 4 + 255) / 256, 256, 0, stream>>>(x, xb, BT * (long)NDIM / 4);
  k_f32_to_bf16<<<(3072L * 1024 / 4 + 255) / 256, 256, 0, stream>>>(Wqkv, wqkvb, 3072L * 1024 / 4);
  k_f32_to_bf16<<<(1024L * 1024 / 4 + 255) / 256, 256, 0, stream>>>(Wout, woutb, 1024L * 1024 / 4);
  k_build_wgb<<<(128 * 1024) / 256, 256, 0, stream>>>(Wg, Wb, wgbb);

  // 2. qkv GEMM (256^2 ring-4 pipeline, head-major vector-store output)
  k_gemm256<u16, true><<<64 * 12, 512, 0, stream>>>(xb, wqkvb, qkvb, BT, 3072, NDIM);

  // 3. fused gates GEMM + sigmoid
  k_gates<<<BT / 128, 256, 0, stream>>>(xb, wgbb, bg, bb, alpha, beta);

  // 4. chunked WY: parallel precompute + sequential chunk GEMMs (16-wave)
  k_prep<<<NU, 256, 0, stream>>>(qkvb, alpha, beta, A63G, oi);
  k_seq<<<NPAIR, 1024, 0, stream>>>(qkvb, oi, A63G, ob);

  // 5. out GEMM (256^2 ring-4 pipeline): 16384x1024 = ob @ woutb^T (fp32 out)
  k_gemm256<float, false><<<64 * 4, 512, 0, stream>>>(ob, woutb, out, BT, NDIM, NDIM);
}